// Round 6
// baseline (1958.093 us; speedup 1.0000x reference)
//
#include <hip/hip_runtime.h>
#include <hip/hip_bf16.h>
#include <math.h>

__device__ __forceinline__ float bf2f(unsigned short u) {
    return __uint_as_float((unsigned)u << 16);
}
__device__ __forceinline__ float ldf(const float* p) { return *p; }
__device__ __forceinline__ float ldf(const __hip_bfloat16* p) {
    return bf2f(*(const unsigned short*)p);
}
__device__ __forceinline__ void ld2(const float* p, float& a, float& b) {
    float2 t = *(const float2*)p; a = t.x; b = t.y;
}
__device__ __forceinline__ void ld2(const __hip_bfloat16* p, float& a, float& b) {
    ushort2 t = *(const ushort2*)p; a = bf2f(t.x); b = bf2f(t.y);
}
__device__ __forceinline__ void ld4(const float* p, float* o) {
    float4 t = *(const float4*)p; o[0] = t.x; o[1] = t.y; o[2] = t.z; o[3] = t.w;
}
__device__ __forceinline__ void ld4(const __hip_bfloat16* p, float* o) {
    ushort4 t = *(const ushort4*)p;
    o[0] = bf2f(t.x); o[1] = bf2f(t.y); o[2] = bf2f(t.z); o[3] = bf2f(t.w);
}
__device__ __forceinline__ void stf(float* p, float v) { *p = v; }
__device__ __forceinline__ void stf(__hip_bfloat16* p, float v) { *p = __float2bfloat16(v); }
__device__ __forceinline__ void st2(float* p, float a, float b) {
    float2 t; t.x = a; t.y = b; *(float2*)p = t;
}
__device__ __forceinline__ void st2(__hip_bfloat16* p, float a, float b) {
    __hip_bfloat162 t; t.x = __float2bfloat16(a); t.y = __float2bfloat16(b);
    *(__hip_bfloat162*)p = t;
}
__device__ __forceinline__ void st4(float* p, float a, float b, float c, float d) {
    float4 t; t.x = a; t.y = b; t.z = c; t.w = d; *(float4*)p = t;
}
__device__ __forceinline__ void st4(__hip_bfloat16* p, float a, float b, float c, float d) {
    union { __hip_bfloat162 h[2]; float2 f; } u;
    u.h[0] = __halves2bfloat162(__float2bfloat16(a), __float2bfloat16(b));
    u.h[1] = __halves2bfloat162(__float2bfloat16(c), __float2bfloat16(d));
    *(float2*)p = u.f;
}

__device__ __forceinline__ float actf(float r, int ACT) {
    if (ACT == 1) r = (r >= 0.f) ? r : 0.1f * r;
    if (ACT == 2) r = 1.f / (1.f + __expf(-r));
    return r;
}

// ---- vectorized row loads (alignment guaranteed by x0 % 4 == 0 construction) ----
template<int IC, typename TIN>
__device__ __forceinline__ void conv_load_ci(const TIN* ipc, int iyb, int ixb,
                                             int Hi, int Wi, float iv[3][IC])
{
    #pragma unroll
    for (int r = 0; r < 3; ++r) {
        int iy = iyb + r;
        bool vy = (unsigned)iy < (unsigned)Hi;
        const TIN* row = ipc + (size_t)iy * Wi;
        if (vy) {
            if constexpr (IC == 9) {            // stride2, X_T=4: head + 2x vec4
                iv[r][0] = (ixb >= 0) ? ldf(row + ixb) : 0.f;
                ld4(row + ixb + 1, &iv[r][1]);
                ld4(row + ixb + 5, &iv[r][5]);
            } else if constexpr (IC == 6) {     // stride1, X_T=4: head + vec4 + tail
                iv[r][0] = (ixb >= 0) ? ldf(row + ixb) : 0.f;
                ld4(row + ixb + 1, &iv[r][1]);
                iv[r][5] = (ixb + 5 < Wi) ? ldf(row + ixb + 5) : 0.f;
            } else if constexpr (IC == 4) {     // stride1, X_T=2: head + vec2 + tail
                iv[r][0] = (ixb >= 0) ? ldf(row + ixb) : 0.f;
                ld2(row + ixb + 1, iv[r][1], iv[r][2]);
                iv[r][3] = (ixb + 3 < Wi) ? ldf(row + ixb + 3) : 0.f;
            } else {
                #pragma unroll
                for (int c = 0; c < IC; ++c) {
                    int ix = ixb + c;
                    iv[r][c] = ((unsigned)ix < (unsigned)Wi) ? ldf(row + ix) : 0.f;
                }
            }
        } else {
            #pragma unroll
            for (int c = 0; c < IC; ++c) iv[r][c] = 0.f;
        }
    }
}

template<int IC, int STRIDE, int X_T, int CO_T>
__device__ __forceinline__ void conv_compute(const float iv[3][IC], const float* swci,
                                             float acc[CO_T][X_T])
{
    #pragma unroll
    for (int cot = 0; cot < CO_T; ++cot) {
        const float4* wp4 = reinterpret_cast<const float4*>(swci + cot * 12);
        float4 wa = wp4[0], wb = wp4[1], wc4 = wp4[2];
        float wreg[9] = {wa.x, wa.y, wa.z, wa.w, wb.x, wb.y, wb.z, wb.w, wc4.x};
        #pragma unroll
        for (int r = 0; r < 3; ++r)
            #pragma unroll
            for (int c = 0; c < 3; ++c)
                #pragma unroll
                for (int u = 0; u < X_T; ++u)
                    acc[cot][u] = fmaf(iv[r][u * STRIDE + c], wreg[r * 3 + c], acc[cot][u]);
    }
}

// ================= register-tiled conv3x3 + BN + act, ci-pipelined =================
// weights [COUT][CIN][3][3]; block: BX lanes in x (X_T outs each), 256/BX rows.
template<int CIN, int STRIDE, int BX, int X_T, int CO_T, int ACT, bool HAS_BN,
         typename TIN, typename TOUT>
__global__ __launch_bounds__(256, 4)
void conv_t_k(const TIN* __restrict__ in, const float* __restrict__ w,
              const float* __restrict__ bconv,
              const float* __restrict__ bg, const float* __restrict__ bb,
              const float* __restrict__ bm, const float* __restrict__ bv,
              TOUT* __restrict__ out,
              int COUT, int Hi, int Wi, int Ho, int Wo,
              int cogs, int ytiles, int xtiles)
{
    constexpr int BY = 256 / BX;
    constexpr int IC = (X_T - 1) * STRIDE + 3;
    __shared__ float sw[CIN * CO_T * 12];
    int b  = blockIdx.x;
    int xt = b % xtiles; b /= xtiles;
    int yt = b % ytiles; b /= ytiles;
    int cg = b % cogs;
    int n  = b / cogs;
    int co0 = cg * CO_T;
    int tid = threadIdx.x;
    for (int idx = tid; idx < CIN * CO_T * 9; idx += 256) {
        int t = idx % 9; int rest = idx / 9;
        int cot = rest % CO_T; int ci = rest / CO_T;
        sw[(ci * CO_T + cot) * 12 + t] = w[((size_t)(co0 + cot) * CIN + ci) * 9 + t];
    }
    __syncthreads();

    int tx = tid % BX, ty = tid / BX;
    int y  = yt * BY + ty;
    int x0 = (xt * BX + tx) * X_T;
    int iyb = y * STRIDE - 1;
    int ixb = x0 * STRIDE - 1;
    const TIN* ip = in + (size_t)n * CIN * Hi * Wi;
    const size_t cstride = (size_t)Hi * Wi;

    float acc[CO_T][X_T];
    #pragma unroll
    for (int c = 0; c < CO_T; ++c)
        #pragma unroll
        for (int u = 0; u < X_T; ++u) acc[c][u] = 0.f;

    float ivA[3][IC], ivB[3][IC];
    conv_load_ci<IC>(ip, iyb, ixb, Hi, Wi, ivA);
    for (int ci = 0; ci < CIN; ci += 2) {
        if (ci + 1 < CIN) conv_load_ci<IC>(ip + (ci + 1) * cstride, iyb, ixb, Hi, Wi, ivB);
        conv_compute<IC, STRIDE, X_T, CO_T>(ivA, &sw[ci * CO_T * 12], acc);
        if (ci + 2 < CIN) conv_load_ci<IC>(ip + (ci + 2) * cstride, iyb, ixb, Hi, Wi, ivA);
        if (ci + 1 < CIN) conv_compute<IC, STRIDE, X_T, CO_T>(ivB, &sw[(ci + 1) * CO_T * 12], acc);
    }

    #pragma unroll
    for (int cot = 0; cot < CO_T; ++cot) {
        int co = co0 + cot;
        float s, bias;
        if (HAS_BN) {
            s = bg[co] * rsqrtf(bv[co] + 1e-5f);
            bias = (bconv[co] - bm[co]) * s + bb[co];
        } else { s = 1.f; bias = bconv[co]; }
        TOUT* op = out + (((size_t)n * COUT + co) * Ho + y) * Wo + x0;
        if constexpr (X_T == 4) {
            st4(op, actf(acc[cot][0] * s + bias, ACT), actf(acc[cot][1] * s + bias, ACT),
                    actf(acc[cot][2] * s + bias, ACT), actf(acc[cot][3] * s + bias, ACT));
        } else if constexpr (X_T == 2) {
            st2(op, actf(acc[cot][0] * s + bias, ACT), actf(acc[cot][1] * s + bias, ACT));
        } else {
            #pragma unroll
            for (int u = 0; u < X_T; ++u) stf(op + u, actf(acc[cot][u] * s + bias, ACT));
        }
    }
}

// ====== phase-decomposed deconv3x3 (s2,p1,op1) + BN + lrelu, 2x2 pos/thread ======
template<typename TIN>
__device__ __forceinline__ void dec_load_ci(const TIN* p, int Wi, bool v_i2, bool v_j2,
                                            float iv[3][3])
{
    #pragma unroll
    for (int r = 0; r < 3; ++r) {
        bool vr = (r < 2) || v_i2;
        const TIN* rp = p + (size_t)r * Wi;
        if (vr) {
            ld2(rp, iv[r][0], iv[r][1]);
            iv[r][2] = v_j2 ? ldf(rp + 2) : 0.f;
        } else {
            iv[r][0] = 0.f; iv[r][1] = 0.f; iv[r][2] = 0.f;
        }
    }
}

template<int CO_T>
__device__ __forceinline__ void dec_compute(const float iv[3][3], const float* swci,
                                            float acc[CO_T][4][4])
{
    #pragma unroll
    for (int cot = 0; cot < CO_T; ++cot) {
        const float4* wp4 = reinterpret_cast<const float4*>(swci + cot * 12);
        float4 wa = wp4[0], wb = wp4[1], wc4 = wp4[2];
        float w0 = wa.x, w1 = wa.y, w2 = wa.z, w3 = wa.w;
        float w4 = wb.x, w5 = wb.y, w6 = wb.z, w7 = wb.w, w8 = wc4.x;
        #pragma unroll
        for (int pi = 0; pi < 2; ++pi)
            #pragma unroll
            for (int pj = 0; pj < 2; ++pj) {
                float A = iv[pi][pj],     B = iv[pi][pj + 1];
                float C = iv[pi + 1][pj], D = iv[pi + 1][pj + 1];
                acc[cot][2*pi  ][2*pj  ] = fmaf(w4, A, acc[cot][2*pi  ][2*pj  ]);
                acc[cot][2*pi  ][2*pj+1] = fmaf(w3, B, fmaf(w5, A, acc[cot][2*pi  ][2*pj+1]));
                acc[cot][2*pi+1][2*pj  ] = fmaf(w1, C, fmaf(w7, A, acc[cot][2*pi+1][2*pj  ]));
                acc[cot][2*pi+1][2*pj+1] = fmaf(w0, D, fmaf(w2, C,
                                           fmaf(w6, B, fmaf(w8, A, acc[cot][2*pi+1][2*pj+1]))));
            }
    }
}

// weights [CIN][COUT][3][3]. Thread: 2x2 input positions -> 4x4 outputs x CO_T.
template<int CIN, int CO_T, int BJ, typename TIN, typename TOUT>
__global__ __launch_bounds__(256, 4)
void deconv_t2_k(const TIN* __restrict__ in, const float* __restrict__ w,
                 const float* __restrict__ bconv,
                 const float* __restrict__ bg, const float* __restrict__ bb,
                 const float* __restrict__ bm, const float* __restrict__ bv,
                 TOUT* __restrict__ out,
                 int COUT, int Hi, int Wi, int cogs, int itiles)
{
    constexpr int BI = 256 / BJ;
    __shared__ float sw[CIN * CO_T * 12];
    int b  = blockIdx.x;
    int it = b % itiles; b /= itiles;
    int cg = b % cogs;
    int n  = b / cogs;
    int co0 = cg * CO_T;
    int tid = threadIdx.x;
    for (int idx = tid; idx < CIN * CO_T * 9; idx += 256) {
        int t = idx % 9; int rest = idx / 9;
        int cot = rest % CO_T; int ci = rest / CO_T;
        sw[(ci * CO_T + cot) * 12 + t] = w[((size_t)ci * COUT + co0 + cot) * 9 + t];
    }
    __syncthreads();

    int tj = tid % BJ, ti = tid / BJ;
    int i0 = (it * BI + ti) * 2;
    int j0 = tj * 2;
    bool v_i2 = (i0 + 2) < Hi;
    bool v_j2 = (j0 + 2) < Wi;
    const TIN* ip = in + (size_t)n * CIN * Hi * Wi + (size_t)i0 * Wi + j0;
    const size_t cstride = (size_t)Hi * Wi;

    float acc[CO_T][4][4];
    #pragma unroll
    for (int c = 0; c < CO_T; ++c)
        #pragma unroll
        for (int r = 0; r < 4; ++r)
            #pragma unroll
            for (int u = 0; u < 4; ++u) acc[c][r][u] = 0.f;

    float ivA[3][3], ivB[3][3];
    dec_load_ci(ip, Wi, v_i2, v_j2, ivA);
    for (int ci = 0; ci < CIN; ci += 2) {
        if (ci + 1 < CIN) dec_load_ci(ip + (ci + 1) * cstride, Wi, v_i2, v_j2, ivB);
        dec_compute<CO_T>(ivA, &sw[ci * CO_T * 12], acc);
        if (ci + 2 < CIN) dec_load_ci(ip + (ci + 2) * cstride, Wi, v_i2, v_j2, ivA);
        if (ci + 1 < CIN) dec_compute<CO_T>(ivB, &sw[(ci + 1) * CO_T * 12], acc);
    }

    int Ho = Hi * 2, Wo = Wi * 2;
    #pragma unroll
    for (int cot = 0; cot < CO_T; ++cot) {
        int co = co0 + cot;
        float s = bg[co] * rsqrtf(bv[co] + 1e-5f);
        float bias = (bconv[co] - bm[co]) * s + bb[co];
        TOUT* op = out + (((size_t)n * COUT + co) * Ho + 2 * i0) * Wo + 2 * j0;
        #pragma unroll
        for (int rr = 0; rr < 4; ++rr) {
            st4(op + (size_t)rr * Wo,
                actf(acc[cot][rr][0] * s + bias, 1),
                actf(acc[cot][rr][1] * s + bias, 1),
                actf(acc[cot][rr][2] * s + bias, 1),
                actf(acc[cot][rr][3] * s + bias, 1));
        }
    }
}

// ---------------- VQ: nearest-embedding + q write + SSE + histogram ----------------
__global__ __launch_bounds__(256)
void vq_k(const float* __restrict__ z, const float* __restrict__ emb,
          float* __restrict__ q, float* __restrict__ sse_acc,
          unsigned int* __restrict__ counts, int HW, int CHW)
{
    __shared__ float se[256 * 10];
    __shared__ unsigned int hist[256];
    __shared__ float wsum[4];
    int tid = threadIdx.x;
    for (int i = tid; i < 2560; i += 256) se[i] = emb[i];
    hist[tid] = 0u;
    __syncthreads();

    int pos = blockIdx.x * 256 + tid;
    int b = pos / HW;
    int sp = pos - b * HW;
    const float* zp = z + (size_t)b * CHW + sp;
    float zv[10];
    #pragma unroll
    for (int c = 0; c < 10; ++c) zv[c] = zp[(size_t)c * HW];

    float best = 3.4e38f;
    int bi = 0;
    for (int k = 0; k < 256; ++k) {
        const float* e = se + k * 10;
        float d = 0.f;
        #pragma unroll
        for (int c = 0; c < 10; ++c) { float t = zv[c] - e[c]; d = fmaf(t, t, d); }
        if (d < best) { best = d; bi = k; }
    }
    atomicAdd(&hist[bi], 1u);

    float* qp = q + (size_t)b * CHW + sp;
    float lsse = 0.f;
    #pragma unroll
    for (int c = 0; c < 10; ++c) {
        float e = se[bi * 10 + c];
        qp[(size_t)c * HW] = e;
        float t = e - zv[c];
        lsse = fmaf(t, t, lsse);
    }
    #pragma unroll
    for (int off = 32; off > 0; off >>= 1) lsse += __shfl_down(lsse, off, 64);
    if ((tid & 63) == 0) wsum[tid >> 6] = lsse;
    __syncthreads();
    if (tid == 0) atomicAdd(sse_acc, wsum[0] + wsum[1] + wsum[2] + wsum[3]);
    atomicAdd(&counts[tid], hist[tid]);
}

__global__ __launch_bounds__(256)
void vq_finalize_k(const float* __restrict__ sse_acc, const unsigned int* __restrict__ counts,
                   float* __restrict__ out_loss, float* __restrict__ out_ppl,
                   float invNC, float invN)
{
    __shared__ float w4[4];
    int tid = threadIdx.x;
    float p = (float)counts[tid] * invN;
    float t = p * logf(p + 1e-10f);
    #pragma unroll
    for (int off = 32; off > 0; off >>= 1) t += __shfl_down(t, off, 64);
    if ((tid & 63) == 0) w4[tid >> 6] = t;
    __syncthreads();
    if (tid == 0) {
        float s = w4[0] + w4[1] + w4[2] + w4[3];
        *out_ppl  = expf(-s);
        *out_loss = 1.25f * sse_acc[0] * invNC;
    }
}

__global__ void zero_k(float* p, int n) {
    int i = blockIdx.x * 256 + threadIdx.x;
    if (i < n) p[i] = 0.f;
}

extern "C" void kernel_launch(void* const* d_in, const int* in_sizes, int n_in,
                              void* d_out, int out_size, void* d_ws, size_t ws_size,
                              hipStream_t stream) {
    const float* x      = (const float*)d_in[0];
    const float* enc_w1 = (const float*)d_in[1];
    const float* enc_b1 = (const float*)d_in[2];
    const float* bn1_g  = (const float*)d_in[3];
    const float* bn1_b  = (const float*)d_in[4];
    const float* bn1_m  = (const float*)d_in[5];
    const float* bn1_v  = (const float*)d_in[6];
    const float* enc_w2 = (const float*)d_in[7];
    const float* enc_b2 = (const float*)d_in[8];
    const float* bn2_g  = (const float*)d_in[9];
    const float* bn2_b  = (const float*)d_in[10];
    const float* bn2_m  = (const float*)d_in[11];
    const float* bn2_v  = (const float*)d_in[12];
    const float* enc_w3 = (const float*)d_in[13];
    const float* enc_b3 = (const float*)d_in[14];
    const float* bn3_g  = (const float*)d_in[15];
    const float* bn3_b  = (const float*)d_in[16];
    const float* bn3_m  = (const float*)d_in[17];
    const float* bn3_v  = (const float*)d_in[18];
    const float* emb    = (const float*)d_in[19];
    const float* dec_w1 = (const float*)d_in[20];
    const float* dec_b1 = (const float*)d_in[21];
    const float* dbn1_g = (const float*)d_in[22];
    const float* dbn1_b = (const float*)d_in[23];
    const float* dbn1_m = (const float*)d_in[24];
    const float* dbn1_v = (const float*)d_in[25];
    const float* dec_w2 = (const float*)d_in[26];
    const float* dec_b2 = (const float*)d_in[27];
    const float* dbn2_g = (const float*)d_in[28];
    const float* dbn2_b = (const float*)d_in[29];
    const float* dbn2_m = (const float*)d_in[30];
    const float* dbn2_v = (const float*)d_in[31];
    const float* dec_w3 = (const float*)d_in[32];
    const float* dec_b3 = (const float*)d_in[33];

    float* ws = (float*)d_ws;
    const size_t Z_OFF   = 0;                         // 1,310,720 f
    const size_t Q_OFF   = 1310720;                   // 1,310,720 f
    const size_t SSE_OFF = 2621440;                   // 1 f
    const size_t CNT_OFF = 2621441;                   // 256 u32
    const size_t RX_OFF  = 2621952;                   // h1 fp32 | dd1 bf16 (same bytes)
    const size_t RY_OFF  = RX_OFF + 16777216;         // h2 fp32 | dd2 bf16
    const size_t NEEDED_F = RY_OFF + 33554432;

    if (ws_size < NEEDED_F * sizeof(float)) return;

    float* zbuf = ws + Z_OFF;
    float* qbuf = ws + Q_OFF;
    float* sse  = ws + SSE_OFF;
    unsigned int* counts = (unsigned int*)(ws + CNT_OFF);
    float* h1 = ws + RX_OFF;
    float* h2 = ws + RY_OFF;
    __hip_bfloat16* dd1 = (__hip_bfloat16*)(ws + RX_OFF);
    __hip_bfloat16* dd2 = (__hip_bfloat16*)(ws + RY_OFF);
    float* out = (float*)d_out;

    zero_k<<<2, 256, 0, stream>>>(ws + SSE_OFF, 257);

    // conv1: 3->32, s2, 256->128. BX=32,X_T=4 (covers 128), CO_T=4, cogs=8, ytiles=16 (BY=8)
    conv_t_k<3, 2, 32, 4, 4, 1, true><<<32 * 8 * 16, 256, 0, stream>>>(
        x, enc_w1, enc_b1, bn1_g, bn1_b, bn1_m, bn1_v, h1, 32, 256, 256, 128, 128, 8, 16, 1);
    // conv2: 32->64, s2, 128->64. BX=16,X_T=4 (covers 64), CO_T=8, cogs=8, ytiles=4 (BY=16)
    conv_t_k<32, 2, 16, 4, 8, 1, true><<<32 * 8 * 4, 256, 0, stream>>>(
        h1, enc_w2, enc_b2, bn2_g, bn2_b, bn2_m, bn2_v, h2, 64, 128, 128, 64, 64, 8, 4, 1);
    // conv3: 64->10, s1, 64. BX=32,X_T=2 (covers 64), CO_T=5, cogs=2, ytiles=8 (BY=8)
    conv_t_k<64, 1, 32, 2, 5, 0, true><<<32 * 2 * 8, 256, 0, stream>>>(
        h2, enc_w3, enc_b3, bn3_g, bn3_b, bn3_m, bn3_v, zbuf, 10, 64, 64, 64, 64, 2, 8, 1);

    vq_k<<<131072 / 256, 256, 0, stream>>>(zbuf, emb, qbuf, sse, counts, 4096, 40960);

    // deconv1: 10->64, 64->128. BJ=32 (covers 64), BI=8, itiles=4, CO_T=4, cogs=16
    deconv_t2_k<10, 4, 32><<<32 * 16 * 4, 256, 0, stream>>>(
        qbuf, dec_w1, dec_b1, dbn1_g, dbn1_b, dbn1_m, dbn1_v, dd1, 64, 64, 64, 16, 4);
    // deconv2: 64->32, 128->256. BJ=64 (covers 128), BI=4, itiles=16, CO_T=4, cogs=8
    deconv_t2_k<64, 4, 64><<<32 * 8 * 16, 256, 0, stream>>>(
        dd1, dec_w2, dec_b2, dbn2_g, dbn2_b, dbn2_m, dbn2_v, dd2, 32, 128, 128, 8, 16);
    // conv_out: 32->3, s1, 256. BX=64,X_T=4 (covers 256), CO_T=3, cogs=1, ytiles=64 (BY=4)
    conv_t_k<32, 1, 64, 4, 3, 2, false><<<32 * 64, 256, 0, stream>>>(
        dd2, dec_w3, dec_b3, nullptr, nullptr, nullptr, nullptr, out, 3, 256, 256, 256, 256, 1, 64, 1);

    vq_finalize_k<<<1, 256, 0, stream>>>(sse, counts, out + 6291456, out + 6291457,
                                         1.f / 1310720.f, 1.f / 131072.f);
}

// Round 7
// 1300.897 us; speedup vs baseline: 1.5052x; 1.5052x over previous
//
#include <hip/hip_runtime.h>
#include <hip/hip_bf16.h>
#include <math.h>

typedef __attribute__((ext_vector_type(8))) short bf8v;   // 8 bf16 in 4 VGPRs
typedef __attribute__((ext_vector_type(4))) float f4v;    // MFMA accumulator

__device__ __forceinline__ float bf2f(unsigned short u) {
    return __uint_as_float((unsigned)u << 16);
}
__device__ __forceinline__ float ldf(const float* p) { return *p; }
__device__ __forceinline__ float ldf(const __hip_bfloat16* p) {
    return bf2f(*(const unsigned short*)p);
}
__device__ __forceinline__ void ld2(const float* p, float& a, float& b) {
    float2 t = *(const float2*)p; a = t.x; b = t.y;
}
__device__ __forceinline__ void ld4(const float* p, float* o) {
    float4 t = *(const float4*)p; o[0] = t.x; o[1] = t.y; o[2] = t.z; o[3] = t.w;
}
__device__ __forceinline__ void stf(float* p, float v) { *p = v; }
__device__ __forceinline__ void st2(float* p, float a, float b) {
    float2 t; t.x = a; t.y = b; *(float2*)p = t;
}
__device__ __forceinline__ void st4(float* p, float a, float b, float c, float d) {
    float4 t; t.x = a; t.y = b; t.z = c; t.w = d; *(float4*)p = t;
}
__device__ __forceinline__ float actf(float r, int ACT) {
    if (ACT == 1) r = (r >= 0.f) ? r : 0.1f * r;
    if (ACT == 2) r = 1.f / (1.f + __expf(-r));
    return r;
}

// ======================= encoder: register-tiled VALU conv =======================
template<int IC, typename TIN>
__device__ __forceinline__ void conv_load_ci(const TIN* ipc, int iyb, int ixb,
                                             int Hi, int Wi, float iv[3][IC])
{
    #pragma unroll
    for (int r = 0; r < 3; ++r) {
        int iy = iyb + r;
        bool vy = (unsigned)iy < (unsigned)Hi;
        const TIN* row = ipc + (size_t)iy * Wi;
        if (vy) {
            if constexpr (IC == 9) {
                iv[r][0] = (ixb >= 0) ? ldf(row + ixb) : 0.f;
                ld4(row + ixb + 1, &iv[r][1]);
                ld4(row + ixb + 5, &iv[r][5]);
            } else if constexpr (IC == 4) {
                iv[r][0] = (ixb >= 0) ? ldf(row + ixb) : 0.f;
                ld2(row + ixb + 1, iv[r][1], iv[r][2]);
                iv[r][3] = (ixb + 3 < Wi) ? ldf(row + ixb + 3) : 0.f;
            } else {
                #pragma unroll
                for (int c = 0; c < IC; ++c) {
                    int ix = ixb + c;
                    iv[r][c] = ((unsigned)ix < (unsigned)Wi) ? ldf(row + ix) : 0.f;
                }
            }
        } else {
            #pragma unroll
            for (int c = 0; c < IC; ++c) iv[r][c] = 0.f;
        }
    }
}

template<int IC, int STRIDE, int X_T, int CO_T>
__device__ __forceinline__ void conv_compute(const float iv[3][IC], const float* swci,
                                             float acc[CO_T][X_T])
{
    #pragma unroll
    for (int cot = 0; cot < CO_T; ++cot) {
        const float4* wp4 = reinterpret_cast<const float4*>(swci + cot * 12);
        float4 wa = wp4[0], wb = wp4[1], wc4 = wp4[2];
        float wreg[9] = {wa.x, wa.y, wa.z, wa.w, wb.x, wb.y, wb.z, wb.w, wc4.x};
        #pragma unroll
        for (int r = 0; r < 3; ++r)
            #pragma unroll
            for (int c = 0; c < 3; ++c)
                #pragma unroll
                for (int u = 0; u < X_T; ++u)
                    acc[cot][u] = fmaf(iv[r][u * STRIDE + c], wreg[r * 3 + c], acc[cot][u]);
    }
}

// weights [COUT][CIN][3][3]; block: BX lanes in x (X_T outs each), 256/BX rows. fp32 NCHW.
template<int CIN, int STRIDE, int BX, int X_T, int CO_T, int ACT, bool HAS_BN>
__global__ __launch_bounds__(256, 4)
void conv_t_k(const float* __restrict__ in, const float* __restrict__ w,
              const float* __restrict__ bconv,
              const float* __restrict__ bg, const float* __restrict__ bb,
              const float* __restrict__ bm, const float* __restrict__ bv,
              float* __restrict__ out,
              int COUT, int Hi, int Wi, int Ho, int Wo,
              int cogs, int ytiles, int xtiles)
{
    constexpr int BY = 256 / BX;
    constexpr int IC = (X_T - 1) * STRIDE + 3;
    __shared__ float sw[CIN * CO_T * 12];
    int b  = blockIdx.x;
    int xt = b % xtiles; b /= xtiles;
    int yt = b % ytiles; b /= ytiles;
    int cg = b % cogs;
    int n  = b / cogs;
    int co0 = cg * CO_T;
    int tid = threadIdx.x;
    for (int idx = tid; idx < CIN * CO_T * 9; idx += 256) {
        int t = idx % 9; int rest = idx / 9;
        int cot = rest % CO_T; int ci = rest / CO_T;
        sw[(ci * CO_T + cot) * 12 + t] = w[((size_t)(co0 + cot) * CIN + ci) * 9 + t];
    }
    __syncthreads();

    int tx = tid % BX, ty = tid / BX;
    int y  = yt * BY + ty;
    int x0 = (xt * BX + tx) * X_T;
    int iyb = y * STRIDE - 1;
    int ixb = x0 * STRIDE - 1;
    const float* ip = in + (size_t)n * CIN * Hi * Wi;
    const size_t cstride = (size_t)Hi * Wi;

    float acc[CO_T][X_T];
    #pragma unroll
    for (int c = 0; c < CO_T; ++c)
        #pragma unroll
        for (int u = 0; u < X_T; ++u) acc[c][u] = 0.f;

    float ivA[3][IC], ivB[3][IC];
    conv_load_ci<IC>(ip, iyb, ixb, Hi, Wi, ivA);
    for (int ci = 0; ci < CIN; ci += 2) {
        if (ci + 1 < CIN) conv_load_ci<IC>(ip + (ci + 1) * cstride, iyb, ixb, Hi, Wi, ivB);
        conv_compute<IC, STRIDE, X_T, CO_T>(ivA, &sw[ci * CO_T * 12], acc);
        if (ci + 2 < CIN) conv_load_ci<IC>(ip + (ci + 2) * cstride, iyb, ixb, Hi, Wi, ivA);
        if (ci + 1 < CIN) conv_compute<IC, STRIDE, X_T, CO_T>(ivB, &sw[(ci + 1) * CO_T * 12], acc);
    }

    #pragma unroll
    for (int cot = 0; cot < CO_T; ++cot) {
        int co = co0 + cot;
        float s, bias;
        if (HAS_BN) {
            s = bg[co] * rsqrtf(bv[co] + 1e-5f);
            bias = (bconv[co] - bm[co]) * s + bb[co];
        } else { s = 1.f; bias = bconv[co]; }
        float* op = out + (((size_t)n * COUT + co) * Ho + y) * Wo + x0;
        if constexpr (X_T == 4) {
            st4(op, actf(acc[cot][0] * s + bias, ACT), actf(acc[cot][1] * s + bias, ACT),
                    actf(acc[cot][2] * s + bias, ACT), actf(acc[cot][3] * s + bias, ACT));
        } else if constexpr (X_T == 2) {
            st2(op, actf(acc[cot][0] * s + bias, ACT), actf(acc[cot][1] * s + bias, ACT));
        } else {
            #pragma unroll
            for (int u = 0; u < X_T; ++u) stf(op + u, actf(acc[cot][u] * s + bias, ACT));
        }
    }
}

// ======================= decoder: NHWC + MFMA =======================
// Deconv phase/tap tables: out(2i+py,2j+px) taps; k-step g -> (di,dj,widx,ci0,phase)
struct DTab { int di[18]; int dj[18]; int wi[18]; int ci0[18]; int ph[18]; };
constexpr DTab TAB1 = {  // deconv1: CINP=32 (q padded), 9 k-steps (1 per tap)
    {0, 0,0, 1,0, 1,1,0,0,  0,0,0,0,0,0,0,0,0},
    {0, 1,0, 0,0, 1,0,1,0,  0,0,0,0,0,0,0,0,0},
    {4, 3,5, 1,7, 0,2,6,8,  0,0,0,0,0,0,0,0,0},
    {0, 0,0, 0,0, 0,0,0,0,  0,0,0,0,0,0,0,0,0},
    {0, 1,1, 2,2, 3,3,3,3,  0,0,0,0,0,0,0,0,0}};
constexpr DTab TAB2 = {  // deconv2: CINP=64, 18 k-steps (2 per tap)
    {0,0,  0,0,0,0,  1,1,0,0,  1,1,1,1,0,0,0,0},
    {0,0,  1,1,0,0,  0,0,0,0,  1,1,0,0,1,1,0,0},
    {4,4,  3,3,5,5,  1,1,7,7,  0,0,2,2,6,6,8,8},
    {0,32, 0,32,0,32, 0,32,0,32, 0,32,0,32,0,32,0,32},
    {0,0,  1,1,1,1,  2,2,2,2,  3,3,3,3,3,3,3,3}};

// pack deconv weights [CINr][COUT][3][3] fp32 -> B-fragment lane order bf16
template<int WHICH>
__global__ __launch_bounds__(256)
void pack_deconv_k(const float* __restrict__ w, __hip_bfloat16* __restrict__ bp)
{
    constexpr int NKS  = (WHICH == 1) ? 9 : 18;
    constexpr int COUT = (WHICH == 1) ? 64 : 32;
    constexpr int CINr = (WHICH == 1) ? 10 : 64;
    constexpr int NT   = COUT / 16;
    constexpr const DTab& T = (WHICH == 1) ? TAB1 : TAB2;
    int idx = blockIdx.x * 256 + threadIdx.x;
    if (idx >= NT * NKS * 64) return;
    int lane = idx & 63;
    int g    = (idx >> 6) % NKS;
    int nt   = idx / (64 * NKS);
    int co   = nt * 16 + (lane & 15);
    int wi   = T.wi[g], ci0 = T.ci0[g];
    __hip_bfloat16* o = bp + (size_t)idx * 8;
    for (int j = 0; j < 8; ++j) {
        int ci = ci0 + (lane >> 4) * 8 + j;
        float f = (ci < CINr) ? w[((size_t)ci * COUT + co) * 9 + wi] : 0.f;
        o[j] = __float2bfloat16(f);
    }
}

// pack conv_out weights [3][32][3][3] fp32 -> B frags (N=16, cols>=3 zero)
__global__ __launch_bounds__(256)
void pack_convout_k(const float* __restrict__ w, __hip_bfloat16* __restrict__ bp)
{
    int idx = blockIdx.x * 256 + threadIdx.x;
    if (idx >= 9 * 64) return;
    int lane = idx & 63;
    int g    = idx >> 6;            // tap r*3+c
    int co   = lane & 15;
    __hip_bfloat16* o = bp + (size_t)idx * 8;
    for (int j = 0; j < 8; ++j) {
        int ci = (lane >> 4) * 8 + j;
        float f = (co < 3) ? w[((size_t)co * 32 + ci) * 9 + g] : 0.f;
        o[j] = __float2bfloat16(f);
    }
}

// unified MFMA deconv (s2,p1,op1) + BN + lrelu. in NHWC [N][HI][HI][CINP] bf16,
// out NHWC [N][2HI][2HI][COUT] bf16. Wave: 16 j-positions x 16 co x all 4 phases.
template<int WHICH, int I_T>
__global__ __launch_bounds__(256, 2)
void deconv_mfma_k(const __hip_bfloat16* __restrict__ in,
                   const __hip_bfloat16* __restrict__ bpack,
                   const float* __restrict__ bconv,
                   const float* __restrict__ bg, const float* __restrict__ bb,
                   const float* __restrict__ bm, const float* __restrict__ bv,
                   __hip_bfloat16* __restrict__ out)
{
    constexpr int NKS  = (WHICH == 1) ? 9 : 18;
    constexpr int CINP = (WHICH == 1) ? 32 : 64;
    constexpr int COUT = (WHICH == 1) ? 64 : 32;
    constexpr int NT   = COUT / 16;
    constexpr int HI   = (WHICH == 1) ? 64 : 128;
    constexpr int JT   = HI / 16;
    constexpr const DTab& T = (WHICH == 1) ? TAB1 : TAB2;

    int lane = threadIdx.x & 63;
    int gw = blockIdx.x * 4 + (threadIdx.x >> 6);
    int nt = gw % NT;  int mt = gw / NT;
    int jt = mt % JT;  mt /= JT;
    int it = mt % (HI / I_T);
    int n  = mt / (HI / I_T);
    int j0 = jt * 16;
    int m  = lane & 15, kc = lane >> 4;
    int jm = j0 + m;

    bf8v bfrag[NKS];
    const bf8v* bpv = reinterpret_cast<const bf8v*>(bpack);
    #pragma unroll
    for (int g = 0; g < NKS; ++g) bfrag[g] = bpv[((size_t)nt * NKS + g) * 64 + lane];

    int co = nt * 16 + m;
    float s = bg[co] * rsqrtf(bv[co] + 1e-5f);
    float bias = (bconv[co] - bm[co]) * s + bb[co];

    for (int t = 0; t < I_T; ++t) {
        int i = it * I_T + t;
        f4v acc[4] = {{0,0,0,0},{0,0,0,0},{0,0,0,0},{0,0,0,0}};
        #pragma unroll
        for (int g = 0; g < NKS; ++g) {
            int ii = i + T.di[g];
            int jj = jm + T.dj[g];
            bf8v a = {0,0,0,0,0,0,0,0};
            if (ii < HI && jj < HI)
                a = *reinterpret_cast<const bf8v*>(
                    in + ((((size_t)n * HI + ii) * HI + jj) * CINP + T.ci0[g] + kc * 8));
            acc[T.ph[g]] = __builtin_amdgcn_mfma_f32_16x16x32_bf16(
                a, bfrag[g], acc[T.ph[g]], 0, 0, 0);
        }
        #pragma unroll
        for (int p = 0; p < 4; ++p) {
            int py = p >> 1, px = p & 1;
            #pragma unroll
            for (int r = 0; r < 4; ++r) {
                int mm = kc * 4 + r;                 // C/D row = (lane>>4)*4 + reg
                float v = acc[p][r] * s + bias;
                v = (v >= 0.f) ? v : 0.1f * v;
                int oy = 2 * i + py, ox = 2 * (j0 + mm) + px;
                out[(((size_t)n * (2 * HI) + oy) * (2 * HI) + ox) * COUT + co] =
                    __float2bfloat16(v);
            }
        }
    }
}

// conv_out: 32->3 s1 + sigmoid. in dd2 NHWC [32][256][256][32] bf16, out NCHW fp32.
__global__ __launch_bounds__(256, 2)
void convout_mfma_k(const __hip_bfloat16* __restrict__ in,
                    const __hip_bfloat16* __restrict__ bpack,
                    const float* __restrict__ b3,
                    float* __restrict__ out)
{
    int lane = threadIdx.x & 63;
    int gw = blockIdx.x * 4 + (threadIdx.x >> 6);
    int xt = gw % 16; int rest = gw / 16;
    int yt = rest % 64;
    int n  = rest / 64;
    int x0 = xt * 16;
    int m = lane & 15, kc = lane >> 4;
    int xm = x0 + m;

    bf8v bfrag[9];
    #pragma unroll
    for (int g = 0; g < 9; ++g)
        bfrag[g] = reinterpret_cast<const bf8v*>(bpack)[g * 64 + lane];

    int co = lane & 15;
    bool cw = (co < 3);
    float bias = cw ? b3[co] : 0.f;

    for (int t = 0; t < 4; ++t) {
        int y = yt * 4 + t;
        f4v acc = {0, 0, 0, 0};
        #pragma unroll
        for (int g = 0; g < 9; ++g) {
            int r = g / 3, c = g % 3;
            int iy = y + r - 1;
            int ix = xm + c - 1;
            bf8v a = {0,0,0,0,0,0,0,0};
            if ((unsigned)iy < 256u && (unsigned)ix < 256u)
                a = *reinterpret_cast<const bf8v*>(
                    in + ((((size_t)n * 256 + iy) * 256 + ix) * 32 + kc * 8));
            acc = __builtin_amdgcn_mfma_f32_16x16x32_bf16(a, bfrag[g], acc, 0, 0, 0);
        }
        if (cw) {
            float* op = out + ((size_t)(n * 3 + co) * 256 + y) * 256 + x0;
            #pragma unroll
            for (int r4 = 0; r4 < 4; ++r4) {
                int mm = kc * 4 + r4;
                float v = acc[r4] + bias;
                op[mm] = 1.f / (1.f + __expf(-v));
            }
        }
    }
}

// ============ VQ: argmin + q write (NHWC bf16, C padded to 32) + SSE + hist ============
__global__ __launch_bounds__(256)
void vq_k(const float* __restrict__ z, const float* __restrict__ emb,
          __hip_bfloat16* __restrict__ q, float* __restrict__ sse_acc,
          unsigned int* __restrict__ counts, int HW, int CHW)
{
    __shared__ float se[256 * 10];
    __shared__ unsigned int hist[256];
    __shared__ float wsum[4];
    int tid = threadIdx.x;
    for (int i = tid; i < 2560; i += 256) se[i] = emb[i];
    hist[tid] = 0u;
    __syncthreads();

    int pos = blockIdx.x * 256 + tid;
    int b = pos / HW;
    int sp = pos - b * HW;
    const float* zp = z + (size_t)b * CHW + sp;
    float zv[10];
    #pragma unroll
    for (int c = 0; c < 10; ++c) zv[c] = zp[(size_t)c * HW];

    float best = 3.4e38f;
    int bi = 0;
    for (int k = 0; k < 256; ++k) {
        const float* e = se + k * 10;
        float d = 0.f;
        #pragma unroll
        for (int c = 0; c < 10; ++c) { float t = zv[c] - e[c]; d = fmaf(t, t, d); }
        if (d < best) { best = d; bi = k; }
    }
    atomicAdd(&hist[bi], 1u);

    __hip_bfloat16* qp = q + (size_t)pos * 32;
    float lsse = 0.f;
    #pragma unroll
    for (int c = 0; c < 10; ++c) {
        float e = se[bi * 10 + c];
        qp[c] = __float2bfloat16(e);
        float t = e - zv[c];
        lsse = fmaf(t, t, lsse);
    }
    #pragma unroll
    for (int c = 10; c < 32; ++c) qp[c] = __float2bfloat16(0.f);

    #pragma unroll
    for (int off = 32; off > 0; off >>= 1) lsse += __shfl_down(lsse, off, 64);
    if ((tid & 63) == 0) wsum[tid >> 6] = lsse;
    __syncthreads();
    if (tid == 0) atomicAdd(sse_acc, wsum[0] + wsum[1] + wsum[2] + wsum[3]);
    atomicAdd(&counts[tid], hist[tid]);
}

__global__ __launch_bounds__(256)
void vq_finalize_k(const float* __restrict__ sse_acc, const unsigned int* __restrict__ counts,
                   float* __restrict__ out_loss, float* __restrict__ out_ppl,
                   float invNC, float invN)
{
    __shared__ float w4[4];
    int tid = threadIdx.x;
    float p = (float)counts[tid] * invN;
    float t = p * logf(p + 1e-10f);
    #pragma unroll
    for (int off = 32; off > 0; off >>= 1) t += __shfl_down(t, off, 64);
    if ((tid & 63) == 0) w4[tid >> 6] = t;
    __syncthreads();
    if (tid == 0) {
        float s = w4[0] + w4[1] + w4[2] + w4[3];
        *out_ppl  = expf(-s);
        *out_loss = 1.25f * sse_acc[0] * invNC;
    }
}

__global__ void zero_k(float* p, int n) {
    int i = blockIdx.x * 256 + threadIdx.x;
    if (i < n) p[i] = 0.f;
}

extern "C" void kernel_launch(void* const* d_in, const int* in_sizes, int n_in,
                              void* d_out, int out_size, void* d_ws, size_t ws_size,
                              hipStream_t stream) {
    const float* x      = (const float*)d_in[0];
    const float* enc_w1 = (const float*)d_in[1];
    const float* enc_b1 = (const float*)d_in[2];
    const float* bn1_g  = (const float*)d_in[3];
    const float* bn1_b  = (const float*)d_in[4];
    const float* bn1_m  = (const float*)d_in[5];
    const float* bn1_v  = (const float*)d_in[6];
    const float* enc_w2 = (const float*)d_in[7];
    const float* enc_b2 = (const float*)d_in[8];
    const float* bn2_g  = (const float*)d_in[9];
    const float* bn2_b  = (const float*)d_in[10];
    const float* bn2_m  = (const float*)d_in[11];
    const float* bn2_v  = (const float*)d_in[12];
    const float* enc_w3 = (const float*)d_in[13];
    const float* enc_b3 = (const float*)d_in[14];
    const float* bn3_g  = (const float*)d_in[15];
    const float* bn3_b  = (const float*)d_in[16];
    const float* bn3_m  = (const float*)d_in[17];
    const float* bn3_v  = (const float*)d_in[18];
    const float* emb    = (const float*)d_in[19];
    const float* dec_w1 = (const float*)d_in[20];
    const float* dec_b1 = (const float*)d_in[21];
    const float* dbn1_g = (const float*)d_in[22];
    const float* dbn1_b = (const float*)d_in[23];
    const float* dbn1_m = (const float*)d_in[24];
    const float* dbn1_v = (const float*)d_in[25];
    const float* dec_w2 = (const float*)d_in[26];
    const float* dec_b2 = (const float*)d_in[27];
    const float* dbn2_g = (const float*)d_in[28];
    const float* dbn2_b = (const float*)d_in[29];
    const float* dbn2_m = (const float*)d_in[30];
    const float* dbn2_v = (const float*)d_in[31];
    const float* dec_w3 = (const float*)d_in[32];
    const float* dec_b3 = (const float*)d_in[33];

    float* ws = (float*)d_ws;
    // workspace (float units); 16B alignment: every offset divisible by 4
    const size_t Z_OFF   = 0;            // z fp32 NCHW: 1,310,720
    const size_t SSE_OFF = 1310720;      // 1
    const size_t CNT_OFF = 1310721;      // 256 u32
    const size_t BP1_OFF = 1310980;      // deconv1 B-pack: 9,216 f (18,432 bf16)
    const size_t BP2_OFF = 1320196;      // deconv2 B-pack: 9,216 f
    const size_t BPO_OFF = 1329412;      // conv_out B-pack: 2,304 f
    const size_t Q_OFF   = 1331716;      // q NHWC bf16 C=32: 2,097,152 f
    const size_t RX_OFF  = 3428868;      // h1 fp32 NCHW 16,777,216 f | dd1 NHWC bf16 (same bytes)
    const size_t RY_OFF  = 20206084;     // h2 fp32 NCHW 8,388,608 f | dd2 NHWC bf16 33,554,432 f
    const size_t NEEDED_F = RY_OFF + 33554432;   // 53,760,516 f ~= 215 MB

    if (ws_size < NEEDED_F * sizeof(float)) return;

    float* zbuf = ws + Z_OFF;
    float* sse  = ws + SSE_OFF;
    unsigned int* counts = (unsigned int*)(ws + CNT_OFF);
    __hip_bfloat16* bp1 = (__hip_bfloat16*)(ws + BP1_OFF);
    __hip_bfloat16* bp2 = (__hip_bfloat16*)(ws + BP2_OFF);
    __hip_bfloat16* bpo = (__hip_bfloat16*)(ws + BPO_OFF);
    __hip_bfloat16* qbuf = (__hip_bfloat16*)(ws + Q_OFF);
    float* h1 = ws + RX_OFF;
    float* h2 = ws + RY_OFF;
    __hip_bfloat16* dd1 = (__hip_bfloat16*)(ws + RX_OFF);
    __hip_bfloat16* dd2 = (__hip_bfloat16*)(ws + RY_OFF);
    float* out = (float*)d_out;

    zero_k<<<2, 256, 0, stream>>>(ws + SSE_OFF, 257);
    pack_deconv_k<1><<<9, 256, 0, stream>>>(dec_w1, bp1);
    pack_deconv_k<2><<<9, 256, 0, stream>>>(dec_w2, bp2);
    pack_convout_k<<<3, 256, 0, stream>>>(dec_w3, bpo);

    // encoder (fp32 NCHW, unchanged)
    conv_t_k<3, 2, 32, 4, 4, 1, true><<<32 * 8 * 16, 256, 0, stream>>>(
        x, enc_w1, enc_b1, bn1_g, bn1_b, bn1_m, bn1_v, h1, 32, 256, 256, 128, 128, 8, 16, 1);
    conv_t_k<32, 2, 16, 4, 8, 1, true><<<32 * 8 * 4, 256, 0, stream>>>(
        h1, enc_w2, enc_b2, bn2_g, bn2_b, bn2_m, bn2_v, h2, 64, 128, 128, 64, 64, 8, 4, 1);
    conv_t_k<64, 1, 32, 2, 5, 0, true><<<32 * 2 * 8, 256, 0, stream>>>(
        h2, enc_w3, enc_b3, bn3_g, bn3_b, bn3_m, bn3_v, zbuf, 10, 64, 64, 64, 64, 2, 8, 1);

    // VQ (fp32 argmin; q written NHWC bf16 padded C=32)
    vq_k<<<131072 / 256, 256, 0, stream>>>(zbuf, emb, qbuf, sse, counts, 4096, 40960);

    // decoder (NHWC bf16 MFMA)
    // deconv1: waves = 4nt*4jt*32it*32n = 16384 -> 4096 blocks
    deconv_mfma_k<1, 2><<<4096, 256, 0, stream>>>(
        qbuf, bp1, dec_b1, dbn1_g, dbn1_b, dbn1_m, dbn1_v, dd1);
    // deconv2: waves = 2nt*8jt*64it*32n = 32768 -> 8192 blocks
    deconv_mfma_k<2, 2><<<8192, 256, 0, stream>>>(
        dd1, bp2, dec_b2, dbn2_g, dbn2_b, dbn2_m, dbn2_v, dd2);
    // conv_out: waves = 16xt*64yt*32n = 32768 -> 8192 blocks
    convout_mfma_k<<<8192, 256, 0, stream>>>(dd2, bpo, dec_b3, out);

    vq_finalize_k<<<1, 256, 0, stream>>>(sse, counts, out + 6291456, out + 6291457,
                                         1.f / 1310720.f, 1.f / 131072.f);
}

// Round 8
// 549.567 us; speedup vs baseline: 3.5630x; 2.3671x over previous
//
#include <hip/hip_runtime.h>
#include <hip/hip_bf16.h>
#include <math.h>

typedef __attribute__((ext_vector_type(8))) short bf8v;   // 8 bf16 in 4 VGPRs
typedef __attribute__((ext_vector_type(4))) float f4v;    // MFMA accumulator

__device__ __forceinline__ float bf2f(unsigned short u) {
    return __uint_as_float((unsigned)u << 16);
}
__device__ __forceinline__ void ld4f(const float* p, float* o) {
    float4 t = *(const float4*)p; o[0] = t.x; o[1] = t.y; o[2] = t.z; o[3] = t.w;
}

// ======================= conv1: 3->32 s2, VALU, NCHW fp32 -> NHWC bf16 =======================
__global__ __launch_bounds__(256, 2)
void conv1_k(const float* __restrict__ x, const float* __restrict__ w,
             const float* __restrict__ bconv,
             const float* __restrict__ bg, const float* __restrict__ bb,
             const float* __restrict__ bm, const float* __restrict__ bv,
             __hip_bfloat16* __restrict__ out)   // [32][128][128][32]
{
    __shared__ float sw[3 * 8 * 12];
    int b  = blockIdx.x;
    int yt = b & 15;
    int cg = (b >> 4) & 3;
    int n  = b >> 6;
    int co0 = cg * 8;
    int tid = threadIdx.x;
    for (int idx = tid; idx < 3 * 8 * 9; idx += 256) {
        int t = idx % 9; int rest = idx / 9;
        int cot = rest % 8; int ci = rest / 8;
        sw[(ci * 8 + cot) * 12 + t] = w[(((size_t)(co0 + cot) * 3) + ci) * 9 + t];
    }
    __syncthreads();

    int tx = tid & 31, ty = tid >> 5;
    int y  = yt * 8 + ty;
    int x0 = tx * 4;
    int iyb = 2 * y - 1;
    int ixb = 2 * x0 - 1;

    float acc[8][4];
    #pragma unroll
    for (int c = 0; c < 8; ++c)
        #pragma unroll
        for (int u = 0; u < 4; ++u) acc[c][u] = 0.f;

    for (int ci = 0; ci < 3; ++ci) {
        const float* ipc = x + ((size_t)n * 3 + ci) * 65536;
        float iv[3][9];
        #pragma unroll
        for (int r = 0; r < 3; ++r) {
            int iy = iyb + r;
            bool vy = (unsigned)iy < 256u;
            const float* row = ipc + (size_t)iy * 256;
            if (vy) {
                iv[r][0] = (ixb >= 0) ? row[ixb] : 0.f;
                ld4f(row + ixb + 1, &iv[r][1]);
                ld4f(row + ixb + 5, &iv[r][5]);
            } else {
                #pragma unroll
                for (int c = 0; c < 9; ++c) iv[r][c] = 0.f;
            }
        }
        #pragma unroll
        for (int cot = 0; cot < 8; ++cot) {
            const float4* wp4 = reinterpret_cast<const float4*>(&sw[(ci * 8 + cot) * 12]);
            float4 wa = wp4[0], wb = wp4[1], wc4 = wp4[2];
            float wreg[9] = {wa.x, wa.y, wa.z, wa.w, wb.x, wb.y, wb.z, wb.w, wc4.x};
            #pragma unroll
            for (int r = 0; r < 3; ++r)
                #pragma unroll
                for (int c = 0; c < 3; ++c)
                    #pragma unroll
                    for (int u = 0; u < 4; ++u)
                        acc[cot][u] = fmaf(iv[r][u * 2 + c], wreg[r * 3 + c], acc[cot][u]);
        }
    }

    float rs[8][4];
    #pragma unroll
    for (int cot = 0; cot < 8; ++cot) {
        int co = co0 + cot;
        float s = bg[co] * rsqrtf(bv[co] + 1e-5f);
        float bias = (bconv[co] - bm[co]) * s + bb[co];
        #pragma unroll
        for (int u = 0; u < 4; ++u) {
            float v = acc[cot][u] * s + bias;
            rs[cot][u] = (v >= 0.f) ? v : 0.1f * v;
        }
    }
    #pragma unroll
    for (int u = 0; u < 4; ++u) {
        union { __hip_bfloat162 h[4]; float4 f; } pk;
        #pragma unroll
        for (int p2 = 0; p2 < 4; ++p2)
            pk.h[p2] = __halves2bfloat162(__float2bfloat16(rs[2 * p2][u]),
                                          __float2bfloat16(rs[2 * p2 + 1][u]));
        *(float4*)(out + (((size_t)n * 128 + y) * 128 + (x0 + u)) * 32 + co0) = pk.f;
    }
}

// ======================= weight packs (B-fragment lane order) =======================
__global__ __launch_bounds__(256)
void pack_conv2_k(const float* __restrict__ w, __hip_bfloat16* __restrict__ bp)
{   // enc_w2 [64][32][3][3] -> frag[nt 0..3][g=tap 0..8][lane][8]
    int idx = blockIdx.x * 256 + threadIdx.x;
    if (idx >= 4 * 9 * 64) return;
    int lane = idx & 63;
    int g    = (idx >> 6) % 9;
    int nt   = idx / 576;
    int co   = nt * 16 + (lane & 15);
    __hip_bfloat16* o = bp + (size_t)idx * 8;
    for (int j = 0; j < 8; ++j) {
        int ci = (lane >> 4) * 8 + j;
        o[j] = __float2bfloat16(w[((size_t)co * 32 + ci) * 9 + g]);
    }
}

__global__ __launch_bounds__(256)
void pack_conv3_k(const float* __restrict__ w, __hip_bfloat16* __restrict__ bp)
{   // enc_w3 [10][64][3][3] -> frag[g = tap*2+cib, 0..17][lane][8], cols>=10 zero
    int idx = blockIdx.x * 256 + threadIdx.x;
    if (idx >= 18 * 64) return;
    int lane = idx & 63;
    int g    = idx >> 6;
    int tap  = g >> 1, cib = g & 1;
    int co   = lane & 15;
    __hip_bfloat16* o = bp + (size_t)idx * 8;
    for (int j = 0; j < 8; ++j) {
        int ci = cib * 32 + (lane >> 4) * 8 + j;
        float f = (co < 10) ? w[((size_t)co * 64 + ci) * 9 + tap] : 0.f;
        o[j] = __float2bfloat16(f);
    }
}

// ======================= conv2: 32->64 s2, MFMA, NHWC =======================
__global__ __launch_bounds__(256, 2)
void conv2_mfma_k(const __hip_bfloat16* __restrict__ in,      // [32][128][128][32]
                  const __hip_bfloat16* __restrict__ bpack,
                  const float* __restrict__ bconv,
                  const float* __restrict__ bg, const float* __restrict__ bb,
                  const float* __restrict__ bm, const float* __restrict__ bv,
                  __hip_bfloat16* __restrict__ out)           // [32][64][64][64]
{
    int lane = threadIdx.x & 63;
    int gw = blockIdx.x * 4 + (threadIdx.x >> 6);
    int nt = gw & 3;
    int xt = (gw >> 2) & 3;
    int yt = (gw >> 4) & 15;
    int n  = gw >> 8;
    int x0 = xt * 16;
    int m = lane & 15, kc = lane >> 4;

    bf8v bfrag[9];
    const bf8v* bpv = reinterpret_cast<const bf8v*>(bpack);
    #pragma unroll
    for (int g = 0; g < 9; ++g) bfrag[g] = bpv[((size_t)nt * 9 + g) * 64 + lane];

    int co = nt * 16 + m;
    float s = bg[co] * rsqrtf(bv[co] + 1e-5f);
    float bias = (bconv[co] - bm[co]) * s + bb[co];

    for (int t = 0; t < 4; ++t) {
        int y = yt * 4 + t;
        f4v acc = {0, 0, 0, 0};
        #pragma unroll
        for (int g = 0; g < 9; ++g) {
            int r = g / 3, c = g % 3;
            int iy = 2 * y + r - 1;
            int ix = 2 * (x0 + m) + c - 1;
            bf8v a = {0,0,0,0,0,0,0,0};
            if ((unsigned)iy < 128u && (unsigned)ix < 128u)
                a = *reinterpret_cast<const bf8v*>(
                    in + (((size_t)(n * 128 + iy)) * 128 + ix) * 32 + kc * 8);
            acc = __builtin_amdgcn_mfma_f32_16x16x32_bf16(a, bfrag[g], acc, 0, 0, 0);
        }
        #pragma unroll
        for (int rr = 0; rr < 4; ++rr) {
            int xx = x0 + kc * 4 + rr;
            float v = acc[rr] * s + bias;
            v = (v >= 0.f) ? v : 0.1f * v;
            out[(((size_t)(n * 64 + y)) * 64 + xx) * 64 + co] = __float2bfloat16(v);
        }
    }
}

// ======================= conv3: 64->10 s1, MFMA + BN, NHWC -> z fp32 NCHW =======================
__global__ __launch_bounds__(256, 2)
void conv3_mfma_k(const __hip_bfloat16* __restrict__ in,      // [32][64][64][64]
                  const __hip_bfloat16* __restrict__ bpack,
                  const float* __restrict__ bconv,
                  const float* __restrict__ bg, const float* __restrict__ bb,
                  const float* __restrict__ bm, const float* __restrict__ bv,
                  float* __restrict__ z)                      // [32][10][64][64]
{
    int lane = threadIdx.x & 63;
    int gw = blockIdx.x * 4 + (threadIdx.x >> 6);
    int xt = gw & 3;
    int yt = (gw >> 2) & 15;
    int n  = gw >> 6;
    int x0 = xt * 16;
    int m = lane & 15, kc = lane >> 4;

    bf8v bfrag[18];
    const bf8v* bpv = reinterpret_cast<const bf8v*>(bpack);
    #pragma unroll
    for (int g = 0; g < 18; ++g) bfrag[g] = bpv[(size_t)g * 64 + lane];

    int co = m;
    bool cw = (co < 10);
    float s = 0.f, bias = 0.f;
    if (cw) {
        s = bg[co] * rsqrtf(bv[co] + 1e-5f);
        bias = (bconv[co] - bm[co]) * s + bb[co];
    }

    for (int t = 0; t < 4; ++t) {
        int y = yt * 4 + t;
        f4v acc = {0, 0, 0, 0};
        #pragma unroll
        for (int g = 0; g < 18; ++g) {
            int tap = g >> 1, cib = g & 1;
            int r = tap / 3, c = tap % 3;
            int iy = y + r - 1;
            int ix = (x0 + m) + c - 1;
            bf8v a = {0,0,0,0,0,0,0,0};
            if ((unsigned)iy < 64u && (unsigned)ix < 64u)
                a = *reinterpret_cast<const bf8v*>(
                    in + (((size_t)(n * 64 + iy)) * 64 + ix) * 64 + cib * 32 + kc * 8);
            acc = __builtin_amdgcn_mfma_f32_16x16x32_bf16(a, bfrag[g], acc, 0, 0, 0);
        }
        if (cw) {
            #pragma unroll
            for (int rr = 0; rr < 4; ++rr) {
                int xx = x0 + kc * 4 + rr;
                z[(((size_t)n * 10 + co) << 12) + y * 64 + xx] = acc[rr] * s + bias;
            }
        }
    }
}

// ======================= decoder (unchanged from r7) =======================
struct DTab { int di[18]; int dj[18]; int wi[18]; int ci0[18]; int ph[18]; };
constexpr DTab TAB1 = {
    {0, 0,0, 1,0, 1,1,0,0,  0,0,0,0,0,0,0,0,0},
    {0, 1,0, 0,0, 1,0,1,0,  0,0,0,0,0,0,0,0,0},
    {4, 3,5, 1,7, 0,2,6,8,  0,0,0,0,0,0,0,0,0},
    {0, 0,0, 0,0, 0,0,0,0,  0,0,0,0,0,0,0,0,0},
    {0, 1,1, 2,2, 3,3,3,3,  0,0,0,0,0,0,0,0,0}};
constexpr DTab TAB2 = {
    {0,0,  0,0,0,0,  1,1,0,0,  1,1,1,1,0,0,0,0},
    {0,0,  1,1,0,0,  0,0,0,0,  1,1,0,0,1,1,0,0},
    {4,4,  3,3,5,5,  1,1,7,7,  0,0,2,2,6,6,8,8},
    {0,32, 0,32,0,32, 0,32,0,32, 0,32,0,32,0,32,0,32},
    {0,0,  1,1,1,1,  2,2,2,2,  3,3,3,3,3,3,3,3}};

template<int WHICH>
__global__ __launch_bounds__(256)
void pack_deconv_k(const float* __restrict__ w, __hip_bfloat16* __restrict__ bp)
{
    constexpr int NKS  = (WHICH == 1) ? 9 : 18;
    constexpr int COUT = (WHICH == 1) ? 64 : 32;
    constexpr int CINr = (WHICH == 1) ? 10 : 64;
    constexpr int NT   = COUT / 16;
    constexpr const DTab& T = (WHICH == 1) ? TAB1 : TAB2;
    int idx = blockIdx.x * 256 + threadIdx.x;
    if (idx >= NT * NKS * 64) return;
    int lane = idx & 63;
    int g    = (idx >> 6) % NKS;
    int nt   = idx / (64 * NKS);
    int co   = nt * 16 + (lane & 15);
    int wi   = T.wi[g], ci0 = T.ci0[g];
    __hip_bfloat16* o = bp + (size_t)idx * 8;
    for (int j = 0; j < 8; ++j) {
        int ci = ci0 + (lane >> 4) * 8 + j;
        float f = (ci < CINr) ? w[((size_t)ci * COUT + co) * 9 + wi] : 0.f;
        o[j] = __float2bfloat16(f);
    }
}

__global__ __launch_bounds__(256)
void pack_convout_k(const float* __restrict__ w, __hip_bfloat16* __restrict__ bp)
{
    int idx = blockIdx.x * 256 + threadIdx.x;
    if (idx >= 9 * 64) return;
    int lane = idx & 63;
    int g    = idx >> 6;
    int co   = lane & 15;
    __hip_bfloat16* o = bp + (size_t)idx * 8;
    for (int j = 0; j < 8; ++j) {
        int ci = (lane >> 4) * 8 + j;
        float f = (co < 3) ? w[((size_t)co * 32 + ci) * 9 + g] : 0.f;
        o[j] = __float2bfloat16(f);
    }
}

template<int WHICH, int I_T>
__global__ __launch_bounds__(256, 2)
void deconv_mfma_k(const __hip_bfloat16* __restrict__ in,
                   const __hip_bfloat16* __restrict__ bpack,
                   const float* __restrict__ bconv,
                   const float* __restrict__ bg, const float* __restrict__ bb,
                   const float* __restrict__ bm, const float* __restrict__ bv,
                   __hip_bfloat16* __restrict__ out)
{
    constexpr int NKS  = (WHICH == 1) ? 9 : 18;
    constexpr int CINP = (WHICH == 1) ? 32 : 64;
    constexpr int COUT = (WHICH == 1) ? 64 : 32;
    constexpr int NT   = COUT / 16;
    constexpr int HI   = (WHICH == 1) ? 64 : 128;
    constexpr int JT   = HI / 16;
    constexpr const DTab& T = (WHICH == 1) ? TAB1 : TAB2;

    int lane = threadIdx.x & 63;
    int gw = blockIdx.x * 4 + (threadIdx.x >> 6);
    int nt = gw % NT;  int mt = gw / NT;
    int jt = mt % JT;  mt /= JT;
    int it = mt % (HI / I_T);
    int n  = mt / (HI / I_T);
    int j0 = jt * 16;
    int m  = lane & 15, kc = lane >> 4;
    int jm = j0 + m;

    bf8v bfrag[NKS];
    const bf8v* bpv = reinterpret_cast<const bf8v*>(bpack);
    #pragma unroll
    for (int g = 0; g < NKS; ++g) bfrag[g] = bpv[((size_t)nt * NKS + g) * 64 + lane];

    int co = nt * 16 + m;
    float s = bg[co] * rsqrtf(bv[co] + 1e-5f);
    float bias = (bconv[co] - bm[co]) * s + bb[co];

    for (int t = 0; t < I_T; ++t) {
        int i = it * I_T + t;
        f4v acc[4] = {{0,0,0,0},{0,0,0,0},{0,0,0,0},{0,0,0,0}};
        #pragma unroll
        for (int g = 0; g < NKS; ++g) {
            int ii = i + T.di[g];
            int jj = jm + T.dj[g];
            bf8v a = {0,0,0,0,0,0,0,0};
            if (ii < HI && jj < HI)
                a = *reinterpret_cast<const bf8v*>(
                    in + ((((size_t)n * HI + ii) * HI + jj) * CINP + T.ci0[g] + kc * 8));
            acc[T.ph[g]] = __builtin_amdgcn_mfma_f32_16x16x32_bf16(
                a, bfrag[g], acc[T.ph[g]], 0, 0, 0);
        }
        #pragma unroll
        for (int p = 0; p < 4; ++p) {
            int py = p >> 1, px = p & 1;
            #pragma unroll
            for (int r = 0; r < 4; ++r) {
                int mm = kc * 4 + r;
                float v = acc[p][r] * s + bias;
                v = (v >= 0.f) ? v : 0.1f * v;
                int oy = 2 * i + py, ox = 2 * (j0 + mm) + px;
                out[(((size_t)n * (2 * HI) + oy) * (2 * HI) + ox) * COUT + co] =
                    __float2bfloat16(v);
            }
        }
    }
}

__global__ __launch_bounds__(256, 2)
void convout_mfma_k(const __hip_bfloat16* __restrict__ in,
                    const __hip_bfloat16* __restrict__ bpack,
                    const float* __restrict__ b3,
                    float* __restrict__ out)
{
    int lane = threadIdx.x & 63;
    int gw = blockIdx.x * 4 + (threadIdx.x >> 6);
    int xt = gw % 16; int rest = gw / 16;
    int yt = rest % 64;
    int n  = rest / 64;
    int x0 = xt * 16;
    int m = lane & 15, kc = lane >> 4;
    int xm = x0 + m;

    bf8v bfrag[9];
    #pragma unroll
    for (int g = 0; g < 9; ++g)
        bfrag[g] = reinterpret_cast<const bf8v*>(bpack)[g * 64 + lane];

    int co = lane & 15;
    bool cw = (co < 3);
    float bias = cw ? b3[co] : 0.f;

    for (int t = 0; t < 4; ++t) {
        int y = yt * 4 + t;
        f4v acc = {0, 0, 0, 0};
        #pragma unroll
        for (int g = 0; g < 9; ++g) {
            int r = g / 3, c = g % 3;
            int iy = y + r - 1;
            int ix = xm + c - 1;
            bf8v a = {0,0,0,0,0,0,0,0};
            if ((unsigned)iy < 256u && (unsigned)ix < 256u)
                a = *reinterpret_cast<const bf8v*>(
                    in + ((((size_t)n * 256 + iy) * 256 + ix) * 32 + kc * 8));
            acc = __builtin_amdgcn_mfma_f32_16x16x32_bf16(a, bfrag[g], acc, 0, 0, 0);
        }
        if (cw) {
            float* op = out + ((size_t)(n * 3 + co) * 256 + y) * 256 + x0;
            #pragma unroll
            for (int r4 = 0; r4 < 4; ++r4) {
                int mm = kc * 4 + r4;
                float v = acc[r4] + bias;
                op[mm] = 1.f / (1.f + __expf(-v));
            }
        }
    }
}

// ============ VQ (fp32 argmin) ============
__global__ __launch_bounds__(256)
void vq_k(const float* __restrict__ z, const float* __restrict__ emb,
          __hip_bfloat16* __restrict__ q, float* __restrict__ sse_acc,
          unsigned int* __restrict__ counts, int HW, int CHW)
{
    __shared__ float se[256 * 10];
    __shared__ unsigned int hist[256];
    __shared__ float wsum[4];
    int tid = threadIdx.x;
    for (int i = tid; i < 2560; i += 256) se[i] = emb[i];
    hist[tid] = 0u;
    __syncthreads();

    int pos = blockIdx.x * 256 + tid;
    int b = pos / HW;
    int sp = pos - b * HW;
    const float* zp = z + (size_t)b * CHW + sp;
    float zv[10];
    #pragma unroll
    for (int c = 0; c < 10; ++c) zv[c] = zp[(size_t)c * HW];

    float best = 3.4e38f;
    int bi = 0;
    for (int k = 0; k < 256; ++k) {
        const float* e = se + k * 10;
        float d = 0.f;
        #pragma unroll
        for (int c = 0; c < 10; ++c) { float t = zv[c] - e[c]; d = fmaf(t, t, d); }
        if (d < best) { best = d; bi = k; }
    }
    atomicAdd(&hist[bi], 1u);

    __hip_bfloat16* qp = q + (size_t)pos * 32;
    float lsse = 0.f;
    #pragma unroll
    for (int c = 0; c < 10; ++c) {
        float e = se[bi * 10 + c];
        qp[c] = __float2bfloat16(e);
        float t = e - zv[c];
        lsse = fmaf(t, t, lsse);
    }
    #pragma unroll
    for (int c = 10; c < 32; ++c) qp[c] = __float2bfloat16(0.f);

    #pragma unroll
    for (int off = 32; off > 0; off >>= 1) lsse += __shfl_down(lsse, off, 64);
    if ((tid & 63) == 0) wsum[tid >> 6] = lsse;
    __syncthreads();
    if (tid == 0) atomicAdd(sse_acc, wsum[0] + wsum[1] + wsum[2] + wsum[3]);
    atomicAdd(&counts[tid], hist[tid]);
}

__global__ __launch_bounds__(256)
void vq_finalize_k(const float* __restrict__ sse_acc, const unsigned int* __restrict__ counts,
                   float* __restrict__ out_loss, float* __restrict__ out_ppl,
                   float invNC, float invN)
{
    __shared__ float w4[4];
    int tid = threadIdx.x;
    float p = (float)counts[tid] * invN;
    float t = p * logf(p + 1e-10f);
    #pragma unroll
    for (int off = 32; off > 0; off >>= 1) t += __shfl_down(t, off, 64);
    if ((tid & 63) == 0) w4[tid >> 6] = t;
    __syncthreads();
    if (tid == 0) {
        float s = w4[0] + w4[1] + w4[2] + w4[3];
        *out_ppl  = expf(-s);
        *out_loss = 1.25f * sse_acc[0] * invNC;
    }
}

__global__ void zero_k(float* p, int n) {
    int i = blockIdx.x * 256 + threadIdx.x;
    if (i < n) p[i] = 0.f;
}

extern "C" void kernel_launch(void* const* d_in, const int* in_sizes, int n_in,
                              void* d_out, int out_size, void* d_ws, size_t ws_size,
                              hipStream_t stream) {
    const float* x      = (const float*)d_in[0];
    const float* enc_w1 = (const float*)d_in[1];
    const float* enc_b1 = (const float*)d_in[2];
    const float* bn1_g  = (const float*)d_in[3];
    const float* bn1_b  = (const float*)d_in[4];
    const float* bn1_m  = (const float*)d_in[5];
    const float* bn1_v  = (const float*)d_in[6];
    const float* enc_w2 = (const float*)d_in[7];
    const float* enc_b2 = (const float*)d_in[8];
    const float* bn2_g  = (const float*)d_in[9];
    const float* bn2_b  = (const float*)d_in[10];
    const float* bn2_m  = (const float*)d_in[11];
    const float* bn2_v  = (const float*)d_in[12];
    const float* enc_w3 = (const float*)d_in[13];
    const float* enc_b3 = (const float*)d_in[14];
    const float* bn3_g  = (const float*)d_in[15];
    const float* bn3_b  = (const float*)d_in[16];
    const float* bn3_m  = (const float*)d_in[17];
    const float* bn3_v  = (const float*)d_in[18];
    const float* emb    = (const float*)d_in[19];
    const float* dec_w1 = (const float*)d_in[20];
    const float* dec_b1 = (const float*)d_in[21];
    const float* dbn1_g = (const float*)d_in[22];
    const float* dbn1_b = (const float*)d_in[23];
    const float* dbn1_m = (const float*)d_in[24];
    const float* dbn1_v = (const float*)d_in[25];
    const float* dec_w2 = (const float*)d_in[26];
    const float* dec_b2 = (const float*)d_in[27];
    const float* dbn2_g = (const float*)d_in[28];
    const float* dbn2_b = (const float*)d_in[29];
    const float* dbn2_m = (const float*)d_in[30];
    const float* dbn2_v = (const float*)d_in[31];
    const float* dec_w3 = (const float*)d_in[32];
    const float* dec_b3 = (const float*)d_in[33];

    float* ws = (float*)d_ws;
    // workspace (float units), all offsets 16B-aligned
    const size_t SSE_OFF  = 0;           // 1 f (+3 pad)
    const size_t CNT_OFF  = 4;           // 256 u32
    const size_t BPC2_OFF = 260;         // conv2 pack: 9216 f
    const size_t BPC3_OFF = 9476;        // conv3 pack: 4608 f
    const size_t BP1_OFF  = 14084;       // deconv1 pack: 9216 f
    const size_t BP2_OFF  = 23300;       // deconv2 pack: 9216 f
    const size_t BPO_OFF  = 32516;       // convout pack: 2304 f
    const size_t Q_OFF    = 34820;       // q NHWC bf16 C=32: 2,097,152 f
    const size_t Z_OFF    = 2131972;     // z fp32 NCHW: 1,310,720 f
    const size_t H1_OFF   = 3442692;     // h1 NHWC bf16: 8,388,608 f
    const size_t H2_OFF   = 11831300;    // h2 NHWC bf16: 4,194,304 f
    const size_t DD2_OFF  = 2131972;     // dd2 NHWC bf16: 16,777,216 f (overlays z/h1/h2, dead)
    const size_t DD1_OFF  = 18909188;    // dd1 NHWC bf16: 16,777,216 f
    const size_t NEEDED_F = DD1_OFF + 16777216;   // 35,686,404 f ~= 143 MB

    if (ws_size < NEEDED_F * sizeof(float)) return;

    float* sse  = ws + SSE_OFF;
    unsigned int* counts = (unsigned int*)(ws + CNT_OFF);
    __hip_bfloat16* bpc2 = (__hip_bfloat16*)(ws + BPC2_OFF);
    __hip_bfloat16* bpc3 = (__hip_bfloat16*)(ws + BPC3_OFF);
    __hip_bfloat16* bp1  = (__hip_bfloat16*)(ws + BP1_OFF);
    __hip_bfloat16* bp2  = (__hip_bfloat16*)(ws + BP2_OFF);
    __hip_bfloat16* bpo  = (__hip_bfloat16*)(ws + BPO_OFF);
    __hip_bfloat16* qbuf = (__hip_bfloat16*)(ws + Q_OFF);
    float* zbuf = ws + Z_OFF;
    __hip_bfloat16* h1  = (__hip_bfloat16*)(ws + H1_OFF);
    __hip_bfloat16* h2  = (__hip_bfloat16*)(ws + H2_OFF);
    __hip_bfloat16* dd1 = (__hip_bfloat16*)(ws + DD1_OFF);
    __hip_bfloat16* dd2 = (__hip_bfloat16*)(ws + DD2_OFF);
    float* out = (float*)d_out;

    zero_k<<<2, 256, 0, stream>>>(ws, 260);
    pack_conv2_k<<<9, 256, 0, stream>>>(enc_w2, bpc2);
    pack_conv3_k<<<5, 256, 0, stream>>>(enc_w3, bpc3);
    pack_deconv_k<1><<<9, 256, 0, stream>>>(dec_w1, bp1);
    pack_deconv_k<2><<<9, 256, 0, stream>>>(dec_w2, bp2);
    pack_convout_k<<<3, 256, 0, stream>>>(dec_w3, bpo);

    // encoder (NHWC bf16)
    conv1_k<<<2048, 256, 0, stream>>>(x, enc_w1, enc_b1, bn1_g, bn1_b, bn1_m, bn1_v, h1);
    conv2_mfma_k<<<2048, 256, 0, stream>>>(h1, bpc2, enc_b2, bn2_g, bn2_b, bn2_m, bn2_v, h2);
    conv3_mfma_k<<<512, 256, 0, stream>>>(h2, bpc3, enc_b3, bn3_g, bn3_b, bn3_m, bn3_v, zbuf);

    // VQ (fp32 argmin on z; q written NHWC bf16 padded C=32)
    vq_k<<<512, 256, 0, stream>>>(zbuf, emb, qbuf, sse, counts, 4096, 40960);

    // decoder (NHWC bf16 MFMA)
    deconv_mfma_k<1, 2><<<4096, 256, 0, stream>>>(
        qbuf, bp1, dec_b1, dbn1_g, dbn1_b, dbn1_m, dbn1_v, dd1);
    deconv_mfma_k<2, 2><<<8192, 256, 0, stream>>>(
        dd1, bp2, dec_b2, dbn2_g, dbn2_b, dbn2_m, dbn2_v, dd2);
    convout_mfma_k<<<8192, 256, 0, stream>>>(dd2, bpo, dec_b3, out);

    vq_finalize_k<<<1, 256, 0, stream>>>(sse, counts, out + 6291456, out + 6291457,
                                         1.f / 1310720.f, 1.f / 131072.f);
}

// Round 9
// 480.287 us; speedup vs baseline: 4.0769x; 1.1442x over previous
//
#include <hip/hip_runtime.h>
#include <hip/hip_bf16.h>
#include <math.h>

typedef __attribute__((ext_vector_type(8))) short bf8v;   // 8 bf16 in 4 VGPRs
typedef __attribute__((ext_vector_type(4))) float f4v;    // MFMA accumulator
typedef const __hip_bfloat16* cbfp;

__device__ __forceinline__ void ld4f(const float* p, float* o) {
    float4 t = *(const float4*)p; o[0] = t.x; o[1] = t.y; o[2] = t.z; o[3] = t.w;
}

// ======================= conv1: 3->32 s2, VALU, NCHW fp32 -> NHWC bf16 =======================
__global__ __launch_bounds__(256, 2)
void conv1_k(const float* __restrict__ x, const float* __restrict__ w,
             const float* __restrict__ bconv,
             const float* __restrict__ bg, const float* __restrict__ bb,
             const float* __restrict__ bm, const float* __restrict__ bv,
             __hip_bfloat16* __restrict__ out)   // [32][128][128][32]
{
    __shared__ float sw[3 * 8 * 12];
    int b  = blockIdx.x;
    int yt = b & 15;
    int cg = (b >> 4) & 3;
    int n  = b >> 6;
    int co0 = cg * 8;
    int tid = threadIdx.x;
    for (int idx = tid; idx < 3 * 8 * 9; idx += 256) {
        int t = idx % 9; int rest = idx / 9;
        int cot = rest % 8; int ci = rest / 8;
        sw[(ci * 8 + cot) * 12 + t] = w[(((size_t)(co0 + cot) * 3) + ci) * 9 + t];
    }
    __syncthreads();

    int tx = tid & 31, ty = tid >> 5;
    int y  = yt * 8 + ty;
    int x0 = tx * 4;
    int iyb = 2 * y - 1;
    int ixb = 2 * x0 - 1;

    float acc[8][4];
    #pragma unroll
    for (int c = 0; c < 8; ++c)
        #pragma unroll
        for (int u = 0; u < 4; ++u) acc[c][u] = 0.f;

    for (int ci = 0; ci < 3; ++ci) {
        const float* ipc = x + ((size_t)n * 3 + ci) * 65536;
        float iv[3][9];
        #pragma unroll
        for (int r = 0; r < 3; ++r) {
            int iy = iyb + r;
            bool vy = (unsigned)iy < 256u;
            const float* row = ipc + (size_t)iy * 256;
            if (vy) {
                iv[r][0] = (ixb >= 0) ? row[ixb] : 0.f;
                ld4f(row + ixb + 1, &iv[r][1]);
                ld4f(row + ixb + 5, &iv[r][5]);
            } else {
                #pragma unroll
                for (int c = 0; c < 9; ++c) iv[r][c] = 0.f;
            }
        }
        #pragma unroll
        for (int cot = 0; cot < 8; ++cot) {
            const float4* wp4 = reinterpret_cast<const float4*>(&sw[(ci * 8 + cot) * 12]);
            float4 wa = wp4[0], wb = wp4[1], wc4 = wp4[2];
            float wreg[9] = {wa.x, wa.y, wa.z, wa.w, wb.x, wb.y, wb.z, wb.w, wc4.x};
            #pragma unroll
            for (int r = 0; r < 3; ++r)
                #pragma unroll
                for (int c = 0; c < 3; ++c)
                    #pragma unroll
                    for (int u = 0; u < 4; ++u)
                        acc[cot][u] = fmaf(iv[r][u * 2 + c], wreg[r * 3 + c], acc[cot][u]);
        }
    }

    float rs[8][4];
    #pragma unroll
    for (int cot = 0; cot < 8; ++cot) {
        int co = co0 + cot;
        float s = bg[co] * rsqrtf(bv[co] + 1e-5f);
        float bias = (bconv[co] - bm[co]) * s + bb[co];
        #pragma unroll
        for (int u = 0; u < 4; ++u) {
            float v = acc[cot][u] * s + bias;
            rs[cot][u] = (v >= 0.f) ? v : 0.1f * v;
        }
    }
    #pragma unroll
    for (int u = 0; u < 4; ++u) {
        union { __hip_bfloat162 h[4]; float4 f; } pk;
        #pragma unroll
        for (int p2 = 0; p2 < 4; ++p2)
            pk.h[p2] = __halves2bfloat162(__float2bfloat16(rs[2 * p2][u]),
                                          __float2bfloat16(rs[2 * p2 + 1][u]));
        *(float4*)(out + (((size_t)n * 128 + y) * 128 + (x0 + u)) * 32 + co0) = pk.f;
    }
}

// ======================= weight packs (A-fragment lane order: row=co) =======================
__global__ __launch_bounds__(256)
void pack_conv2_k(const float* __restrict__ w, __hip_bfloat16* __restrict__ bp)
{   // enc_w2 [64][32][3][3] -> frag[nt][g=tap][lane][8]
    int idx = blockIdx.x * 256 + threadIdx.x;
    if (idx >= 4 * 9 * 64) return;
    int lane = idx & 63;
    int g    = (idx >> 6) % 9;
    int nt   = idx / 576;
    int co   = nt * 16 + (lane & 15);
    __hip_bfloat16* o = bp + (size_t)idx * 8;
    for (int j = 0; j < 8; ++j) {
        int ci = (lane >> 4) * 8 + j;
        o[j] = __float2bfloat16(w[((size_t)co * 32 + ci) * 9 + g]);
    }
}

__global__ __launch_bounds__(256)
void pack_conv3_k(const float* __restrict__ w, __hip_bfloat16* __restrict__ bp)
{   // enc_w3 [10][64][3][3] -> frag[g = tap*2+cib][lane][8], rows>=10 zero
    int idx = blockIdx.x * 256 + threadIdx.x;
    if (idx >= 18 * 64) return;
    int lane = idx & 63;
    int g    = idx >> 6;
    int tap  = g >> 1, cib = g & 1;
    int co   = lane & 15;
    __hip_bfloat16* o = bp + (size_t)idx * 8;
    for (int j = 0; j < 8; ++j) {
        int ci = cib * 32 + (lane >> 4) * 8 + j;
        float f = (co < 10) ? w[((size_t)co * 64 + ci) * 9 + tap] : 0.f;
        o[j] = __float2bfloat16(f);
    }
}

struct DTab { int di[18]; int dj[18]; int wi[18]; int ci0[18]; int ph[18]; };
constexpr DTab TAB1 = {
    {0, 0,0, 1,0, 1,1,0,0,  0,0,0,0,0,0,0,0,0},
    {0, 1,0, 0,0, 1,0,1,0,  0,0,0,0,0,0,0,0,0},
    {4, 3,5, 1,7, 0,2,6,8,  0,0,0,0,0,0,0,0,0},
    {0, 0,0, 0,0, 0,0,0,0,  0,0,0,0,0,0,0,0,0},
    {0, 1,1, 2,2, 3,3,3,3,  0,0,0,0,0,0,0,0,0}};
constexpr DTab TAB2 = {
    {0,0,  0,0,0,0,  1,1,0,0,  1,1,1,1,0,0,0,0},
    {0,0,  1,1,0,0,  0,0,0,0,  1,1,0,0,1,1,0,0},
    {4,4,  3,3,5,5,  1,1,7,7,  0,0,2,2,6,6,8,8},
    {0,32, 0,32,0,32, 0,32,0,32, 0,32,0,32,0,32,0,32},
    {0,0,  1,1,1,1,  2,2,2,2,  3,3,3,3,3,3,3,3}};

template<int WHICH>
__global__ __launch_bounds__(256)
void pack_deconv_k(const float* __restrict__ w, __hip_bfloat16* __restrict__ bp)
{
    constexpr int NKS  = (WHICH == 1) ? 9 : 18;
    constexpr int COUT = (WHICH == 1) ? 64 : 32;
    constexpr int CINr = (WHICH == 1) ? 10 : 64;
    constexpr int NT   = COUT / 16;
    constexpr const DTab& T = (WHICH == 1) ? TAB1 : TAB2;
    int idx = blockIdx.x * 256 + threadIdx.x;
    if (idx >= NT * NKS * 64) return;
    int lane = idx & 63;
    int g    = (idx >> 6) % NKS;
    int nt   = idx / (64 * NKS);
    int co   = nt * 16 + (lane & 15);
    int wi   = T.wi[g], ci0 = T.ci0[g];
    __hip_bfloat16* o = bp + (size_t)idx * 8;
    for (int j = 0; j < 8; ++j) {
        int ci = ci0 + (lane >> 4) * 8 + j;
        float f = (ci < CINr) ? w[((size_t)ci * COUT + co) * 9 + wi] : 0.f;
        o[j] = __float2bfloat16(f);
    }
}

__global__ __launch_bounds__(256)
void pack_convout_k(const float* __restrict__ w, __hip_bfloat16* __restrict__ bp)
{
    int idx = blockIdx.x * 256 + threadIdx.x;
    if (idx >= 9 * 64) return;
    int lane = idx & 63;
    int g    = idx >> 6;
    int co   = lane & 15;
    __hip_bfloat16* o = bp + (size_t)idx * 8;
    for (int j = 0; j < 8; ++j) {
        int ci = (lane >> 4) * 8 + j;
        float f = (co < 3) ? w[((size_t)co * 32 + ci) * 9 + g] : 0.f;
        o[j] = __float2bfloat16(f);
    }
}

// ======================= conv2: 32->64 s2, MFMA (swapped), NHWC =======================
__global__ __launch_bounds__(256, 2)
void conv2_mfma_k(const __hip_bfloat16* __restrict__ in,      // [32][128][128][32]
                  const __hip_bfloat16* __restrict__ bpack,
                  const float* __restrict__ bconv,
                  const float* __restrict__ bg, const float* __restrict__ bb,
                  const float* __restrict__ bm, const float* __restrict__ bv,
                  __hip_bfloat16* __restrict__ out,           // [32][64][64][64]
                  cbfp zp)
{
    int lane = threadIdx.x & 63;
    int gw = blockIdx.x * 4 + (threadIdx.x >> 6);
    int nt = gw & 3;
    int xt = (gw >> 2) & 3;
    int yt = (gw >> 4) & 15;
    int n  = gw >> 8;
    int m = lane & 15, kc = lane >> 4;
    int xm = xt * 16 + m;

    bf8v bfrag[9];
    const bf8v* bpv = reinterpret_cast<const bf8v*>(bpack);
    #pragma unroll
    for (int g = 0; g < 9; ++g) bfrag[g] = bpv[((size_t)nt * 9 + g) * 64 + lane];

    int co0 = nt * 16 + kc * 4;
    float s4[4], b4[4];
    #pragma unroll
    for (int r = 0; r < 4; ++r) {
        int co = co0 + r;
        float s = bg[co] * rsqrtf(bv[co] + 1e-5f);
        s4[r] = s; b4[r] = (bconv[co] - bm[co]) * s + bb[co];
    }
    bool vc0 = (xm > 0);

    for (int t = 0; t < 4; ++t) {
        int y = yt * 4 + t;
        cbfp rb[3], pc0[3];
        #pragma unroll
        for (int r = 0; r < 3; ++r) {
            int iy = 2 * y + r - 1;
            bool vy = (unsigned)iy < 128u;
            rb[r]  = vy ? in + (((size_t)n * 128 + iy) * 128 + 2 * xm) * 32 + kc * 8 : zp;
            pc0[r] = vc0 ? rb[r] - 32 : zp;
        }
        bf8v av[9];
        #pragma unroll
        for (int g = 0; g < 9; ++g) {
            int r = g / 3, c = g % 3;
            cbfp pg = (c == 0) ? pc0[r] : rb[r];
            av[g] = *reinterpret_cast<const bf8v*>(pg + (c == 2 ? 32 : 0));
        }
        f4v acc = {0, 0, 0, 0};
        #pragma unroll
        for (int g = 0; g < 9; ++g)
            acc = __builtin_amdgcn_mfma_f32_16x16x32_bf16(bfrag[g], av[g], acc, 0, 0, 0);

        union { __hip_bfloat162 h[2]; float2 f; } pk;
        float v0 = acc[0] * s4[0] + b4[0]; v0 = v0 >= 0.f ? v0 : 0.1f * v0;
        float v1 = acc[1] * s4[1] + b4[1]; v1 = v1 >= 0.f ? v1 : 0.1f * v1;
        float v2 = acc[2] * s4[2] + b4[2]; v2 = v2 >= 0.f ? v2 : 0.1f * v2;
        float v3 = acc[3] * s4[3] + b4[3]; v3 = v3 >= 0.f ? v3 : 0.1f * v3;
        pk.h[0] = __halves2bfloat162(__float2bfloat16(v0), __float2bfloat16(v1));
        pk.h[1] = __halves2bfloat162(__float2bfloat16(v2), __float2bfloat16(v3));
        *(float2*)(out + (((size_t)n * 64 + y) * 64 + xm) * 64 + co0) = pk.f;
    }
}

// ======================= conv3: 64->10 s1, MFMA (swapped) -> z fp32 NCHW =======================
__global__ __launch_bounds__(256, 2)
void conv3_mfma_k(const __hip_bfloat16* __restrict__ in,      // [32][64][64][64]
                  const __hip_bfloat16* __restrict__ bpack,
                  const float* __restrict__ bconv,
                  const float* __restrict__ bg, const float* __restrict__ bb,
                  const float* __restrict__ bm, const float* __restrict__ bv,
                  float* __restrict__ z, cbfp zp)              // [32][10][64][64]
{
    __shared__ bf8v sB[18 * 64];
    const bf8v* bpv = reinterpret_cast<const bf8v*>(bpack);
    for (int idx = threadIdx.x; idx < 18 * 64; idx += 256) sB[idx] = bpv[idx];
    __syncthreads();

    int lane = threadIdx.x & 63;
    int gw = blockIdx.x * 4 + (threadIdx.x >> 6);
    int xt = gw & 3;
    int yt = (gw >> 2) & 15;
    int n  = gw >> 6;
    int m = lane & 15, kc = lane >> 4;
    int xm = xt * 16 + m;

    float s4[4], b4[4];
    #pragma unroll
    for (int r = 0; r < 4; ++r) {
        int co = kc * 4 + r;
        if (co < 10) {
            float s = bg[co] * rsqrtf(bv[co] + 1e-5f);
            s4[r] = s; b4[r] = (bconv[co] - bm[co]) * s + bb[co];
        } else { s4[r] = 0.f; b4[r] = 0.f; }
    }
    bool vc0 = (xm > 0), vc2 = (xm < 63);

    for (int t = 0; t < 4; ++t) {
        int y = yt * 4 + t;
        cbfp rb[3], pc0[3], pc2[3];
        #pragma unroll
        for (int r = 0; r < 3; ++r) {
            int iy = y + r - 1;
            bool vy = (unsigned)iy < 64u;
            rb[r]  = vy ? in + (((size_t)n * 64 + iy) * 64 + xm) * 64 + kc * 8 : zp;
            pc0[r] = vc0 ? rb[r] - 64 : zp;
            pc2[r] = vc2 ? rb[r] + 64 : zp;
        }
        bf8v av[18];
        #pragma unroll
        for (int g = 0; g < 18; ++g) {
            int tap = g >> 1, cib = g & 1;
            int r = tap / 3, c = tap % 3;
            cbfp pg = (c == 0) ? pc0[r] : ((c == 2) ? pc2[r] : rb[r]);
            av[g] = *reinterpret_cast<const bf8v*>(pg + cib * 32);
        }
        f4v acc = {0, 0, 0, 0};
        #pragma unroll
        for (int g = 0; g < 18; ++g)
            acc = __builtin_amdgcn_mfma_f32_16x16x32_bf16(sB[g * 64 + lane], av[g], acc, 0, 0, 0);

        #pragma unroll
        for (int r = 0; r < 4; ++r) {
            int co = kc * 4 + r;
            if (co < 10)
                z[(((size_t)n * 10 + co) << 12) + y * 64 + xm] = acc[r] * s4[r] + b4[r];
        }
    }
}

// =============== unified MFMA deconv (swapped), NHWC bf16 ===============
template<int WHICH, int I_T>
__global__ __launch_bounds__(256, 2)
void deconv_mfma_k(const __hip_bfloat16* __restrict__ in,
                   const __hip_bfloat16* __restrict__ bpack,
                   const float* __restrict__ bconv,
                   const float* __restrict__ bg, const float* __restrict__ bb,
                   const float* __restrict__ bm, const float* __restrict__ bv,
                   __hip_bfloat16* __restrict__ out, cbfp zp)
{
    constexpr int NKS  = (WHICH == 1) ? 9 : 18;
    constexpr int CINP = (WHICH == 1) ? 32 : 64;
    constexpr int COUT = (WHICH == 1) ? 64 : 32;
    constexpr int NT   = COUT / 16;
    constexpr int HI   = (WHICH == 1) ? 64 : 128;
    constexpr int HO   = HI * 2;
    constexpr int JT   = HI / 16;
    constexpr const DTab& T = (WHICH == 1) ? TAB1 : TAB2;

    __shared__ bf8v sB[(WHICH == 2) ? NT * NKS * 64 : 1];
    const bf8v* bpv = reinterpret_cast<const bf8v*>(bpack);
    if constexpr (WHICH == 2) {
        for (int idx = threadIdx.x; idx < NT * NKS * 64; idx += 256) sB[idx] = bpv[idx];
        __syncthreads();
    }

    int lane = threadIdx.x & 63;
    int gw = blockIdx.x * 4 + (threadIdx.x >> 6);
    int nt = gw % NT;  int mt = gw / NT;
    int jt = mt % JT;  mt /= JT;
    int it = mt % (HI / I_T);
    int n  = mt / (HI / I_T);
    int j0 = jt * 16;
    int m  = lane & 15, kc = lane >> 4;
    int jm = j0 + m;

    bf8v bfrag[(WHICH == 1) ? NKS : 1];
    if constexpr (WHICH == 1) {
        #pragma unroll
        for (int g = 0; g < NKS; ++g) bfrag[g] = bpv[((size_t)nt * NKS + g) * 64 + lane];
    }

    int co0 = nt * 16 + kc * 4;
    float s4[4], b4[4];
    #pragma unroll
    for (int r = 0; r < 4; ++r) {
        int co = co0 + r;
        float s = bg[co] * rsqrtf(bv[co] + 1e-5f);
        s4[r] = s; b4[r] = (bconv[co] - bm[co]) * s + bb[co];
    }
    bool vj = (jm + 1) < HI;

    for (int t = 0; t < I_T; ++t) {
        int i = it * I_T + t;
        bool vi = (i + 1) < HI;
        cbfp p00 = in + (((size_t)n * HI + i) * HI + jm) * CINP + kc * 8;
        cbfp p01 = vj ? p00 + CINP : zp;
        cbfp p10 = vi ? p00 + (size_t)HI * CINP : zp;
        cbfp p11 = (vi && vj) ? p00 + (size_t)(HI + 1) * CINP : zp;

        bf8v av[NKS];
        #pragma unroll
        for (int g = 0; g < NKS; ++g) {
            cbfp pg = T.di[g] ? (T.dj[g] ? p11 : p10) : (T.dj[g] ? p01 : p00);
            av[g] = *reinterpret_cast<const bf8v*>(pg + T.ci0[g]);
        }
        f4v acc[4] = {{0,0,0,0},{0,0,0,0},{0,0,0,0},{0,0,0,0}};
        #pragma unroll
        for (int g = 0; g < NKS; ++g) {
            bf8v bw;
            if constexpr (WHICH == 2) bw = sB[(nt * NKS + g) * 64 + lane];
            else                      bw = bfrag[g];
            acc[T.ph[g]] = __builtin_amdgcn_mfma_f32_16x16x32_bf16(bw, av[g], acc[T.ph[g]], 0, 0, 0);
        }

        __hip_bfloat16* ob = out + (((size_t)n * HO + 2 * i) * HO + 2 * jm) * COUT + co0;
        #pragma unroll
        for (int p = 0; p < 4; ++p) {
            int py = p >> 1, px = p & 1;
            float v0 = acc[p][0] * s4[0] + b4[0]; v0 = v0 >= 0.f ? v0 : 0.1f * v0;
            float v1 = acc[p][1] * s4[1] + b4[1]; v1 = v1 >= 0.f ? v1 : 0.1f * v1;
            float v2 = acc[p][2] * s4[2] + b4[2]; v2 = v2 >= 0.f ? v2 : 0.1f * v2;
            float v3 = acc[p][3] * s4[3] + b4[3]; v3 = v3 >= 0.f ? v3 : 0.1f * v3;
            union { __hip_bfloat162 h[2]; float2 f; } pk;
            pk.h[0] = __halves2bfloat162(__float2bfloat16(v0), __float2bfloat16(v1));
            pk.h[1] = __halves2bfloat162(__float2bfloat16(v2), __float2bfloat16(v3));
            *(float2*)(ob + ((size_t)py * HO + px) * COUT) = pk.f;
        }
    }
}

// ======================= conv_out: 32->3 s1 + sigmoid (swapped) =======================
__global__ __launch_bounds__(256, 2)
void convout_mfma_k(const __hip_bfloat16* __restrict__ in,    // [32][256][256][32]
                    const __hip_bfloat16* __restrict__ bpack,
                    const float* __restrict__ b3,
                    float* __restrict__ out, cbfp zp)
{
    int lane = threadIdx.x & 63;
    int gw = blockIdx.x * 4 + (threadIdx.x >> 6);
    int xt = gw & 15;
    int yt = (gw >> 4) & 63;
    int n  = gw >> 10;
    int m = lane & 15, kc = lane >> 4;
    int xm = xt * 16 + m;

    bf8v bfrag[9];
    #pragma unroll
    for (int g = 0; g < 9; ++g)
        bfrag[g] = reinterpret_cast<const bf8v*>(bpack)[g * 64 + lane];

    float bias0 = b3[0], bias1 = b3[1], bias2 = b3[2];
    bool vc0 = (xm > 0), vc2 = (xm < 255);

    for (int t = 0; t < 4; ++t) {
        int y = yt * 4 + t;
        cbfp rb[3], pc0[3], pc2[3];
        #pragma unroll
        for (int r = 0; r < 3; ++r) {
            int iy = y + r - 1;
            bool vy = (unsigned)iy < 256u;
            rb[r]  = vy ? in + (((size_t)n * 256 + iy) * 256 + xm) * 32 + kc * 8 : zp;
            pc0[r] = vc0 ? rb[r] - 32 : zp;
            pc2[r] = vc2 ? rb[r] + 32 : zp;
        }
        bf8v av[9];
        #pragma unroll
        for (int g = 0; g < 9; ++g) {
            int r = g / 3, c = g % 3;
            cbfp pg = (c == 0) ? pc0[r] : ((c == 2) ? pc2[r] : rb[r]);
            av[g] = *reinterpret_cast<const bf8v*>(pg);
        }
        f4v acc = {0, 0, 0, 0};
        #pragma unroll
        for (int g = 0; g < 9; ++g)
            acc = __builtin_amdgcn_mfma_f32_16x16x32_bf16(bfrag[g], av[g], acc, 0, 0, 0);

        if (kc == 0) {
            size_t ybase = ((size_t)n * 3) * 65536 + (size_t)y * 256 + xm;
            float v0 = acc[0] + bias0;
            float v1 = acc[1] + bias1;
            float v2 = acc[2] + bias2;
            out[ybase]             = 1.f / (1.f + __expf(-v0));
            out[ybase + 65536]     = 1.f / (1.f + __expf(-v1));
            out[ybase + 131072]    = 1.f / (1.f + __expf(-v2));
        }
    }
}

// ============ VQ (fp32 argmin) ============
__global__ __launch_bounds__(256)
void vq_k(const float* __restrict__ z, const float* __restrict__ emb,
          __hip_bfloat16* __restrict__ q, float* __restrict__ sse_acc,
          unsigned int* __restrict__ counts, int HW, int CHW)
{
    __shared__ float se[256 * 10];
    __shared__ unsigned int hist[256];
    __shared__ float wsum[4];
    int tid = threadIdx.x;
    for (int i = tid; i < 2560; i += 256) se[i] = emb[i];
    hist[tid] = 0u;
    __syncthreads();

    int pos = blockIdx.x * 256 + tid;
    int b = pos / HW;
    int sp = pos - b * HW;
    const float* zpz = z + (size_t)b * CHW + sp;
    float zv[10];
    #pragma unroll
    for (int c = 0; c < 10; ++c) zv[c] = zpz[(size_t)c * HW];

    float best = 3.4e38f;
    int bi = 0;
    for (int k = 0; k < 256; ++k) {
        const float* e = se + k * 10;
        float d = 0.f;
        #pragma unroll
        for (int c = 0; c < 10; ++c) { float t = zv[c] - e[c]; d = fmaf(t, t, d); }
        if (d < best) { best = d; bi = k; }
    }
    atomicAdd(&hist[bi], 1u);

    __hip_bfloat16* qp = q + (size_t)pos * 32;
    float lsse = 0.f;
    #pragma unroll
    for (int c = 0; c < 10; ++c) {
        float e = se[bi * 10 + c];
        qp[c] = __float2bfloat16(e);
        float t = e - zv[c];
        lsse = fmaf(t, t, lsse);
    }
    #pragma unroll
    for (int c = 10; c < 32; ++c) qp[c] = __float2bfloat16(0.f);

    #pragma unroll
    for (int off = 32; off > 0; off >>= 1) lsse += __shfl_down(lsse, off, 64);
    if ((tid & 63) == 0) wsum[tid >> 6] = lsse;
    __syncthreads();
    if (tid == 0) atomicAdd(sse_acc, wsum[0] + wsum[1] + wsum[2] + wsum[3]);
    atomicAdd(&counts[tid], hist[tid]);
}

__global__ __launch_bounds__(256)
void vq_finalize_k(const float* __restrict__ sse_acc, const unsigned int* __restrict__ counts,
                   float* __restrict__ out_loss, float* __restrict__ out_ppl,
                   float invNC, float invN)
{
    __shared__ float w4[4];
    int tid = threadIdx.x;
    float p = (float)counts[tid] * invN;
    float t = p * logf(p + 1e-10f);
    #pragma unroll
    for (int off = 32; off > 0; off >>= 1) t += __shfl_down(t, off, 64);
    if ((tid & 63) == 0) w4[tid >> 6] = t;
    __syncthreads();
    if (tid == 0) {
        float s = w4[0] + w4[1] + w4[2] + w4[3];
        *out_ppl  = expf(-s);
        *out_loss = 1.25f * sse_acc[0] * invNC;
    }
}

__global__ void zero_k(float* p, int n) {
    int i = blockIdx.x * 256 + threadIdx.x;
    if (i < n) p[i] = 0.f;
}

extern "C" void kernel_launch(void* const* d_in, const int* in_sizes, int n_in,
                              void* d_out, int out_size, void* d_ws, size_t ws_size,
                              hipStream_t stream) {
    const float* x      = (const float*)d_in[0];
    const float* enc_w1 = (const float*)d_in[1];
    const float* enc_b1 = (const float*)d_in[2];
    const float* bn1_g  = (const float*)d_in[3];
    const float* bn1_b  = (const float*)d_in[4];
    const float* bn1_m  = (const float*)d_in[5];
    const float* bn1_v  = (const float*)d_in[6];
    const float* enc_w2 = (const float*)d_in[7];
    const float* enc_b2 = (const float*)d_in[8];
    const float* bn2_g  = (const float*)d_in[9];
    const float* bn2_b  = (const float*)d_in[10];
    const float* bn2_m  = (const float*)d_in[11];
    const float* bn2_v  = (const float*)d_in[12];
    const float* enc_w3 = (const float*)d_in[13];
    const float* enc_b3 = (const float*)d_in[14];
    const float* bn3_g  = (const float*)d_in[15];
    const float* bn3_b  = (const float*)d_in[16];
    const float* bn3_m  = (const float*)d_in[17];
    const float* bn3_v  = (const float*)d_in[18];
    const float* emb    = (const float*)d_in[19];
    const float* dec_w1 = (const float*)d_in[20];
    const float* dec_b1 = (const float*)d_in[21];
    const float* dbn1_g = (const float*)d_in[22];
    const float* dbn1_b = (const float*)d_in[23];
    const float* dbn1_m = (const float*)d_in[24];
    const float* dbn1_v = (const float*)d_in[25];
    const float* dec_w2 = (const float*)d_in[26];
    const float* dec_b2 = (const float*)d_in[27];
    const float* dbn2_g = (const float*)d_in[28];
    const float* dbn2_b = (const float*)d_in[29];
    const float* dbn2_m = (const float*)d_in[30];
    const float* dbn2_v = (const float*)d_in[31];
    const float* dec_w3 = (const float*)d_in[32];
    const float* dec_b3 = (const float*)d_in[33];

    float* ws = (float*)d_ws;
    // workspace (float units), all 16B-aligned
    const size_t SSE_OFF  = 0;           // 1 f
    const size_t CNT_OFF  = 4;           // 256 u32
    const size_t ZP_OFF   = 260;         // 256 f zero page (1 KB)
    const size_t BPC2_OFF = 516;         // conv2 pack: 9216 f
    const size_t BPC3_OFF = 9732;        // conv3 pack: 4608 f
    const size_t BP1_OFF  = 14340;       // deconv1 pack: 9216 f
    const size_t BP2_OFF  = 23556;       // deconv2 pack: 9216 f
    const size_t BPO_OFF  = 32772;       // convout pack: 2304 f
    const size_t Q_OFF    = 35076;       // q NHWC bf16 C=32: 2,097,152 f
    const size_t Z_OFF    = 2132228;     // z fp32 NCHW: 1,310,720 f
    const size_t H1_OFF   = 3442948;     // h1 NHWC bf16: 8,388,608 f
    const size_t H2_OFF   = 11831556;    // h2 NHWC bf16: 4,194,304 f
    const size_t DD2_OFF  = 2132228;     // dd2 bf16 16,777,216 f (overlays z/h1/h2, dead)
    const size_t DD1_OFF  = 18909444;    // dd1 bf16 16,777,216 f
    const size_t NEEDED_F = DD1_OFF + 16777216;   // ~143 MB

    if (ws_size < NEEDED_F * sizeof(float)) return;

    float* sse  = ws + SSE_OFF;
    unsigned int* counts = (unsigned int*)(ws + CNT_OFF);
    cbfp zp = (cbfp)(ws + ZP_OFF + 128);   // middle of zero page, +/-512B margin
    __hip_bfloat16* bpc2 = (__hip_bfloat16*)(ws + BPC2_OFF);
    __hip_bfloat16* bpc3 = (__hip_bfloat16*)(ws + BPC3_OFF);
    __hip_bfloat16* bp1  = (__hip_bfloat16*)(ws + BP1_OFF);
    __hip_bfloat16* bp2  = (__hip_bfloat16*)(ws + BP2_OFF);
    __hip_bfloat16* bpo  = (__hip_bfloat16*)(ws + BPO_OFF);
    __hip_bfloat16* qbuf = (__hip_bfloat16*)(ws + Q_OFF);
    float* zbuf = ws + Z_OFF;
    __hip_bfloat16* h1  = (__hip_bfloat16*)(ws + H1_OFF);
    __hip_bfloat16* h2  = (__hip_bfloat16*)(ws + H2_OFF);
    __hip_bfloat16* dd1 = (__hip_bfloat16*)(ws + DD1_OFF);
    __hip_bfloat16* dd2 = (__hip_bfloat16*)(ws + DD2_OFF);
    float* out = (float*)d_out;

    zero_k<<<3, 256, 0, stream>>>(ws, 516);
    pack_conv2_k<<<9, 256, 0, stream>>>(enc_w2, bpc2);
    pack_conv3_k<<<5, 256, 0, stream>>>(enc_w3, bpc3);
    pack_deconv_k<1><<<9, 256, 0, stream>>>(dec_w1, bp1);
    pack_deconv_k<2><<<9, 256, 0, stream>>>(dec_w2, bp2);
    pack_convout_k<<<3, 256, 0, stream>>>(dec_w3, bpo);

    // encoder
    conv1_k<<<2048, 256, 0, stream>>>(x, enc_w1, enc_b1, bn1_g, bn1_b, bn1_m, bn1_v, h1);
    conv2_mfma_k<<<2048, 256, 0, stream>>>(h1, bpc2, enc_b2, bn2_g, bn2_b, bn2_m, bn2_v, h2, zp);
    conv3_mfma_k<<<512, 256, 0, stream>>>(h2, bpc3, enc_b3, bn3_g, bn3_b, bn3_m, bn3_v, zbuf, zp);

    // VQ
    vq_k<<<512, 256, 0, stream>>>(zbuf, emb, qbuf, sse, counts, 4096, 40960);

    // decoder
    deconv_mfma_k<1, 2><<<4096, 256, 0, stream>>>(
        qbuf, bp1, dec_b1, dbn1_g, dbn1_b, dbn1_m, dbn1_v, dd1, zp);
    deconv_mfma_k<2, 2><<<8192, 256, 0, stream>>>(
        dd1, bp2, dec_b2, dbn2_g, dbn2_b, dbn2_m, dbn2_v, dd2, zp);
    convout_mfma_k<<<8192, 256, 0, stream>>>(dd2, bpo, dec_b3, out, zp);

    vq_finalize_k<<<1, 256, 0, stream>>>(sse, counts, out + 6291456, out + 6291457,
                                         1.f / 1310720.f, 1.f / 131072.f);
}

// Round 11
// 469.605 us; speedup vs baseline: 4.1697x; 1.0227x over previous
//
#include <hip/hip_runtime.h>
#include <hip/hip_bf16.h>
#include <math.h>

typedef __attribute__((ext_vector_type(8))) short bf8v;   // 8 bf16 in 4 VGPRs
typedef __attribute__((ext_vector_type(4))) float f4v;    // MFMA accumulator
typedef const __hip_bfloat16* cbfp;

__device__ __forceinline__ void ld4f(const float* p, float* o) {
    float4 t = *(const float4*)p; o[0] = t.x; o[1] = t.y; o[2] = t.z; o[3] = t.w;
}

// ======================= conv1: 3->32 s2, VALU, NCHW fp32 -> NHWC bf16 =======================
__global__ __launch_bounds__(256, 2)
void conv1_k(const float* __restrict__ x, const float* __restrict__ w,
             const float* __restrict__ bconv,
             const float* __restrict__ bg, const float* __restrict__ bb,
             const float* __restrict__ bm, const float* __restrict__ bv,
             __hip_bfloat16* __restrict__ out)   // [32][128][128][32]
{
    __shared__ float sw[3 * 8 * 12];
    int b  = blockIdx.x;
    int yt = b & 15;
    int cg = (b >> 4) & 3;
    int n  = b >> 6;
    int co0 = cg * 8;
    int tid = threadIdx.x;
    for (int idx = tid; idx < 3 * 8 * 9; idx += 256) {
        int t = idx % 9; int rest = idx / 9;
        int cot = rest % 8; int ci = rest / 8;
        sw[(ci * 8 + cot) * 12 + t] = w[(((size_t)(co0 + cot) * 3) + ci) * 9 + t];
    }
    __syncthreads();

    int tx = tid & 31, ty = tid >> 5;
    int y  = yt * 8 + ty;
    int x0 = tx * 4;
    int iyb = 2 * y - 1;
    int ixb = 2 * x0 - 1;

    float acc[8][4];
    #pragma unroll
    for (int c = 0; c < 8; ++c)
        #pragma unroll
        for (int u = 0; u < 4; ++u) acc[c][u] = 0.f;

    for (int ci = 0; ci < 3; ++ci) {
        const float* ipc = x + ((size_t)n * 3 + ci) * 65536;
        float iv[3][9];
        #pragma unroll
        for (int r = 0; r < 3; ++r) {
            int iy = iyb + r;
            bool vy = (unsigned)iy < 256u;
            const float* row = ipc + (size_t)iy * 256;
            if (vy) {
                iv[r][0] = (ixb >= 0) ? row[ixb] : 0.f;
                ld4f(row + ixb + 1, &iv[r][1]);
                ld4f(row + ixb + 5, &iv[r][5]);
            } else {
                #pragma unroll
                for (int c = 0; c < 9; ++c) iv[r][c] = 0.f;
            }
        }
        #pragma unroll
        for (int cot = 0; cot < 8; ++cot) {
            const float4* wp4 = reinterpret_cast<const float4*>(&sw[(ci * 8 + cot) * 12]);
            float4 wa = wp4[0], wb = wp4[1], wc4 = wp4[2];
            float wreg[9] = {wa.x, wa.y, wa.z, wa.w, wb.x, wb.y, wb.z, wb.w, wc4.x};
            #pragma unroll
            for (int r = 0; r < 3; ++r)
                #pragma unroll
                for (int c = 0; c < 3; ++c)
                    #pragma unroll
                    for (int u = 0; u < 4; ++u)
                        acc[cot][u] = fmaf(iv[r][u * 2 + c], wreg[r * 3 + c], acc[cot][u]);
        }
    }

    float rs[8][4];
    #pragma unroll
    for (int cot = 0; cot < 8; ++cot) {
        int co = co0 + cot;
        float s = bg[co] * rsqrtf(bv[co] + 1e-5f);
        float bias = (bconv[co] - bm[co]) * s + bb[co];
        #pragma unroll
        for (int u = 0; u < 4; ++u) {
            float v = acc[cot][u] * s + bias;
            rs[cot][u] = (v >= 0.f) ? v : 0.1f * v;
        }
    }
    #pragma unroll
    for (int u = 0; u < 4; ++u) {
        union { __hip_bfloat162 h[4]; float4 f; } pk;
        #pragma unroll
        for (int p2 = 0; p2 < 4; ++p2)
            pk.h[p2] = __halves2bfloat162(__float2bfloat16(rs[2 * p2][u]),
                                          __float2bfloat16(rs[2 * p2 + 1][u]));
        *(float4*)(out + (((size_t)n * 128 + y) * 128 + (x0 + u)) * 32 + co0) = pk.f;
    }
}

// ======================= weight packs (A-fragment lane order: row=co) =======================
__global__ __launch_bounds__(256)
void pack_conv2_k(const float* __restrict__ w, __hip_bfloat16* __restrict__ bp)
{   // enc_w2 [64][32][3][3] -> frag[nt][g=tap][lane][8]
    int idx = blockIdx.x * 256 + threadIdx.x;
    if (idx >= 4 * 9 * 64) return;
    int lane = idx & 63;
    int g    = (idx >> 6) % 9;
    int nt   = idx / 576;
    int co   = nt * 16 + (lane & 15);
    __hip_bfloat16* o = bp + (size_t)idx * 8;
    for (int j = 0; j < 8; ++j) {
        int ci = (lane >> 4) * 8 + j;
        o[j] = __float2bfloat16(w[((size_t)co * 32 + ci) * 9 + g]);
    }
}

__global__ __launch_bounds__(256)
void pack_conv3_k(const float* __restrict__ w, __hip_bfloat16* __restrict__ bp)
{   // enc_w3 [10][64][3][3] -> frag[g = tap*2+cib][lane][8], rows>=10 zero
    int idx = blockIdx.x * 256 + threadIdx.x;
    if (idx >= 18 * 64) return;
    int lane = idx & 63;
    int g    = idx >> 6;
    int tap  = g >> 1, cib = g & 1;
    int co   = lane & 15;
    __hip_bfloat16* o = bp + (size_t)idx * 8;
    for (int j = 0; j < 8; ++j) {
        int ci = cib * 32 + (lane >> 4) * 8 + j;
        float f = (co < 10) ? w[((size_t)co * 64 + ci) * 9 + tap] : 0.f;
        o[j] = __float2bfloat16(f);
    }
}

struct DTab { int di[18]; int dj[18]; int wi[18]; int ci0[18]; int ph[18]; };
constexpr DTab TAB1 = {
    {0, 0,0, 1,0, 1,1,0,0,  0,0,0,0,0,0,0,0,0},
    {0, 1,0, 0,0, 1,0,1,0,  0,0,0,0,0,0,0,0,0},
    {4, 3,5, 1,7, 0,2,6,8,  0,0,0,0,0,0,0,0,0},
    {0, 0,0, 0,0, 0,0,0,0,  0,0,0,0,0,0,0,0,0},
    {0, 1,1, 2,2, 3,3,3,3,  0,0,0,0,0,0,0,0,0}};
constexpr DTab TAB2 = {
    {0,0,  0,0,0,0,  1,1,0,0,  1,1,1,1,0,0,0,0},
    {0,0,  1,1,0,0,  0,0,0,0,  1,1,0,0,1,1,0,0},
    {4,4,  3,3,5,5,  1,1,7,7,  0,0,2,2,6,6,8,8},
    {0,32, 0,32,0,32, 0,32,0,32, 0,32,0,32,0,32,0,32},
    {0,0,  1,1,1,1,  2,2,2,2,  3,3,3,3,3,3,3,3}};

template<int WHICH>
__global__ __launch_bounds__(256)
void pack_deconv_k(const float* __restrict__ w, __hip_bfloat16* __restrict__ bp)
{
    constexpr int NKS  = (WHICH == 1) ? 9 : 18;
    constexpr int COUT = (WHICH == 1) ? 64 : 32;
    constexpr int CINr = (WHICH == 1) ? 10 : 64;
    constexpr int NT   = COUT / 16;
    constexpr const DTab& T = (WHICH == 1) ? TAB1 : TAB2;
    int idx = blockIdx.x * 256 + threadIdx.x;
    if (idx >= NT * NKS * 64) return;
    int lane = idx & 63;
    int g    = (idx >> 6) % NKS;
    int nt   = idx / (64 * NKS);
    int co   = nt * 16 + (lane & 15);
    int wi   = T.wi[g], ci0 = T.ci0[g];
    __hip_bfloat16* o = bp + (size_t)idx * 8;
    for (int j = 0; j < 8; ++j) {
        int ci = ci0 + (lane >> 4) * 8 + j;
        float f = (ci < CINr) ? w[((size_t)ci * COUT + co) * 9 + wi] : 0.f;
        o[j] = __float2bfloat16(f);
    }
}

__global__ __launch_bounds__(256)
void pack_convout_k(const float* __restrict__ w, __hip_bfloat16* __restrict__ bp)
{
    int idx = blockIdx.x * 256 + threadIdx.x;
    if (idx >= 9 * 64) return;
    int lane = idx & 63;
    int g    = idx >> 6;
    int co   = lane & 15;
    __hip_bfloat16* o = bp + (size_t)idx * 8;
    for (int j = 0; j < 8; ++j) {
        int ci = (lane >> 4) * 8 + j;
        float f = (co < 3) ? w[((size_t)co * 32 + ci) * 9 + g] : 0.f;
        o[j] = __float2bfloat16(f);
    }
}

// ======================= conv2: 32->64 s2, MFMA (swapped), NHWC =======================
__global__ __launch_bounds__(256, 2)
void conv2_mfma_k(const __hip_bfloat16* __restrict__ in,      // [32][128][128][32]
                  const __hip_bfloat16* __restrict__ bpack,
                  const float* __restrict__ bconv,
                  const float* __restrict__ bg, const float* __restrict__ bb,
                  const float* __restrict__ bm, const float* __restrict__ bv,
                  __hip_bfloat16* __restrict__ out,           // [32][64][64][64]
                  cbfp zp)
{
    int lane = threadIdx.x & 63;
    int gw = blockIdx.x * 4 + (threadIdx.x >> 6);
    int nt = gw & 3;
    int xt = (gw >> 2) & 3;
    int yt = (gw >> 4) & 15;
    int n  = gw >> 8;
    int m = lane & 15, kc = lane >> 4;
    int xm = xt * 16 + m;

    bf8v bfrag[9];
    const bf8v* bpv = reinterpret_cast<const bf8v*>(bpack);
    #pragma unroll
    for (int g = 0; g < 9; ++g) bfrag[g] = bpv[((size_t)nt * 9 + g) * 64 + lane];

    int co0 = nt * 16 + kc * 4;
    float s4[4], b4[4];
    #pragma unroll
    for (int r = 0; r < 4; ++r) {
        int co = co0 + r;
        float s = bg[co] * rsqrtf(bv[co] + 1e-5f);
        s4[r] = s; b4[r] = (bconv[co] - bm[co]) * s + bb[co];
    }
    bool vc0 = (xm > 0);

    for (int t = 0; t < 4; ++t) {
        int y = yt * 4 + t;
        cbfp rb[3], pc0[3];
        #pragma unroll
        for (int r = 0; r < 3; ++r) {
            int iy = 2 * y + r - 1;
            bool vy = (unsigned)iy < 128u;
            rb[r]  = vy ? in + (((size_t)n * 128 + iy) * 128 + 2 * xm) * 32 + kc * 8 : zp;
            pc0[r] = vc0 ? rb[r] - 32 : zp;
        }
        bf8v av[9];
        #pragma unroll
        for (int g = 0; g < 9; ++g) {
            int r = g / 3, c = g % 3;
            cbfp pg = (c == 0) ? pc0[r] : rb[r];
            av[g] = *reinterpret_cast<const bf8v*>(pg + (c == 2 ? 32 : 0));
        }
        f4v acc = {0, 0, 0, 0};
        #pragma unroll
        for (int g = 0; g < 9; ++g)
            acc = __builtin_amdgcn_mfma_f32_16x16x32_bf16(bfrag[g], av[g], acc, 0, 0, 0);

        union { __hip_bfloat162 h[2]; float2 f; } pk;
        float v0 = acc[0] * s4[0] + b4[0]; v0 = v0 >= 0.f ? v0 : 0.1f * v0;
        float v1 = acc[1] * s4[1] + b4[1]; v1 = v1 >= 0.f ? v1 : 0.1f * v1;
        float v2 = acc[2] * s4[2] + b4[2]; v2 = v2 >= 0.f ? v2 : 0.1f * v2;
        float v3 = acc[3] * s4[3] + b4[3]; v3 = v3 >= 0.f ? v3 : 0.1f * v3;
        pk.h[0] = __halves2bfloat162(__float2bfloat16(v0), __float2bfloat16(v1));
        pk.h[1] = __halves2bfloat162(__float2bfloat16(v2), __float2bfloat16(v3));
        *(float2*)(out + (((size_t)n * 64 + y) * 64 + xm) * 64 + co0) = pk.f;
    }
}

// ======================= conv3: 64->10 s1, MFMA (swapped) -> z fp32 NCHW =======================
__global__ __launch_bounds__(256, 2)
void conv3_mfma_k(const __hip_bfloat16* __restrict__ in,      // [32][64][64][64]
                  const __hip_bfloat16* __restrict__ bpack,
                  const float* __restrict__ bconv,
                  const float* __restrict__ bg, const float* __restrict__ bb,
                  const float* __restrict__ bm, const float* __restrict__ bv,
                  float* __restrict__ z, cbfp zp)              // [32][10][64][64]
{
    __shared__ bf8v sB[18 * 64];
    const bf8v* bpv = reinterpret_cast<const bf8v*>(bpack);
    for (int idx = threadIdx.x; idx < 18 * 64; idx += 256) sB[idx] = bpv[idx];
    __syncthreads();

    int lane = threadIdx.x & 63;
    int gw = blockIdx.x * 4 + (threadIdx.x >> 6);
    int xt = gw & 3;
    int yt = (gw >> 2) & 15;
    int n  = gw >> 6;
    int m = lane & 15, kc = lane >> 4;
    int xm = xt * 16 + m;

    float s4[4], b4[4];
    #pragma unroll
    for (int r = 0; r < 4; ++r) {
        int co = kc * 4 + r;
        if (co < 10) {
            float s = bg[co] * rsqrtf(bv[co] + 1e-5f);
            s4[r] = s; b4[r] = (bconv[co] - bm[co]) * s + bb[co];
        } else { s4[r] = 0.f; b4[r] = 0.f; }
    }
    bool vc0 = (xm > 0), vc2 = (xm < 63);

    for (int t = 0; t < 4; ++t) {
        int y = yt * 4 + t;
        cbfp rb[3], pc0[3], pc2[3];
        #pragma unroll
        for (int r = 0; r < 3; ++r) {
            int iy = y + r - 1;
            bool vy = (unsigned)iy < 64u;
            rb[r]  = vy ? in + (((size_t)n * 64 + iy) * 64 + xm) * 64 + kc * 8 : zp;
            pc0[r] = vc0 ? rb[r] - 64 : zp;
            pc2[r] = vc2 ? rb[r] + 64 : zp;
        }
        bf8v av[18];
        #pragma unroll
        for (int g = 0; g < 18; ++g) {
            int tap = g >> 1, cib = g & 1;
            int r = tap / 3, c = tap % 3;
            cbfp pg = (c == 0) ? pc0[r] : ((c == 2) ? pc2[r] : rb[r]);
            av[g] = *reinterpret_cast<const bf8v*>(pg + cib * 32);
        }
        f4v acc = {0, 0, 0, 0};
        #pragma unroll
        for (int g = 0; g < 18; ++g)
            acc = __builtin_amdgcn_mfma_f32_16x16x32_bf16(sB[g * 64 + lane], av[g], acc, 0, 0, 0);

        #pragma unroll
        for (int r = 0; r < 4; ++r) {
            int co = kc * 4 + r;
            if (co < 10)
                z[(((size_t)n * 10 + co) << 12) + y * 64 + xm] = acc[r] * s4[r] + b4[r];
        }
    }
}

// =============== unified MFMA deconv (swapped), NHWC bf16 ===============
// WHICH==2: nt is block-uniform (low block-index bit) -> LDS stages only 18KB.
template<int WHICH, int I_T>
__global__ __launch_bounds__(256, 2)
void deconv_mfma_k(const __hip_bfloat16* __restrict__ in,
                   const __hip_bfloat16* __restrict__ bpack,
                   const float* __restrict__ bconv,
                   const float* __restrict__ bg, const float* __restrict__ bb,
                   const float* __restrict__ bm, const float* __restrict__ bv,
                   __hip_bfloat16* __restrict__ out, cbfp zp)
{
    constexpr int NKS  = (WHICH == 1) ? 9 : 18;
    constexpr int CINP = (WHICH == 1) ? 32 : 64;
    constexpr int COUT = (WHICH == 1) ? 64 : 32;
    constexpr int NT   = COUT / 16;
    constexpr int HI   = (WHICH == 1) ? 64 : 128;
    constexpr int HO   = HI * 2;
    constexpr int JT   = HI / 16;
    constexpr const DTab& T = (WHICH == 1) ? TAB1 : TAB2;

    __shared__ bf8v sB[(WHICH == 2) ? NKS * 64 : 1];
    const bf8v* bpv = reinterpret_cast<const bf8v*>(bpack);

    int lane = threadIdx.x & 63;
    int nt, jt, it, n;
    if constexpr (WHICH == 2) {
        nt = blockIdx.x & 1;                       // block-uniform co-tile
        int sid = (blockIdx.x >> 1) * 4 + (threadIdx.x >> 6);
        jt = sid % JT;  sid /= JT;
        it = sid % (HI / I_T);
        n  = sid / (HI / I_T);
        for (int idx = threadIdx.x; idx < NKS * 64; idx += 256)
            sB[idx] = bpv[(size_t)nt * NKS * 64 + idx];
        __syncthreads();
    } else {
        int gw = blockIdx.x * 4 + (threadIdx.x >> 6);
        nt = gw % NT;  int mt = gw / NT;
        jt = mt % JT;  mt /= JT;
        it = mt % (HI / I_T);
        n  = mt / (HI / I_T);
    }
    int j0 = jt * 16;
    int m  = lane & 15, kc = lane >> 4;
    int jm = j0 + m;

    bf8v bfrag[(WHICH == 1) ? NKS : 1];
    if constexpr (WHICH == 1) {
        #pragma unroll
        for (int g = 0; g < NKS; ++g) bfrag[g] = bpv[((size_t)nt * NKS + g) * 64 + lane];
    }

    int co0 = nt * 16 + kc * 4;
    float s4[4], b4[4];
    #pragma unroll
    for (int r = 0; r < 4; ++r) {
        int co = co0 + r;
        float s = bg[co] * rsqrtf(bv[co] + 1e-5f);
        s4[r] = s; b4[r] = (bconv[co] - bm[co]) * s + bb[co];
    }
    bool vj = (jm + 1) < HI;

    for (int t = 0; t < I_T; ++t) {
        int i = it * I_T + t;
        bool vi = (i + 1) < HI;
        cbfp p00 = in + (((size_t)n * HI + i) * HI + jm) * CINP + kc * 8;
        cbfp p01 = vj ? p00 + CINP : zp;
        cbfp p10 = vi ? p00 + (size_t)HI * CINP : zp;
        cbfp p11 = (vi && vj) ? p00 + (size_t)(HI + 1) * CINP : zp;

        bf8v av[NKS];
        #pragma unroll
        for (int g = 0; g < NKS; ++g) {
            cbfp pg = T.di[g] ? (T.dj[g] ? p11 : p10) : (T.dj[g] ? p01 : p00);
            av[g] = *reinterpret_cast<const bf8v*>(pg + T.ci0[g]);
        }
        f4v acc[4] = {{0,0,0,0},{0,0,0,0},{0,0,0,0},{0,0,0,0}};
        #pragma unroll
        for (int g = 0; g < NKS; ++g) {
            bf8v bw;
            if constexpr (WHICH == 2) bw = sB[g * 64 + lane];
            else                      bw = bfrag[g];
            acc[T.ph[g]] = __builtin_amdgcn_mfma_f32_16x16x32_bf16(bw, av[g], acc[T.ph[g]], 0, 0, 0);
        }

        __hip_bfloat16* ob = out + (((size_t)n * HO + 2 * i) * HO + 2 * jm) * COUT + co0;
        #pragma unroll
        for (int p = 0; p < 4; ++p) {
            int py = p >> 1, px = p & 1;
            float v0 = acc[p][0] * s4[0] + b4[0]; v0 = v0 >= 0.f ? v0 : 0.1f * v0;
            float v1 = acc[p][1] * s4[1] + b4[1]; v1 = v1 >= 0.f ? v1 : 0.1f * v1;
            float v2 = acc[p][2] * s4[2] + b4[2]; v2 = v2 >= 0.f ? v2 : 0.1f * v2;
            float v3 = acc[p][3] * s4[3] + b4[3]; v3 = v3 >= 0.f ? v3 : 0.1f * v3;
            union { __hip_bfloat162 h[2]; float2 f; } pk;
            pk.h[0] = __halves2bfloat162(__float2bfloat16(v0), __float2bfloat16(v1));
            pk.h[1] = __halves2bfloat162(__float2bfloat16(v2), __float2bfloat16(v3));
            *(float2*)(ob + ((size_t)py * HO + px) * COUT) = pk.f;
        }
    }
}

// ======================= conv_out: 32->3 s1 + sigmoid (swapped) =======================
__global__ __launch_bounds__(256, 2)
void convout_mfma_k(const __hip_bfloat16* __restrict__ in,    // [32][256][256][32]
                    const __hip_bfloat16* __restrict__ bpack,
                    const float* __restrict__ b3,
                    float* __restrict__ out, cbfp zp)
{
    int lane = threadIdx.x & 63;
    int gw = blockIdx.x * 4 + (threadIdx.x >> 6);
    int xt = gw & 15;
    int yt = (gw >> 4) & 63;
    int n  = gw >> 10;
    int m = lane & 15, kc = lane >> 4;
    int xm = xt * 16 + m;

    bf8v bfrag[9];
    #pragma unroll
    for (int g = 0; g < 9; ++g)
        bfrag[g] = reinterpret_cast<const bf8v*>(bpack)[g * 64 + lane];

    float bias0 = b3[0], bias1 = b3[1], bias2 = b3[2];
    bool vc0 = (xm > 0), vc2 = (xm < 255);

    for (int t = 0; t < 4; ++t) {
        int y = yt * 4 + t;
        cbfp rb[3], pc0[3], pc2[3];
        #pragma unroll
        for (int r = 0; r < 3; ++r) {
            int iy = y + r - 1;
            bool vy = (unsigned)iy < 256u;
            rb[r]  = vy ? in + (((size_t)n * 256 + iy) * 256 + xm) * 32 + kc * 8 : zp;
            pc0[r] = vc0 ? rb[r] - 32 : zp;
            pc2[r] = vc2 ? rb[r] + 32 : zp;
        }
        bf8v av[9];
        #pragma unroll
        for (int g = 0; g < 9; ++g) {
            int r = g / 3, c = g % 3;
            cbfp pg = (c == 0) ? pc0[r] : ((c == 2) ? pc2[r] : rb[r]);
            av[g] = *reinterpret_cast<const bf8v*>(pg);
        }
        f4v acc = {0, 0, 0, 0};
        #pragma unroll
        for (int g = 0; g < 9; ++g)
            acc = __builtin_amdgcn_mfma_f32_16x16x32_bf16(bfrag[g], av[g], acc, 0, 0, 0);

        if (kc == 0) {
            size_t ybase = ((size_t)n * 3) * 65536 + (size_t)y * 256 + xm;
            float v0 = acc[0] + bias0;
            float v1 = acc[1] + bias1;
            float v2 = acc[2] + bias2;
            out[ybase]             = 1.f / (1.f + __expf(-v0));
            out[ybase + 65536]     = 1.f / (1.f + __expf(-v1));
            out[ybase + 131072]    = 1.f / (1.f + __expf(-v2));
        }
    }
}

// ============ VQ (fp32 argmin) ============
__global__ __launch_bounds__(256)
void vq_k(const float* __restrict__ z, const float* __restrict__ emb,
          __hip_bfloat16* __restrict__ q, float* __restrict__ sse_acc,
          unsigned int* __restrict__ counts, int HW, int CHW)
{
    __shared__ float se[256 * 10];
    __shared__ unsigned int hist[256];
    __shared__ float wsum[4];
    int tid = threadIdx.x;
    for (int i = tid; i < 2560; i += 256) se[i] = emb[i];
    hist[tid] = 0u;
    __syncthreads();

    int pos = blockIdx.x * 256 + tid;
    int b = pos / HW;
    int sp = pos - b * HW;
    const float* zpz = z + (size_t)b * CHW + sp;
    float zv[10];
    #pragma unroll
    for (int c = 0; c < 10; ++c) zv[c] = zpz[(size_t)c * HW];

    float best = 3.4e38f;
    int bi = 0;
    for (int k = 0; k < 256; ++k) {
        const float* e = se + k * 10;
        float d = 0.f;
        #pragma unroll
        for (int c = 0; c < 10; ++c) { float t = zv[c] - e[c]; d = fmaf(t, t, d); }
        if (d < best) { best = d; bi = k; }
    }
    atomicAdd(&hist[bi], 1u);

    __hip_bfloat16* qp = q + (size_t)pos * 32;
    float lsse = 0.f;
    #pragma unroll
    for (int c = 0; c < 10; ++c) {
        float e = se[bi * 10 + c];
        qp[c] = __float2bfloat16(e);
        float t = e - zv[c];
        lsse = fmaf(t, t, lsse);
    }
    #pragma unroll
    for (int c = 10; c < 32; ++c) qp[c] = __float2bfloat16(0.f);

    #pragma unroll
    for (int off = 32; off > 0; off >>= 1) lsse += __shfl_down(lsse, off, 64);
    if ((tid & 63) == 0) wsum[tid >> 6] = lsse;
    __syncthreads();
    if (tid == 0) atomicAdd(sse_acc, wsum[0] + wsum[1] + wsum[2] + wsum[3]);
    atomicAdd(&counts[tid], hist[tid]);
}

__global__ __launch_bounds__(256)
void vq_finalize_k(const float* __restrict__ sse_acc, const unsigned int* __restrict__ counts,
                   float* __restrict__ out_loss, float* __restrict__ out_ppl,
                   float invNC, float invN)
{
    __shared__ float w4[4];
    int tid = threadIdx.x;
    float p = (float)counts[tid] * invN;
    float t = p * logf(p + 1e-10f);
    #pragma unroll
    for (int off = 32; off > 0; off >>= 1) t += __shfl_down(t, off, 64);
    if ((tid & 63) == 0) w4[tid >> 6] = t;
    __syncthreads();
    if (tid == 0) {
        float s = w4[0] + w4[1] + w4[2] + w4[3];
        *out_ppl  = expf(-s);
        *out_loss = 1.25f * sse_acc[0] * invNC;
    }
}

__global__ void zero_k(float* p, int n) {
    int i = blockIdx.x * 256 + threadIdx.x;
    if (i < n) p[i] = 0.f;
}

extern "C" void kernel_launch(void* const* d_in, const int* in_sizes, int n_in,
                              void* d_out, int out_size, void* d_ws, size_t ws_size,
                              hipStream_t stream) {
    const float* x      = (const float*)d_in[0];
    const float* enc_w1 = (const float*)d_in[1];
    const float* enc_b1 = (const float*)d_in[2];
    const float* bn1_g  = (const float*)d_in[3];
    const float* bn1_b  = (const float*)d_in[4];
    const float* bn1_m  = (const float*)d_in[5];
    const float* bn1_v  = (const float*)d_in[6];
    const float* enc_w2 = (const float*)d_in[7];
    const float* enc_b2 = (const float*)d_in[8];
    const float* bn2_g  = (const float*)d_in[9];
    const float* bn2_b  = (const float*)d_in[10];
    const float* bn2_m  = (const float*)d_in[11];
    const float* bn2_v  = (const float*)d_in[12];
    const float* enc_w3 = (const float*)d_in[13];
    const float* enc_b3 = (const float*)d_in[14];
    const float* bn3_g  = (const float*)d_in[15];
    const float* bn3_b  = (const float*)d_in[16];
    const float* bn3_m  = (const float*)d_in[17];
    const float* bn3_v  = (const float*)d_in[18];
    const float* emb    = (const float*)d_in[19];
    const float* dec_w1 = (const float*)d_in[20];
    const float* dec_b1 = (const float*)d_in[21];
    const float* dbn1_g = (const float*)d_in[22];
    const float* dbn1_b = (const float*)d_in[23];
    const float* dbn1_m = (const float*)d_in[24];
    const float* dbn1_v = (const float*)d_in[25];
    const float* dec_w2 = (const float*)d_in[26];
    const float* dec_b2 = (const float*)d_in[27];
    const float* dbn2_g = (const float*)d_in[28];
    const float* dbn2_b = (const float*)d_in[29];
    const float* dbn2_m = (const float*)d_in[30];
    const float* dbn2_v = (const float*)d_in[31];
    const float* dec_w3 = (const float*)d_in[32];
    const float* dec_b3 = (const float*)d_in[33];

    float* ws = (float*)d_ws;
    // workspace (float units), all 16B-aligned
    const size_t SSE_OFF  = 0;           // 1 f
    const size_t CNT_OFF  = 4;           // 256 u32
    const size_t ZP_OFF   = 260;         // 256 f zero page (1 KB)
    const size_t BPC2_OFF = 516;         // conv2 pack: 9216 f
    const size_t BPC3_OFF = 9732;        // conv3 pack: 4608 f
    const size_t BP1_OFF  = 14340;       // deconv1 pack: 9216 f
    const size_t BP2_OFF  = 23556;       // deconv2 pack: 9216 f
    const size_t BPO_OFF  = 32772;       // convout pack: 2304 f
    const size_t Q_OFF    = 35076;       // q NHWC bf16 C=32: 2,097,152 f
    const size_t Z_OFF    = 2132228;     // z fp32 NCHW: 1,310,720 f
    const size_t H1_OFF   = 3442948;     // h1 NHWC bf16: 8,388,608 f
    const size_t H2_OFF   = 11831556;    // h2 NHWC bf16: 4,194,304 f
    const size_t DD2_OFF  = 2132228;     // dd2 bf16 16,777,216 f (overlays z/h1/h2, dead)
    const size_t DD1_OFF  = 18909444;    // dd1 bf16 16,777,216 f
    const size_t NEEDED_F = DD1_OFF + 16777216;   // ~143 MB

    if (ws_size < NEEDED_F * sizeof(float)) return;

    float* sse  = ws + SSE_OFF;
    unsigned int* counts = (unsigned int*)(ws + CNT_OFF);
    cbfp zp = (cbfp)(ws + ZP_OFF + 128);   // middle of zero page, +/-512B margin
    __hip_bfloat16* bpc2 = (__hip_bfloat16*)(ws + BPC2_OFF);
    __hip_bfloat16* bpc3 = (__hip_bfloat16*)(ws + BPC3_OFF);
    __hip_bfloat16* bp1  = (__hip_bfloat16*)(ws + BP1_OFF);
    __hip_bfloat16* bp2  = (__hip_bfloat16*)(ws + BP2_OFF);
    __hip_bfloat16* bpo  = (__hip_bfloat16*)(ws + BPO_OFF);
    __hip_bfloat16* qbuf = (__hip_bfloat16*)(ws + Q_OFF);
    float* zbuf = ws + Z_OFF;
    __hip_bfloat16* h1  = (__hip_bfloat16*)(ws + H1_OFF);
    __hip_bfloat16* h2  = (__hip_bfloat16*)(ws + H2_OFF);
    __hip_bfloat16* dd1 = (__hip_bfloat16*)(ws + DD1_OFF);
    __hip_bfloat16* dd2 = (__hip_bfloat16*)(ws + DD2_OFF);
    float* out = (float*)d_out;

    zero_k<<<3, 256, 0, stream>>>(ws, 516);
    pack_conv2_k<<<9, 256, 0, stream>>>(enc_w2, bpc2);
    pack_conv3_k<<<5, 256, 0, stream>>>(enc_w3, bpc3);
    pack_deconv_k<1><<<9, 256, 0, stream>>>(dec_w1, bp1);
    pack_deconv_k<2><<<9, 256, 0, stream>>>(dec_w2, bp2);
    pack_convout_k<<<3, 256, 0, stream>>>(dec_w3, bpo);

    // encoder
    conv1_k<<<2048, 256, 0, stream>>>(x, enc_w1, enc_b1, bn1_g, bn1_b, bn1_m, bn1_v, h1);
    conv2_mfma_k<<<2048, 256, 0, stream>>>(h1, bpc2, enc_b2, bn2_g, bn2_b, bn2_m, bn2_v, h2, zp);
    conv3_mfma_k<<<512, 256, 0, stream>>>(h2, bpc3, enc_b3, bn3_g, bn3_b, bn3_m, bn3_v, zbuf, zp);

    // VQ
    vq_k<<<512, 256, 0, stream>>>(zbuf, emb, qbuf, sse, counts, 4096, 40960);

    // decoder
    deconv_mfma_k<1, 2><<<4096, 256, 0, stream>>>(
        qbuf, bp1, dec_b1, dbn1_g, dbn1_b, dbn1_m, dbn1_v, dd1, zp);
    deconv_mfma_k<2, 2><<<8192, 256, 0, stream>>>(
        dd1, bp2, dec_b2, dbn2_g, dbn2_b, dbn2_m, dbn2_v, dd2, zp);
    convout_mfma_k<<<8192, 256, 0, stream>>>(dd2, bpo, dec_b3, out, zp);

    vq_finalize_k<<<1, 256, 0, stream>>>(sse, counts, out + 6291456, out + 6291457,
                                         1.f / 1310720.f, 1.f / 131072.f);
}

// Round 12
// 447.375 us; speedup vs baseline: 4.3769x; 1.0497x over previous
//
#include <hip/hip_runtime.h>
#include <hip/hip_bf16.h>
#include <math.h>

typedef __attribute__((ext_vector_type(8))) short bf8v;   // 8 bf16 in 4 VGPRs
typedef __attribute__((ext_vector_type(4))) float f4v;    // MFMA accumulator
typedef const __hip_bfloat16* cbfp;

__device__ __forceinline__ void ld4f(const float* p, float* o) {
    float4 t = *(const float4*)p; o[0] = t.x; o[1] = t.y; o[2] = t.z; o[3] = t.w;
}

// ======================= conv1: 3->32 s2, VALU, NCHW fp32 -> NHWC bf16 =======================
__global__ __launch_bounds__(256, 2)
void conv1_k(const float* __restrict__ x, const float* __restrict__ w,
             const float* __restrict__ bconv,
             const float* __restrict__ bg, const float* __restrict__ bb,
             const float* __restrict__ bm, const float* __restrict__ bv,
             __hip_bfloat16* __restrict__ out)   // [32][128][128][32]
{
    __shared__ float sw[3 * 8 * 12];
    int b  = blockIdx.x;
    int yt = b & 15;
    int cg = (b >> 4) & 3;
    int n  = b >> 6;
    int co0 = cg * 8;
    int tid = threadIdx.x;
    for (int idx = tid; idx < 3 * 8 * 9; idx += 256) {
        int t = idx % 9; int rest = idx / 9;
        int cot = rest % 8; int ci = rest / 8;
        sw[(ci * 8 + cot) * 12 + t] = w[(((size_t)(co0 + cot) * 3) + ci) * 9 + t];
    }
    __syncthreads();

    int tx = tid & 31, ty = tid >> 5;
    int y  = yt * 8 + ty;
    int x0 = tx * 4;
    int iyb = 2 * y - 1;
    int ixb = 2 * x0 - 1;

    float acc[8][4];
    #pragma unroll
    for (int c = 0; c < 8; ++c)
        #pragma unroll
        for (int u = 0; u < 4; ++u) acc[c][u] = 0.f;

    for (int ci = 0; ci < 3; ++ci) {
        const float* ipc = x + ((size_t)n * 3 + ci) * 65536;
        float iv[3][9];
        #pragma unroll
        for (int r = 0; r < 3; ++r) {
            int iy = iyb + r;
            bool vy = (unsigned)iy < 256u;
            const float* row = ipc + (size_t)iy * 256;
            if (vy) {
                iv[r][0] = (ixb >= 0) ? row[ixb] : 0.f;
                ld4f(row + ixb + 1, &iv[r][1]);
                ld4f(row + ixb + 5, &iv[r][5]);
            } else {
                #pragma unroll
                for (int c = 0; c < 9; ++c) iv[r][c] = 0.f;
            }
        }
        #pragma unroll
        for (int cot = 0; cot < 8; ++cot) {
            const float4* wp4 = reinterpret_cast<const float4*>(&sw[(ci * 8 + cot) * 12]);
            float4 wa = wp4[0], wb = wp4[1], wc4 = wp4[2];
            float wreg[9] = {wa.x, wa.y, wa.z, wa.w, wb.x, wb.y, wb.z, wb.w, wc4.x};
            #pragma unroll
            for (int r = 0; r < 3; ++r)
                #pragma unroll
                for (int c = 0; c < 3; ++c)
                    #pragma unroll
                    for (int u = 0; u < 4; ++u)
                        acc[cot][u] = fmaf(iv[r][u * 2 + c], wreg[r * 3 + c], acc[cot][u]);
        }
    }

    float rs[8][4];
    #pragma unroll
    for (int cot = 0; cot < 8; ++cot) {
        int co = co0 + cot;
        float s = bg[co] * rsqrtf(bv[co] + 1e-5f);
        float bias = (bconv[co] - bm[co]) * s + bb[co];
        #pragma unroll
        for (int u = 0; u < 4; ++u) {
            float v = acc[cot][u] * s + bias;
            rs[cot][u] = (v >= 0.f) ? v : 0.1f * v;
        }
    }
    #pragma unroll
    for (int u = 0; u < 4; ++u) {
        union { __hip_bfloat162 h[4]; float4 f; } pk;
        #pragma unroll
        for (int p2 = 0; p2 < 4; ++p2)
            pk.h[p2] = __halves2bfloat162(__float2bfloat16(rs[2 * p2][u]),
                                          __float2bfloat16(rs[2 * p2 + 1][u]));
        *(float4*)(out + (((size_t)n * 128 + y) * 128 + (x0 + u)) * 32 + co0) = pk.f;
    }
}

// ======================= weight packs (A-fragment lane order: row=co) =======================
__global__ __launch_bounds__(256)
void pack_conv2_k(const float* __restrict__ w, __hip_bfloat16* __restrict__ bp)
{
    int idx = blockIdx.x * 256 + threadIdx.x;
    if (idx >= 4 * 9 * 64) return;
    int lane = idx & 63;
    int g    = (idx >> 6) % 9;
    int nt   = idx / 576;
    int co   = nt * 16 + (lane & 15);
    __hip_bfloat16* o = bp + (size_t)idx * 8;
    for (int j = 0; j < 8; ++j) {
        int ci = (lane >> 4) * 8 + j;
        o[j] = __float2bfloat16(w[((size_t)co * 32 + ci) * 9 + g]);
    }
}

__global__ __launch_bounds__(256)
void pack_conv3_k(const float* __restrict__ w, __hip_bfloat16* __restrict__ bp)
{
    int idx = blockIdx.x * 256 + threadIdx.x;
    if (idx >= 18 * 64) return;
    int lane = idx & 63;
    int g    = idx >> 6;
    int tap  = g >> 1, cib = g & 1;
    int co   = lane & 15;
    __hip_bfloat16* o = bp + (size_t)idx * 8;
    for (int j = 0; j < 8; ++j) {
        int ci = cib * 32 + (lane >> 4) * 8 + j;
        float f = (co < 10) ? w[((size_t)co * 64 + ci) * 9 + tap] : 0.f;
        o[j] = __float2bfloat16(f);
    }
}

struct DTab { int di[18]; int dj[18]; int wi[18]; int ci0[18]; int ph[18]; };
constexpr DTab TAB1 = {
    {0, 0,0, 1,0, 1,1,0,0,  0,0,0,0,0,0,0,0,0},
    {0, 1,0, 0,0, 1,0,1,0,  0,0,0,0,0,0,0,0,0},
    {4, 3,5, 1,7, 0,2,6,8,  0,0,0,0,0,0,0,0,0},
    {0, 0,0, 0,0, 0,0,0,0,  0,0,0,0,0,0,0,0,0},
    {0, 1,1, 2,2, 3,3,3,3,  0,0,0,0,0,0,0,0,0}};
constexpr DTab TAB2 = {
    {0,0,  0,0,0,0,  1,1,0,0,  1,1,1,1,0,0,0,0},
    {0,0,  1,1,0,0,  0,0,0,0,  1,1,0,0,1,1,0,0},
    {4,4,  3,3,5,5,  1,1,7,7,  0,0,2,2,6,6,8,8},
    {0,32, 0,32,0,32, 0,32,0,32, 0,32,0,32,0,32,0,32},
    {0,0,  1,1,1,1,  2,2,2,2,  3,3,3,3,3,3,3,3}};

template<int WHICH>
__global__ __launch_bounds__(256)
void pack_deconv_k(const float* __restrict__ w, __hip_bfloat16* __restrict__ bp)
{
    constexpr int NKS  = (WHICH == 1) ? 9 : 18;
    constexpr int COUT = (WHICH == 1) ? 64 : 32;
    constexpr int CINr = (WHICH == 1) ? 10 : 64;
    constexpr int NT   = COUT / 16;
    constexpr const DTab& T = (WHICH == 1) ? TAB1 : TAB2;
    int idx = blockIdx.x * 256 + threadIdx.x;
    if (idx >= NT * NKS * 64) return;
    int lane = idx & 63;
    int g    = (idx >> 6) % NKS;
    int nt   = idx / (64 * NKS);
    int co   = nt * 16 + (lane & 15);
    int wi   = T.wi[g], ci0 = T.ci0[g];
    __hip_bfloat16* o = bp + (size_t)idx * 8;
    for (int j = 0; j < 8; ++j) {
        int ci = ci0 + (lane >> 4) * 8 + j;
        float f = (ci < CINr) ? w[((size_t)ci * COUT + co) * 9 + wi] : 0.f;
        o[j] = __float2bfloat16(f);
    }
}

__global__ __launch_bounds__(256)
void pack_convout_k(const float* __restrict__ w, __hip_bfloat16* __restrict__ bp)
{
    int idx = blockIdx.x * 256 + threadIdx.x;
    if (idx >= 9 * 64) return;
    int lane = idx & 63;
    int g    = idx >> 6;
    int co   = lane & 15;
    __hip_bfloat16* o = bp + (size_t)idx * 8;
    for (int j = 0; j < 8; ++j) {
        int ci = (lane >> 4) * 8 + j;
        float f = (co < 3) ? w[((size_t)co * 32 + ci) * 9 + g] : 0.f;
        o[j] = __float2bfloat16(f);
    }
}

// ======================= conv2: 32->64 s2, MFMA (swapped), NHWC =======================
__global__ __launch_bounds__(256, 2)
void conv2_mfma_k(const __hip_bfloat16* __restrict__ in,      // [32][128][128][32]
                  const __hip_bfloat16* __restrict__ bpack,
                  const float* __restrict__ bconv,
                  const float* __restrict__ bg, const float* __restrict__ bb,
                  const float* __restrict__ bm, const float* __restrict__ bv,
                  __hip_bfloat16* __restrict__ out,           // [32][64][64][64]
                  cbfp zp)
{
    int lane = threadIdx.x & 63;
    int gw = blockIdx.x * 4 + (threadIdx.x >> 6);
    int nt = gw & 3;
    int xt = (gw >> 2) & 3;
    int yt = (gw >> 4) & 15;
    int n  = gw >> 8;
    int m = lane & 15, kc = lane >> 4;
    int xm = xt * 16 + m;

    bf8v bfrag[9];
    const bf8v* bpv = reinterpret_cast<const bf8v*>(bpack);
    #pragma unroll
    for (int g = 0; g < 9; ++g) bfrag[g] = bpv[((size_t)nt * 9 + g) * 64 + lane];

    int co0 = nt * 16 + kc * 4;
    float s4[4], b4[4];
    #pragma unroll
    for (int r = 0; r < 4; ++r) {
        int co = co0 + r;
        float s = bg[co] * rsqrtf(bv[co] + 1e-5f);
        s4[r] = s; b4[r] = (bconv[co] - bm[co]) * s + bb[co];
    }
    bool vc0 = (xm > 0);

    for (int t = 0; t < 4; ++t) {
        int y = yt * 4 + t;
        cbfp rb[3], pc0[3];
        #pragma unroll
        for (int r = 0; r < 3; ++r) {
            int iy = 2 * y + r - 1;
            bool vy = (unsigned)iy < 128u;
            rb[r]  = vy ? in + (((size_t)n * 128 + iy) * 128 + 2 * xm) * 32 + kc * 8 : zp;
            pc0[r] = vc0 ? rb[r] - 32 : zp;
        }
        bf8v av[9];
        #pragma unroll
        for (int g = 0; g < 9; ++g) {
            int r = g / 3, c = g % 3;
            cbfp pg = (c == 0) ? pc0[r] : rb[r];
            av[g] = *reinterpret_cast<const bf8v*>(pg + (c == 2 ? 32 : 0));
        }
        f4v acc = {0, 0, 0, 0};
        #pragma unroll
        for (int g = 0; g < 9; ++g)
            acc = __builtin_amdgcn_mfma_f32_16x16x32_bf16(bfrag[g], av[g], acc, 0, 0, 0);

        union { __hip_bfloat162 h[2]; float2 f; } pk;
        float v0 = acc[0] * s4[0] + b4[0]; v0 = v0 >= 0.f ? v0 : 0.1f * v0;
        float v1 = acc[1] * s4[1] + b4[1]; v1 = v1 >= 0.f ? v1 : 0.1f * v1;
        float v2 = acc[2] * s4[2] + b4[2]; v2 = v2 >= 0.f ? v2 : 0.1f * v2;
        float v3 = acc[3] * s4[3] + b4[3]; v3 = v3 >= 0.f ? v3 : 0.1f * v3;
        pk.h[0] = __halves2bfloat162(__float2bfloat16(v0), __float2bfloat16(v1));
        pk.h[1] = __halves2bfloat162(__float2bfloat16(v2), __float2bfloat16(v3));
        *(float2*)(out + (((size_t)n * 64 + y) * 64 + xm) * 64 + co0) = pk.f;
    }
}

// ======================= conv3: 64->10 s1, MFMA (swapped) -> z fp32 NCHW =======================
__global__ __launch_bounds__(256, 2)
void conv3_mfma_k(const __hip_bfloat16* __restrict__ in,      // [32][64][64][64]
                  const __hip_bfloat16* __restrict__ bpack,
                  const float* __restrict__ bconv,
                  const float* __restrict__ bg, const float* __restrict__ bb,
                  const float* __restrict__ bm, const float* __restrict__ bv,
                  float* __restrict__ z, cbfp zp)              // [32][10][64][64]
{
    __shared__ bf8v sB[18 * 64];
    const bf8v* bpv = reinterpret_cast<const bf8v*>(bpack);
    for (int idx = threadIdx.x; idx < 18 * 64; idx += 256) sB[idx] = bpv[idx];
    __syncthreads();

    int lane = threadIdx.x & 63;
    int gw = blockIdx.x * 4 + (threadIdx.x >> 6);
    int xt = gw & 3;
    int yt = (gw >> 2) & 15;
    int n  = gw >> 6;
    int m = lane & 15, kc = lane >> 4;
    int xm = xt * 16 + m;

    float s4[4], b4[4];
    #pragma unroll
    for (int r = 0; r < 4; ++r) {
        int co = kc * 4 + r;
        if (co < 10) {
            float s = bg[co] * rsqrtf(bv[co] + 1e-5f);
            s4[r] = s; b4[r] = (bconv[co] - bm[co]) * s + bb[co];
        } else { s4[r] = 0.f; b4[r] = 0.f; }
    }
    bool vc0 = (xm > 0), vc2 = (xm < 63);

    for (int t = 0; t < 4; ++t) {
        int y = yt * 4 + t;
        cbfp rb[3], pc0[3], pc2[3];
        #pragma unroll
        for (int r = 0; r < 3; ++r) {
            int iy = y + r - 1;
            bool vy = (unsigned)iy < 64u;
            rb[r]  = vy ? in + (((size_t)n * 64 + iy) * 64 + xm) * 64 + kc * 8 : zp;
            pc0[r] = vc0 ? rb[r] - 64 : zp;
            pc2[r] = vc2 ? rb[r] + 64 : zp;
        }
        bf8v av[18];
        #pragma unroll
        for (int g = 0; g < 18; ++g) {
            int tap = g >> 1, cib = g & 1;
            int r = tap / 3, c = tap % 3;
            cbfp pg = (c == 0) ? pc0[r] : ((c == 2) ? pc2[r] : rb[r]);
            av[g] = *reinterpret_cast<const bf8v*>(pg + cib * 32);
        }
        f4v acc = {0, 0, 0, 0};
        #pragma unroll
        for (int g = 0; g < 18; ++g)
            acc = __builtin_amdgcn_mfma_f32_16x16x32_bf16(sB[g * 64 + lane], av[g], acc, 0, 0, 0);

        #pragma unroll
        for (int r = 0; r < 4; ++r) {
            int co = kc * 4 + r;
            if (co < 10)
                z[(((size_t)n * 10 + co) << 12) + y * 64 + xm] = acc[r] * s4[r] + b4[r];
        }
    }
}

// =============== unified MFMA deconv (swapped), plane-split outputs ===============
// dd1 layout: [4][32][128][128][16] (plane = co/16).  dd2 chunk: [2][16][256][256][16].
template<int WHICH, int I_T>
__global__ __launch_bounds__(256, 2)
void deconv_mfma_k(const __hip_bfloat16* __restrict__ in,
                   const __hip_bfloat16* __restrict__ bpack,
                   const float* __restrict__ bconv,
                   const float* __restrict__ bg, const float* __restrict__ bb,
                   const float* __restrict__ bm, const float* __restrict__ bv,
                   __hip_bfloat16* __restrict__ out, cbfp zp, int n_base)
{
    constexpr int NKS  = (WHICH == 1) ? 9 : 18;
    constexpr int COUT = (WHICH == 1) ? 64 : 32;
    constexpr int NT   = COUT / 16;
    constexpr int HI   = (WHICH == 1) ? 64 : 128;
    constexpr int HO   = HI * 2;
    constexpr int JT   = HI / 16;
    constexpr size_t PL_IN  = (size_t)32 * 128 * 128 * 16;   // dd1 plane (WHICH==2 input)
    constexpr size_t PL_OUT = (WHICH == 1) ? (size_t)32 * 128 * 128 * 16
                                           : (size_t)16 * 256 * 256 * 16;
    constexpr const DTab& T = (WHICH == 1) ? TAB1 : TAB2;

    __shared__ bf8v sB[(WHICH == 2) ? NKS * 64 : 1];
    const bf8v* bpv = reinterpret_cast<const bf8v*>(bpack);

    int lane = threadIdx.x & 63;
    int nt, jt, it, nl;
    if constexpr (WHICH == 2) {
        nt = blockIdx.x & 1;                       // block-uniform co-plane
        int sid = (blockIdx.x >> 1) * 4 + (threadIdx.x >> 6);
        jt = sid % JT;  sid /= JT;
        it = sid % (HI / I_T);
        nl = sid / (HI / I_T);                     // local n (chunk of 16)
        for (int idx = threadIdx.x; idx < NKS * 64; idx += 256)
            sB[idx] = bpv[(size_t)nt * NKS * 64 + idx];
        __syncthreads();
    } else {
        int gw = blockIdx.x * 4 + (threadIdx.x >> 6);
        nt = gw % NT;  int mt = gw / NT;
        jt = mt % JT;  mt /= JT;
        it = mt % (HI / I_T);
        nl = mt / (HI / I_T);
    }
    int n = n_base + nl;                           // global image index
    int j0 = jt * 16;
    int m  = lane & 15, kc = lane >> 4;
    int jm = j0 + m;

    bf8v bfrag[(WHICH == 1) ? NKS : 1];
    if constexpr (WHICH == 1) {
        #pragma unroll
        for (int g = 0; g < NKS; ++g) bfrag[g] = bpv[((size_t)nt * NKS + g) * 64 + lane];
    }

    int co0 = nt * 16 + kc * 4;
    float s4[4], b4[4];
    #pragma unroll
    for (int r = 0; r < 4; ++r) {
        int co = co0 + r;
        float s = bg[co] * rsqrtf(bv[co] + 1e-5f);
        s4[r] = s; b4[r] = (bconv[co] - bm[co]) * s + bb[co];
    }
    bool vj = (jm + 1) < HI;

    for (int t = 0; t < I_T; ++t) {
        int i = it * I_T + t;
        bool vi = (i + 1) < HI;
        bf8v av[NKS];

        if constexpr (WHICH == 1) {
            // input q interleaved [N][64][64][32]
            cbfp p00 = in + (((size_t)n * HI + i) * HI + jm) * 32 + kc * 8;
            cbfp p01 = vj ? p00 + 32 : zp;
            cbfp p10 = vi ? p00 + (size_t)HI * 32 : zp;
            cbfp p11 = (vi && vj) ? p00 + (size_t)(HI + 1) * 32 : zp;
            #pragma unroll
            for (int g = 0; g < NKS; ++g) {
                cbfp pg = T.di[g] ? (T.dj[g] ? p11 : p10) : (T.dj[g] ? p01 : p00);
                av[g] = *reinterpret_cast<const bf8v*>(pg);
            }
        } else {
            // input dd1 4-plane: lane's ci = ci0 + kc*8 -> plane (ci/16), off (ci%16)
            cbfp baseA = in + (size_t)(kc >> 1) * PL_IN + (kc & 1) * 8;
            cbfp pA00 = baseA + (((size_t)n * HI + i) * HI + jm) * 16;
            cbfp pB00 = pA00 + 2 * PL_IN;
            cbfp pA01 = vj ? pA00 + 16 : zp;
            cbfp pB01 = vj ? pB00 + 16 : zp;
            cbfp pA10 = vi ? pA00 + (size_t)HI * 16 : zp;
            cbfp pB10 = vi ? pB00 + (size_t)HI * 16 : zp;
            cbfp pA11 = (vi && vj) ? pA00 + (size_t)(HI + 1) * 16 : zp;
            cbfp pB11 = (vi && vj) ? pB00 + (size_t)(HI + 1) * 16 : zp;
            #pragma unroll
            for (int g = 0; g < NKS; ++g) {
                cbfp pg;
                if (T.ci0[g]) pg = T.di[g] ? (T.dj[g] ? pB11 : pB10) : (T.dj[g] ? pB01 : pB00);
                else          pg = T.di[g] ? (T.dj[g] ? pA11 : pA10) : (T.dj[g] ? pA01 : pA00);
                av[g] = *reinterpret_cast<const bf8v*>(pg);
            }
        }

        f4v acc[4] = {{0,0,0,0},{0,0,0,0},{0,0,0,0},{0,0,0,0}};
        #pragma unroll
        for (int g = 0; g < NKS; ++g) {
            bf8v bw;
            if constexpr (WHICH == 2) bw = sB[g * 64 + lane];
            else                      bw = bfrag[g];
            acc[T.ph[g]] = __builtin_amdgcn_mfma_f32_16x16x32_bf16(bw, av[g], acc[T.ph[g]], 0, 0, 0);
        }

        // plane-split store: plane nt, in-plane channel kc*4 (chunk-local n for WHICH==2)
        __hip_bfloat16* ob = out + (size_t)nt * PL_OUT
                           + (((size_t)nl * HO + 2 * i) * HO + 2 * jm) * 16 + kc * 4;
        #pragma unroll
        for (int p = 0; p < 4; ++p) {
            int py = p >> 1, px = p & 1;
            float v0 = acc[p][0] * s4[0] + b4[0]; v0 = v0 >= 0.f ? v0 : 0.1f * v0;
            float v1 = acc[p][1] * s4[1] + b4[1]; v1 = v1 >= 0.f ? v1 : 0.1f * v1;
            float v2 = acc[p][2] * s4[2] + b4[2]; v2 = v2 >= 0.f ? v2 : 0.1f * v2;
            float v3 = acc[p][3] * s4[3] + b4[3]; v3 = v3 >= 0.f ? v3 : 0.1f * v3;
            union { __hip_bfloat162 h[2]; float2 f; } pk;
            pk.h[0] = __halves2bfloat162(__float2bfloat16(v0), __float2bfloat16(v1));
            pk.h[1] = __halves2bfloat162(__float2bfloat16(v2), __float2bfloat16(v3));
            *(float2*)(ob + ((size_t)py * HO + px) * 16) = pk.f;
        }
    }
}

// ======================= conv_out: 32->3 s1 + sigmoid, dd2 2-plane chunk input =======================
__global__ __launch_bounds__(256, 2)
void convout_mfma_k(const __hip_bfloat16* __restrict__ in,    // [2][16][256][256][16]
                    const __hip_bfloat16* __restrict__ bpack,
                    const float* __restrict__ b3,
                    float* __restrict__ out, cbfp zp, int n_base)
{
    constexpr size_t PL2 = (size_t)16 * 256 * 256 * 16;
    int lane = threadIdx.x & 63;
    int gw = blockIdx.x * 4 + (threadIdx.x >> 6);
    int xt = gw & 15;
    int yt = (gw >> 4) & 63;
    int nl = gw >> 10;                 // local n (0..15)
    int n  = n_base + nl;
    int m = lane & 15, kc = lane >> 4;
    int xm = xt * 16 + m;

    bf8v bfrag[9];
    #pragma unroll
    for (int g = 0; g < 9; ++g)
        bfrag[g] = reinterpret_cast<const bf8v*>(bpack)[g * 64 + lane];

    float bias0 = b3[0], bias1 = b3[1], bias2 = b3[2];
    bool vc0 = (xm > 0), vc2 = (xm < 255);
    cbfp baseA = in + (size_t)(kc >> 1) * PL2 + (kc & 1) * 8;

    for (int t = 0; t < 4; ++t) {
        int y = yt * 4 + t;
        cbfp rb[3], pc0[3], pc2[3];
        #pragma unroll
        for (int r = 0; r < 3; ++r) {
            int iy = y + r - 1;
            bool vy = (unsigned)iy < 256u;
            rb[r]  = vy ? baseA + (((size_t)nl * 256 + iy) * 256 + xm) * 16 : zp;
            pc0[r] = vc0 ? rb[r] - 16 : zp;
            pc2[r] = vc2 ? rb[r] + 16 : zp;
        }
        bf8v av[9];
        #pragma unroll
        for (int g = 0; g < 9; ++g) {
            int r = g / 3, c = g % 3;
            cbfp pg = (c == 0) ? pc0[r] : ((c == 2) ? pc2[r] : rb[r]);
            av[g] = *reinterpret_cast<const bf8v*>(pg);
        }
        f4v acc = {0, 0, 0, 0};
        #pragma unroll
        for (int g = 0; g < 9; ++g)
            acc = __builtin_amdgcn_mfma_f32_16x16x32_bf16(bfrag[g], av[g], acc, 0, 0, 0);

        if (kc == 0) {
            size_t ybase = ((size_t)n * 3) * 65536 + (size_t)y * 256 + xm;
            float v0 = acc[0] + bias0;
            float v1 = acc[1] + bias1;
            float v2 = acc[2] + bias2;
            out[ybase]             = 1.f / (1.f + __expf(-v0));
            out[ybase + 65536]     = 1.f / (1.f + __expf(-v1));
            out[ybase + 131072]    = 1.f / (1.f + __expf(-v2));
        }
    }
}

// ============ VQ (fp32 argmin) ============
__global__ __launch_bounds__(256)
void vq_k(const float* __restrict__ z, const float* __restrict__ emb,
          __hip_bfloat16* __restrict__ q, float* __restrict__ sse_acc,
          unsigned int* __restrict__ counts, int HW, int CHW)
{
    __shared__ float se[256 * 10];
    __shared__ unsigned int hist[256];
    __shared__ float wsum[4];
    int tid = threadIdx.x;
    for (int i = tid; i < 2560; i += 256) se[i] = emb[i];
    hist[tid] = 0u;
    __syncthreads();

    int pos = blockIdx.x * 256 + tid;
    int b = pos / HW;
    int sp = pos - b * HW;
    const float* zpz = z + (size_t)b * CHW + sp;
    float zv[10];
    #pragma unroll
    for (int c = 0; c < 10; ++c) zv[c] = zpz[(size_t)c * HW];

    float best = 3.4e38f;
    int bi = 0;
    for (int k = 0; k < 256; ++k) {
        const float* e = se + k * 10;
        float d = 0.f;
        #pragma unroll
        for (int c = 0; c < 10; ++c) { float t = zv[c] - e[c]; d = fmaf(t, t, d); }
        if (d < best) { best = d; bi = k; }
    }
    atomicAdd(&hist[bi], 1u);

    __hip_bfloat16* qp = q + (size_t)pos * 32;
    float lsse = 0.f;
    #pragma unroll
    for (int c = 0; c < 10; ++c) {
        float e = se[bi * 10 + c];
        qp[c] = __float2bfloat16(e);
        float t = e - zv[c];
        lsse = fmaf(t, t, lsse);
    }
    #pragma unroll
    for (int c = 10; c < 32; ++c) qp[c] = __float2bfloat16(0.f);

    #pragma unroll
    for (int off = 32; off > 0; off >>= 1) lsse += __shfl_down(lsse, off, 64);
    if ((tid & 63) == 0) wsum[tid >> 6] = lsse;
    __syncthreads();
    if (tid == 0) atomicAdd(sse_acc, wsum[0] + wsum[1] + wsum[2] + wsum[3]);
    atomicAdd(&counts[tid], hist[tid]);
}

__global__ __launch_bounds__(256)
void vq_finalize_k(const float* __restrict__ sse_acc, const unsigned int* __restrict__ counts,
                   float* __restrict__ out_loss, float* __restrict__ out_ppl,
                   float invNC, float invN)
{
    __shared__ float w4[4];
    int tid = threadIdx.x;
    float p = (float)counts[tid] * invN;
    float t = p * logf(p + 1e-10f);
    #pragma unroll
    for (int off = 32; off > 0; off >>= 1) t += __shfl_down(t, off, 64);
    if ((tid & 63) == 0) w4[tid >> 6] = t;
    __syncthreads();
    if (tid == 0) {
        float s = w4[0] + w4[1] + w4[2] + w4[3];
        *out_ppl  = expf(-s);
        *out_loss = 1.25f * sse_acc[0] * invNC;
    }
}

__global__ void zero_k(float* p, int n) {
    int i = blockIdx.x * 256 + threadIdx.x;
    if (i < n) p[i] = 0.f;
}

extern "C" void kernel_launch(void* const* d_in, const int* in_sizes, int n_in,
                              void* d_out, int out_size, void* d_ws, size_t ws_size,
                              hipStream_t stream) {
    const float* x      = (const float*)d_in[0];
    const float* enc_w1 = (const float*)d_in[1];
    const float* enc_b1 = (const float*)d_in[2];
    const float* bn1_g  = (const float*)d_in[3];
    const float* bn1_b  = (const float*)d_in[4];
    const float* bn1_m  = (const float*)d_in[5];
    const float* bn1_v  = (const float*)d_in[6];
    const float* enc_w2 = (const float*)d_in[7];
    const float* enc_b2 = (const float*)d_in[8];
    const float* bn2_g  = (const float*)d_in[9];
    const float* bn2_b  = (const float*)d_in[10];
    const float* bn2_m  = (const float*)d_in[11];
    const float* bn2_v  = (const float*)d_in[12];
    const float* enc_w3 = (const float*)d_in[13];
    const float* enc_b3 = (const float*)d_in[14];
    const float* bn3_g  = (const float*)d_in[15];
    const float* bn3_b  = (const float*)d_in[16];
    const float* bn3_m  = (const float*)d_in[17];
    const float* bn3_v  = (const float*)d_in[18];
    const float* emb    = (const float*)d_in[19];
    const float* dec_w1 = (const float*)d_in[20];
    const float* dec_b1 = (const float*)d_in[21];
    const float* dbn1_g = (const float*)d_in[22];
    const float* dbn1_b = (const float*)d_in[23];
    const float* dbn1_m = (const float*)d_in[24];
    const float* dbn1_v = (const float*)d_in[25];
    const float* dec_w2 = (const float*)d_in[26];
    const float* dec_b2 = (const float*)d_in[27];
    const float* dbn2_g = (const float*)d_in[28];
    const float* dbn2_b = (const float*)d_in[29];
    const float* dbn2_m = (const float*)d_in[30];
    const float* dbn2_v = (const float*)d_in[31];
    const float* dec_w3 = (const float*)d_in[32];
    const float* dec_b3 = (const float*)d_in[33];

    float* ws = (float*)d_ws;
    // workspace (float units), all 16B-aligned
    const size_t SSE_OFF  = 0;           // 1 f
    const size_t CNT_OFF  = 4;           // 256 u32
    const size_t ZP_OFF   = 260;         // 256 f zero page (1 KB)
    const size_t BPC2_OFF = 516;         // conv2 pack: 9216 f
    const size_t BPC3_OFF = 9732;        // conv3 pack: 4608 f
    const size_t BP1_OFF  = 14340;       // deconv1 pack: 9216 f
    const size_t BP2_OFF  = 23556;       // deconv2 pack: 9216 f
    const size_t BPO_OFF  = 32772;       // convout pack: 2304 f
    const size_t Q_OFF    = 35076;       // q NHWC bf16 C=32: 2,097,152 f
    const size_t Z_OFF    = 2132228;     // z fp32 NCHW: 1,310,720 f
    const size_t H1_OFF   = 3442948;     // h1 NHWC bf16: 8,388,608 f
    const size_t H2_OFF   = 11831556;    // h2 NHWC bf16: 4,194,304 f
    const size_t DD2_OFF  = 2132228;     // dd2 CHUNK (16 imgs, 2-plane): 16,777,216 f (overlays z/h1/h2)
    const size_t DD1_OFF  = 18909444;    // dd1 (4-plane): 16,777,216 f
    const size_t NEEDED_F = DD1_OFF + 16777216;   // ~143 MB

    if (ws_size < NEEDED_F * sizeof(float)) return;

    float* sse  = ws + SSE_OFF;
    unsigned int* counts = (unsigned int*)(ws + CNT_OFF);
    cbfp zp = (cbfp)(ws + ZP_OFF + 128);   // middle of zero page, +/-512B margin
    __hip_bfloat16* bpc2 = (__hip_bfloat16*)(ws + BPC2_OFF);
    __hip_bfloat16* bpc3 = (__hip_bfloat16*)(ws + BPC3_OFF);
    __hip_bfloat16* bp1  = (__hip_bfloat16*)(ws + BP1_OFF);
    __hip_bfloat16* bp2  = (__hip_bfloat16*)(ws + BP2_OFF);
    __hip_bfloat16* bpo  = (__hip_bfloat16*)(ws + BPO_OFF);
    __hip_bfloat16* qbuf = (__hip_bfloat16*)(ws + Q_OFF);
    float* zbuf = ws + Z_OFF;
    __hip_bfloat16* h1  = (__hip_bfloat16*)(ws + H1_OFF);
    __hip_bfloat16* h2  = (__hip_bfloat16*)(ws + H2_OFF);
    __hip_bfloat16* dd1 = (__hip_bfloat16*)(ws + DD1_OFF);
    __hip_bfloat16* dd2 = (__hip_bfloat16*)(ws + DD2_OFF);
    float* out = (float*)d_out;

    zero_k<<<3, 256, 0, stream>>>(ws, 516);
    pack_conv2_k<<<9, 256, 0, stream>>>(enc_w2, bpc2);
    pack_conv3_k<<<5, 256, 0, stream>>>(enc_w3, bpc3);
    pack_deconv_k<1><<<9, 256, 0, stream>>>(dec_w1, bp1);
    pack_deconv_k<2><<<9, 256, 0, stream>>>(dec_w2, bp2);
    pack_convout_k<<<3, 256, 0, stream>>>(dec_w3, bpo);

    // encoder
    conv1_k<<<2048, 256, 0, stream>>>(x, enc_w1, enc_b1, bn1_g, bn1_b, bn1_m, bn1_v, h1);
    conv2_mfma_k<<<2048, 256, 0, stream>>>(h1, bpc2, enc_b2, bn2_g, bn2_b, bn2_m, bn2_v, h2, zp);
    conv3_mfma_k<<<512, 256, 0, stream>>>(h2, bpc3, enc_b3, bn3_g, bn3_b, bn3_m, bn3_v, zbuf, zp);

    // VQ
    vq_k<<<512, 256, 0, stream>>>(zbuf, emb, qbuf, sse, counts, 4096, 40960);

    // decoder: deconv1 all n -> dd1 (4-plane); then per 16-image chunk deconv2 -> dd2 -> convout
    deconv_mfma_k<1, 2><<<4096, 256, 0, stream>>>(
        qbuf, bp1, dec_b1, dbn1_g, dbn1_b, dbn1_m, dbn1_v, dd1, zp, 0);
    for (int half = 0; half < 2; ++half) {
        deconv_mfma_k<2, 2><<<4096, 256, 0, stream>>>(
            dd1, bp2, dec_b2, dbn2_g, dbn2_b, dbn2_m, dbn2_v, dd2, zp, half * 16);
        convout_mfma_k<<<4096, 256, 0, stream>>>(dd2, bpo, dec_b3, out, zp, half * 16);
    }

    vq_finalize_k<<<1, 256, 0, stream>>>(sse, counts, out + 6291456, out + 6291457,
                                         1.f / 1310720.f, 1.f / 131072.f);
}

// Round 13
// 410.258 us; speedup vs baseline: 4.7728x; 1.0905x over previous
//
#include <hip/hip_runtime.h>
#include <hip/hip_bf16.h>
#include <math.h>

typedef __attribute__((ext_vector_type(8))) short bf8v;   // 8 bf16 in 4 VGPRs
typedef __attribute__((ext_vector_type(4))) float f4v;    // MFMA accumulator
typedef const __hip_bfloat16* cbfp;

__device__ __forceinline__ void ld4f(const float* p, float* o) {
    float4 t = *(const float4*)p; o[0] = t.x; o[1] = t.y; o[2] = t.z; o[3] = t.w;
}

// ======================= conv1: 3->32 s2, VALU, NCHW fp32 -> NHWC bf16 =======================
__global__ __launch_bounds__(256, 2)
void conv1_k(const float* __restrict__ x, const float* __restrict__ w,
             const float* __restrict__ bconv,
             const float* __restrict__ bg, const float* __restrict__ bb,
             const float* __restrict__ bm, const float* __restrict__ bv,
             __hip_bfloat16* __restrict__ out)   // [32][128][128][32]
{
    __shared__ float sw[3 * 8 * 12];
    int b  = blockIdx.x;
    int yt = b & 15;
    int cg = (b >> 4) & 3;
    int n  = b >> 6;
    int co0 = cg * 8;
    int tid = threadIdx.x;
    for (int idx = tid; idx < 3 * 8 * 9; idx += 256) {
        int t = idx % 9; int rest = idx / 9;
        int cot = rest % 8; int ci = rest / 8;
        sw[(ci * 8 + cot) * 12 + t] = w[(((size_t)(co0 + cot) * 3) + ci) * 9 + t];
    }
    __syncthreads();

    int tx = tid & 31, ty = tid >> 5;
    int y  = yt * 8 + ty;
    int x0 = tx * 4;
    int iyb = 2 * y - 1;
    int ixb = 2 * x0 - 1;

    float acc[8][4];
    #pragma unroll
    for (int c = 0; c < 8; ++c)
        #pragma unroll
        for (int u = 0; u < 4; ++u) acc[c][u] = 0.f;

    for (int ci = 0; ci < 3; ++ci) {
        const float* ipc = x + ((size_t)n * 3 + ci) * 65536;
        float iv[3][9];
        #pragma unroll
        for (int r = 0; r < 3; ++r) {
            int iy = iyb + r;
            bool vy = (unsigned)iy < 256u;
            const float* row = ipc + (size_t)iy * 256;
            if (vy) {
                iv[r][0] = (ixb >= 0) ? row[ixb] : 0.f;
                ld4f(row + ixb + 1, &iv[r][1]);
                ld4f(row + ixb + 5, &iv[r][5]);
            } else {
                #pragma unroll
                for (int c = 0; c < 9; ++c) iv[r][c] = 0.f;
            }
        }
        #pragma unroll
        for (int cot = 0; cot < 8; ++cot) {
            const float4* wp4 = reinterpret_cast<const float4*>(&sw[(ci * 8 + cot) * 12]);
            float4 wa = wp4[0], wb = wp4[1], wc4 = wp4[2];
            float wreg[9] = {wa.x, wa.y, wa.z, wa.w, wb.x, wb.y, wb.z, wb.w, wc4.x};
            #pragma unroll
            for (int r = 0; r < 3; ++r)
                #pragma unroll
                for (int c = 0; c < 3; ++c)
                    #pragma unroll
                    for (int u = 0; u < 4; ++u)
                        acc[cot][u] = fmaf(iv[r][u * 2 + c], wreg[r * 3 + c], acc[cot][u]);
        }
    }

    float rs[8][4];
    #pragma unroll
    for (int cot = 0; cot < 8; ++cot) {
        int co = co0 + cot;
        float s = bg[co] * rsqrtf(bv[co] + 1e-5f);
        float bias = (bconv[co] - bm[co]) * s + bb[co];
        #pragma unroll
        for (int u = 0; u < 4; ++u) {
            float v = acc[cot][u] * s + bias;
            rs[cot][u] = (v >= 0.f) ? v : 0.1f * v;
        }
    }
    #pragma unroll
    for (int u = 0; u < 4; ++u) {
        union { __hip_bfloat162 h[4]; float4 f; } pk;
        #pragma unroll
        for (int p2 = 0; p2 < 4; ++p2)
            pk.h[p2] = __halves2bfloat162(__float2bfloat16(rs[2 * p2][u]),
                                          __float2bfloat16(rs[2 * p2 + 1][u]));
        *(float4*)(out + (((size_t)n * 128 + y) * 128 + (x0 + u)) * 32 + co0) = pk.f;
    }
}

// ======================= weight packs (A-fragment lane order: row=co) =======================
__global__ __launch_bounds__(256)
void pack_conv2_k(const float* __restrict__ w, __hip_bfloat16* __restrict__ bp)
{
    int idx = blockIdx.x * 256 + threadIdx.x;
    if (idx >= 4 * 9 * 64) return;
    int lane = idx & 63;
    int g    = (idx >> 6) % 9;
    int nt   = idx / 576;
    int co   = nt * 16 + (lane & 15);
    __hip_bfloat16* o = bp + (size_t)idx * 8;
    for (int j = 0; j < 8; ++j) {
        int ci = (lane >> 4) * 8 + j;
        o[j] = __float2bfloat16(w[((size_t)co * 32 + ci) * 9 + g]);
    }
}

__global__ __launch_bounds__(256)
void pack_conv3_k(const float* __restrict__ w, __hip_bfloat16* __restrict__ bp)
{
    int idx = blockIdx.x * 256 + threadIdx.x;
    if (idx >= 18 * 64) return;
    int lane = idx & 63;
    int g    = idx >> 6;
    int tap  = g >> 1, cib = g & 1;
    int co   = lane & 15;
    __hip_bfloat16* o = bp + (size_t)idx * 8;
    for (int j = 0; j < 8; ++j) {
        int ci = cib * 32 + (lane >> 4) * 8 + j;
        float f = (co < 10) ? w[((size_t)co * 64 + ci) * 9 + tap] : 0.f;
        o[j] = __float2bfloat16(f);
    }
}

struct DTab { int di[18]; int dj[18]; int wi[18]; int ci0[18]; int ph[18]; };
constexpr DTab TAB1 = {
    {0, 0,0, 1,0, 1,1,0,0,  0,0,0,0,0,0,0,0,0},
    {0, 1,0, 0,0, 1,0,1,0,  0,0,0,0,0,0,0,0,0},
    {4, 3,5, 1,7, 0,2,6,8,  0,0,0,0,0,0,0,0,0},
    {0, 0,0, 0,0, 0,0,0,0,  0,0,0,0,0,0,0,0,0},
    {0, 1,1, 2,2, 3,3,3,3,  0,0,0,0,0,0,0,0,0}};
constexpr DTab TAB2 = {
    {0,0,  0,0,0,0,  1,1,0,0,  1,1,1,1,0,0,0,0},
    {0,0,  1,1,0,0,  0,0,0,0,  1,1,0,0,1,1,0,0},
    {4,4,  3,3,5,5,  1,1,7,7,  0,0,2,2,6,6,8,8},
    {0,32, 0,32,0,32, 0,32,0,32, 0,32,0,32,0,32,0,32},
    {0,0,  1,1,1,1,  2,2,2,2,  3,3,3,3,3,3,3,3}};

template<int WHICH>
__global__ __launch_bounds__(256)
void pack_deconv_k(const float* __restrict__ w, __hip_bfloat16* __restrict__ bp)
{
    constexpr int NKS  = (WHICH == 1) ? 9 : 18;
    constexpr int COUT = (WHICH == 1) ? 64 : 32;
    constexpr int CINr = (WHICH == 1) ? 10 : 64;
    constexpr int NT   = COUT / 16;
    constexpr const DTab& T = (WHICH == 1) ? TAB1 : TAB2;
    int idx = blockIdx.x * 256 + threadIdx.x;
    if (idx >= NT * NKS * 64) return;
    int lane = idx & 63;
    int g    = (idx >> 6) % NKS;
    int nt   = idx / (64 * NKS);
    int co   = nt * 16 + (lane & 15);
    int wi   = T.wi[g], ci0 = T.ci0[g];
    __hip_bfloat16* o = bp + (size_t)idx * 8;
    for (int j = 0; j < 8; ++j) {
        int ci = ci0 + (lane >> 4) * 8 + j;
        float f = (ci < CINr) ? w[((size_t)ci * COUT + co) * 9 + wi] : 0.f;
        o[j] = __float2bfloat16(f);
    }
}

__global__ __launch_bounds__(256)
void pack_convout_k(const float* __restrict__ w, __hip_bfloat16* __restrict__ bp)
{
    int idx = blockIdx.x * 256 + threadIdx.x;
    if (idx >= 9 * 64) return;
    int lane = idx & 63;
    int g    = idx >> 6;
    int co   = lane & 15;
    __hip_bfloat16* o = bp + (size_t)idx * 8;
    for (int j = 0; j < 8; ++j) {
        int ci = (lane >> 4) * 8 + j;
        float f = (co < 3) ? w[((size_t)co * 32 + ci) * 9 + g] : 0.f;
        o[j] = __float2bfloat16(f);
    }
}

// ======================= conv2: 32->64 s2, MFMA (swapped), NHWC =======================
__global__ __launch_bounds__(256, 2)
void conv2_mfma_k(const __hip_bfloat16* __restrict__ in,      // [32][128][128][32]
                  const __hip_bfloat16* __restrict__ bpack,
                  const float* __restrict__ bconv,
                  const float* __restrict__ bg, const float* __restrict__ bb,
                  const float* __restrict__ bm, const float* __restrict__ bv,
                  __hip_bfloat16* __restrict__ out,           // [32][64][64][64]
                  cbfp zp)
{
    int lane = threadIdx.x & 63;
    int gw = blockIdx.x * 4 + (threadIdx.x >> 6);
    int nt = gw & 3;
    int xt = (gw >> 2) & 3;
    int yt = (gw >> 4) & 15;
    int n  = gw >> 8;
    int m = lane & 15, kc = lane >> 4;
    int xm = xt * 16 + m;

    bf8v bfrag[9];
    const bf8v* bpv = reinterpret_cast<const bf8v*>(bpack);
    #pragma unroll
    for (int g = 0; g < 9; ++g) bfrag[g] = bpv[((size_t)nt * 9 + g) * 64 + lane];

    int co0 = nt * 16 + kc * 4;
    float s4[4], b4[4];
    #pragma unroll
    for (int r = 0; r < 4; ++r) {
        int co = co0 + r;
        float s = bg[co] * rsqrtf(bv[co] + 1e-5f);
        s4[r] = s; b4[r] = (bconv[co] - bm[co]) * s + bb[co];
    }
    bool vc0 = (xm > 0);

    for (int t = 0; t < 4; ++t) {
        int y = yt * 4 + t;
        cbfp rb[3], pc0[3];
        #pragma unroll
        for (int r = 0; r < 3; ++r) {
            int iy = 2 * y + r - 1;
            bool vy = (unsigned)iy < 128u;
            rb[r]  = vy ? in + (((size_t)n * 128 + iy) * 128 + 2 * xm) * 32 + kc * 8 : zp;
            pc0[r] = vc0 ? rb[r] - 32 : zp;
        }
        bf8v av[9];
        #pragma unroll
        for (int g = 0; g < 9; ++g) {
            int r = g / 3, c = g % 3;
            cbfp pg = (c == 0) ? pc0[r] : rb[r];
            av[g] = *reinterpret_cast<const bf8v*>(pg + (c == 2 ? 32 : 0));
        }
        f4v acc = {0, 0, 0, 0};
        #pragma unroll
        for (int g = 0; g < 9; ++g)
            acc = __builtin_amdgcn_mfma_f32_16x16x32_bf16(bfrag[g], av[g], acc, 0, 0, 0);

        union { __hip_bfloat162 h[2]; float2 f; } pk;
        float v0 = acc[0] * s4[0] + b4[0]; v0 = v0 >= 0.f ? v0 : 0.1f * v0;
        float v1 = acc[1] * s4[1] + b4[1]; v1 = v1 >= 0.f ? v1 : 0.1f * v1;
        float v2 = acc[2] * s4[2] + b4[2]; v2 = v2 >= 0.f ? v2 : 0.1f * v2;
        float v3 = acc[3] * s4[3] + b4[3]; v3 = v3 >= 0.f ? v3 : 0.1f * v3;
        pk.h[0] = __halves2bfloat162(__float2bfloat16(v0), __float2bfloat16(v1));
        pk.h[1] = __halves2bfloat162(__float2bfloat16(v2), __float2bfloat16(v3));
        *(float2*)(out + (((size_t)n * 64 + y) * 64 + xm) * 64 + co0) = pk.f;
    }
}

// ======================= conv3: 64->10 s1, MFMA (swapped) -> z fp32 NCHW =======================
__global__ __launch_bounds__(256, 2)
void conv3_mfma_k(const __hip_bfloat16* __restrict__ in,      // [32][64][64][64]
                  const __hip_bfloat16* __restrict__ bpack,
                  const float* __restrict__ bconv,
                  const float* __restrict__ bg, const float* __restrict__ bb,
                  const float* __restrict__ bm, const float* __restrict__ bv,
                  float* __restrict__ z, cbfp zp)              // [32][10][64][64]
{
    __shared__ bf8v sB[18 * 64];
    const bf8v* bpv = reinterpret_cast<const bf8v*>(bpack);
    for (int idx = threadIdx.x; idx < 18 * 64; idx += 256) sB[idx] = bpv[idx];
    __syncthreads();

    int lane = threadIdx.x & 63;
    int gw = blockIdx.x * 4 + (threadIdx.x >> 6);
    int xt = gw & 3;
    int yt = (gw >> 2) & 15;
    int n  = gw >> 6;
    int m = lane & 15, kc = lane >> 4;
    int xm = xt * 16 + m;

    float s4[4], b4[4];
    #pragma unroll
    for (int r = 0; r < 4; ++r) {
        int co = kc * 4 + r;
        if (co < 10) {
            float s = bg[co] * rsqrtf(bv[co] + 1e-5f);
            s4[r] = s; b4[r] = (bconv[co] - bm[co]) * s + bb[co];
        } else { s4[r] = 0.f; b4[r] = 0.f; }
    }
    bool vc0 = (xm > 0), vc2 = (xm < 63);

    for (int t = 0; t < 4; ++t) {
        int y = yt * 4 + t;
        cbfp rb[3], pc0[3], pc2[3];
        #pragma unroll
        for (int r = 0; r < 3; ++r) {
            int iy = y + r - 1;
            bool vy = (unsigned)iy < 64u;
            rb[r]  = vy ? in + (((size_t)n * 64 + iy) * 64 + xm) * 64 + kc * 8 : zp;
            pc0[r] = vc0 ? rb[r] - 64 : zp;
            pc2[r] = vc2 ? rb[r] + 64 : zp;
        }
        bf8v av[18];
        #pragma unroll
        for (int g = 0; g < 18; ++g) {
            int tap = g >> 1, cib = g & 1;
            int r = tap / 3, c = tap % 3;
            cbfp pg = (c == 0) ? pc0[r] : ((c == 2) ? pc2[r] : rb[r]);
            av[g] = *reinterpret_cast<const bf8v*>(pg + cib * 32);
        }
        f4v acc = {0, 0, 0, 0};
        #pragma unroll
        for (int g = 0; g < 18; ++g)
            acc = __builtin_amdgcn_mfma_f32_16x16x32_bf16(sB[g * 64 + lane], av[g], acc, 0, 0, 0);

        #pragma unroll
        for (int r = 0; r < 4; ++r) {
            int co = kc * 4 + r;
            if (co < 10)
                z[(((size_t)n * 10 + co) << 12) + y * 64 + xm] = acc[r] * s4[r] + b4[r];
        }
    }
}

// =============== unified MFMA deconv (swapped), plane-split outputs ===============
// dd1 layout: [4][32][128][128][16] (plane = co/16).  dd2 chunk: [2][16][256][256][16].
// WHICH==2: XCD-aware decode — nt pairs land on the same XCD, contiguous sid chunks.
template<int WHICH, int I_T>
__global__ __launch_bounds__(256, 2)
void deconv_mfma_k(const __hip_bfloat16* __restrict__ in,
                   const __hip_bfloat16* __restrict__ bpack,
                   const float* __restrict__ bconv,
                   const float* __restrict__ bg, const float* __restrict__ bb,
                   const float* __restrict__ bm, const float* __restrict__ bv,
                   __hip_bfloat16* __restrict__ out, cbfp zp, int n_base)
{
    constexpr int NKS  = (WHICH == 1) ? 9 : 18;
    constexpr int COUT = (WHICH == 1) ? 64 : 32;
    constexpr int NT   = COUT / 16;
    constexpr int HI   = (WHICH == 1) ? 64 : 128;
    constexpr int HO   = HI * 2;
    constexpr int JT   = HI / 16;
    constexpr size_t PL_IN  = (size_t)32 * 128 * 128 * 16;   // dd1 plane (WHICH==2 input)
    constexpr size_t PL_OUT = (WHICH == 1) ? (size_t)32 * 128 * 128 * 16
                                           : (size_t)16 * 256 * 256 * 16;
    constexpr const DTab& T = (WHICH == 1) ? TAB1 : TAB2;

    __shared__ bf8v sB[(WHICH == 2) ? NKS * 64 : 1];
    const bf8v* bpv = reinterpret_cast<const bf8v*>(bpack);

    int lane = threadIdx.x & 63;
    int nt, jt, it, nl;
    if constexpr (WHICH == 2) {
        // 2048 blocks: xcd = bid&7, loc = bid>>3 (0..255), nt = loc&1,
        // sid chunked per-XCD so both nt for a tile share an L2.
        int xcd = blockIdx.x & 7;
        int loc = blockIdx.x >> 3;
        nt = loc & 1;
        int sid = (xcd * 128 + (loc >> 1)) * 4 + (threadIdx.x >> 6);
        jt = sid % JT;  sid /= JT;
        it = sid % (HI / I_T);
        nl = sid / (HI / I_T);                     // local n (chunk of 16)
        for (int idx = threadIdx.x; idx < NKS * 64; idx += 256)
            sB[idx] = bpv[(size_t)nt * NKS * 64 + idx];
        __syncthreads();
    } else {
        int gw = blockIdx.x * 4 + (threadIdx.x >> 6);
        nt = gw % NT;  int mt = gw / NT;
        jt = mt % JT;  mt /= JT;
        it = mt % (HI / I_T);
        nl = mt / (HI / I_T);
    }
    int n = n_base + nl;                           // global image index
    int j0 = jt * 16;
    int m  = lane & 15, kc = lane >> 4;
    int jm = j0 + m;

    bf8v bfrag[(WHICH == 1) ? NKS : 1];
    if constexpr (WHICH == 1) {
        #pragma unroll
        for (int g = 0; g < NKS; ++g) bfrag[g] = bpv[((size_t)nt * NKS + g) * 64 + lane];
    }

    int co0 = nt * 16 + kc * 4;
    float s4[4], b4[4];
    #pragma unroll
    for (int r = 0; r < 4; ++r) {
        int co = co0 + r;
        float s = bg[co] * rsqrtf(bv[co] + 1e-5f);
        s4[r] = s; b4[r] = (bconv[co] - bm[co]) * s + bb[co];
    }
    bool vj = (jm + 1) < HI;

    #pragma unroll
    for (int t = 0; t < I_T; ++t) {
        int i = it * I_T + t;
        bool vi = (i + 1) < HI;
        bf8v av[NKS];

        if constexpr (WHICH == 1) {
            // input q interleaved [N][64][64][32]
            cbfp p00 = in + (((size_t)n * HI + i) * HI + jm) * 32 + kc * 8;
            cbfp p01 = vj ? p00 + 32 : zp;
            cbfp p10 = vi ? p00 + (size_t)HI * 32 : zp;
            cbfp p11 = (vi && vj) ? p00 + (size_t)(HI + 1) * 32 : zp;
            #pragma unroll
            for (int g = 0; g < NKS; ++g) {
                cbfp pg = T.di[g] ? (T.dj[g] ? p11 : p10) : (T.dj[g] ? p01 : p00);
                av[g] = *reinterpret_cast<const bf8v*>(pg);
            }
        } else {
            // input dd1 4-plane: lane's ci = ci0 + kc*8 -> plane (ci/16), off (ci%16)
            cbfp baseA = in + (size_t)(kc >> 1) * PL_IN + (kc & 1) * 8;
            cbfp pA00 = baseA + (((size_t)n * HI + i) * HI + jm) * 16;
            cbfp pB00 = pA00 + 2 * PL_IN;
            cbfp pA01 = vj ? pA00 + 16 : zp;
            cbfp pB01 = vj ? pB00 + 16 : zp;
            cbfp pA10 = vi ? pA00 + (size_t)HI * 16 : zp;
            cbfp pB10 = vi ? pB00 + (size_t)HI * 16 : zp;
            cbfp pA11 = (vi && vj) ? pA00 + (size_t)(HI + 1) * 16 : zp;
            cbfp pB11 = (vi && vj) ? pB00 + (size_t)(HI + 1) * 16 : zp;
            #pragma unroll
            for (int g = 0; g < NKS; ++g) {
                cbfp pg;
                if (T.ci0[g]) pg = T.di[g] ? (T.dj[g] ? pB11 : pB10) : (T.dj[g] ? pB01 : pB00);
                else          pg = T.di[g] ? (T.dj[g] ? pA11 : pA10) : (T.dj[g] ? pA01 : pA00);
                av[g] = *reinterpret_cast<const bf8v*>(pg);
            }
        }

        f4v acc[4] = {{0,0,0,0},{0,0,0,0},{0,0,0,0},{0,0,0,0}};
        #pragma unroll
        for (int g = 0; g < NKS; ++g) {
            bf8v bw;
            if constexpr (WHICH == 2) bw = sB[g * 64 + lane];
            else                      bw = bfrag[g];
            acc[T.ph[g]] = __builtin_amdgcn_mfma_f32_16x16x32_bf16(bw, av[g], acc[T.ph[g]], 0, 0, 0);
        }

        // plane-split store: plane nt, in-plane channel kc*4 (chunk-local n for WHICH==2)
        __hip_bfloat16* ob = out + (size_t)nt * PL_OUT
                           + (((size_t)nl * HO + 2 * i) * HO + 2 * jm) * 16 + kc * 4;
        #pragma unroll
        for (int p = 0; p < 4; ++p) {
            int py = p >> 1, px = p & 1;
            float v0 = acc[p][0] * s4[0] + b4[0]; v0 = v0 >= 0.f ? v0 : 0.1f * v0;
            float v1 = acc[p][1] * s4[1] + b4[1]; v1 = v1 >= 0.f ? v1 : 0.1f * v1;
            float v2 = acc[p][2] * s4[2] + b4[2]; v2 = v2 >= 0.f ? v2 : 0.1f * v2;
            float v3 = acc[p][3] * s4[3] + b4[3]; v3 = v3 >= 0.f ? v3 : 0.1f * v3;
            union { __hip_bfloat162 h[2]; float2 f; } pk;
            pk.h[0] = __halves2bfloat162(__float2bfloat16(v0), __float2bfloat16(v1));
            pk.h[1] = __halves2bfloat162(__float2bfloat16(v2), __float2bfloat16(v3));
            *(float2*)(ob + ((size_t)py * HO + px) * 16) = pk.f;
        }
    }
}

// ======================= conv_out: 32->3 s1 + sigmoid, dd2 2-plane chunk input =======================
__global__ __launch_bounds__(256, 2)
void convout_mfma_k(const __hip_bfloat16* __restrict__ in,    // [2][16][256][256][16]
                    const __hip_bfloat16* __restrict__ bpack,
                    const float* __restrict__ b3,
                    float* __restrict__ out, cbfp zp, int n_base)
{
    constexpr size_t PL2 = (size_t)16 * 256 * 256 * 16;
    int lane = threadIdx.x & 63;
    // XCD-chunked block swizzle (4096 blocks): contiguous gw chunks per XCD
    int swz = ((blockIdx.x & 7) << 9) + (blockIdx.x >> 3);
    int gw = swz * 4 + (threadIdx.x >> 6);
    int xt = gw & 15;
    int yt = (gw >> 4) & 63;
    int nl = gw >> 10;                 // local n (0..15)
    int n  = n_base + nl;
    int m = lane & 15, kc = lane >> 4;
    int xm = xt * 16 + m;

    bf8v bfrag[9];
    #pragma unroll
    for (int g = 0; g < 9; ++g)
        bfrag[g] = reinterpret_cast<const bf8v*>(bpack)[g * 64 + lane];

    float bias0 = b3[0], bias1 = b3[1], bias2 = b3[2];
    bool vc0 = (xm > 0), vc2 = (xm < 255);
    cbfp baseA = in + (size_t)(kc >> 1) * PL2 + (kc & 1) * 8;

    for (int t = 0; t < 4; ++t) {
        int y = yt * 4 + t;
        cbfp rb[3], pc0[3], pc2[3];
        #pragma unroll
        for (int r = 0; r < 3; ++r) {
            int iy = y + r - 1;
            bool vy = (unsigned)iy < 256u;
            rb[r]  = vy ? baseA + (((size_t)nl * 256 + iy) * 256 + xm) * 16 : zp;
            pc0[r] = vc0 ? rb[r] - 16 : zp;
            pc2[r] = vc2 ? rb[r] + 16 : zp;
        }
        bf8v av[9];
        #pragma unroll
        for (int g = 0; g < 9; ++g) {
            int r = g / 3, c = g % 3;
            cbfp pg = (c == 0) ? pc0[r] : ((c == 2) ? pc2[r] : rb[r]);
            av[g] = *reinterpret_cast<const bf8v*>(pg);
        }
        f4v acc = {0, 0, 0, 0};
        #pragma unroll
        for (int g = 0; g < 9; ++g)
            acc = __builtin_amdgcn_mfma_f32_16x16x32_bf16(bfrag[g], av[g], acc, 0, 0, 0);

        if (kc == 0) {
            size_t ybase = ((size_t)n * 3) * 65536 + (size_t)y * 256 + xm;
            float v0 = acc[0] + bias0;
            float v1 = acc[1] + bias1;
            float v2 = acc[2] + bias2;
            out[ybase]             = 1.f / (1.f + __expf(-v0));
            out[ybase + 65536]     = 1.f / (1.f + __expf(-v1));
            out[ybase + 131072]    = 1.f / (1.f + __expf(-v2));
        }
    }
}

// ============ VQ (fp32 argmin) ============
__global__ __launch_bounds__(256)
void vq_k(const float* __restrict__ z, const float* __restrict__ emb,
          __hip_bfloat16* __restrict__ q, float* __restrict__ sse_acc,
          unsigned int* __restrict__ counts, int HW, int CHW)
{
    __shared__ float se[256 * 10];
    __shared__ unsigned int hist[256];
    __shared__ float wsum[4];
    int tid = threadIdx.x;
    for (int i = tid; i < 2560; i += 256) se[i] = emb[i];
    hist[tid] = 0u;
    __syncthreads();

    int pos = blockIdx.x * 256 + tid;
    int b = pos / HW;
    int sp = pos - b * HW;
    const float* zpz = z + (size_t)b * CHW + sp;
    float zv[10];
    #pragma unroll
    for (int c = 0; c < 10; ++c) zv[c] = zpz[(size_t)c * HW];

    float best = 3.4e38f;
    int bi = 0;
    for (int k = 0; k < 256; ++k) {
        const float* e = se + k * 10;
        float d = 0.f;
        #pragma unroll
        for (int c = 0; c < 10; ++c) { float t = zv[c] - e[c]; d = fmaf(t, t, d); }
        if (d < best) { best = d; bi = k; }
    }
    atomicAdd(&hist[bi], 1u);

    __hip_bfloat16* qp = q + (size_t)pos * 32;
    float lsse = 0.f;
    #pragma unroll
    for (int c = 0; c < 10; ++c) {
        float e = se[bi * 10 + c];
        qp[c] = __float2bfloat16(e);
        float t = e - zv[c];
        lsse = fmaf(t, t, lsse);
    }
    #pragma unroll
    for (int c = 10; c < 32; ++c) qp[c] = __float2bfloat16(0.f);

    #pragma unroll
    for (int off = 32; off > 0; off >>= 1) lsse += __shfl_down(lsse, off, 64);
    if ((tid & 63) == 0) wsum[tid >> 6] = lsse;
    __syncthreads();
    if (tid == 0) atomicAdd(sse_acc, wsum[0] + wsum[1] + wsum[2] + wsum[3]);
    atomicAdd(&counts[tid], hist[tid]);
}

__global__ __launch_bounds__(256)
void vq_finalize_k(const float* __restrict__ sse_acc, const unsigned int* __restrict__ counts,
                   float* __restrict__ out_loss, float* __restrict__ out_ppl,
                   float invNC, float invN)
{
    __shared__ float w4[4];
    int tid = threadIdx.x;
    float p = (float)counts[tid] * invN;
    float t = p * logf(p + 1e-10f);
    #pragma unroll
    for (int off = 32; off > 0; off >>= 1) t += __shfl_down(t, off, 64);
    if ((tid & 63) == 0) w4[tid >> 6] = t;
    __syncthreads();
    if (tid == 0) {
        float s = w4[0] + w4[1] + w4[2] + w4[3];
        *out_ppl  = expf(-s);
        *out_loss = 1.25f * sse_acc[0] * invNC;
    }
}

__global__ void zero_k(float* p, int n) {
    int i = blockIdx.x * 256 + threadIdx.x;
    if (i < n) p[i] = 0.f;
}

extern "C" void kernel_launch(void* const* d_in, const int* in_sizes, int n_in,
                              void* d_out, int out_size, void* d_ws, size_t ws_size,
                              hipStream_t stream) {
    const float* x      = (const float*)d_in[0];
    const float* enc_w1 = (const float*)d_in[1];
    const float* enc_b1 = (const float*)d_in[2];
    const float* bn1_g  = (const float*)d_in[3];
    const float* bn1_b  = (const float*)d_in[4];
    const float* bn1_m  = (const float*)d_in[5];
    const float* bn1_v  = (const float*)d_in[6];
    const float* enc_w2 = (const float*)d_in[7];
    const float* enc_b2 = (const float*)d_in[8];
    const float* bn2_g  = (const float*)d_in[9];
    const float* bn2_b  = (const float*)d_in[10];
    const float* bn2_m  = (const float*)d_in[11];
    const float* bn2_v  = (const float*)d_in[12];
    const float* enc_w3 = (const float*)d_in[13];
    const float* enc_b3 = (const float*)d_in[14];
    const float* bn3_g  = (const float*)d_in[15];
    const float* bn3_b  = (const float*)d_in[16];
    const float* bn3_m  = (const float*)d_in[17];
    const float* bn3_v  = (const float*)d_in[18];
    const float* emb    = (const float*)d_in[19];
    const float* dec_w1 = (const float*)d_in[20];
    const float* dec_b1 = (const float*)d_in[21];
    const float* dbn1_g = (const float*)d_in[22];
    const float* dbn1_b = (const float*)d_in[23];
    const float* dbn1_m = (const float*)d_in[24];
    const float* dbn1_v = (const float*)d_in[25];
    const float* dec_w2 = (const float*)d_in[26];
    const float* dec_b2 = (const float*)d_in[27];
    const float* dbn2_g = (const float*)d_in[28];
    const float* dbn2_b = (const float*)d_in[29];
    const float* dbn2_m = (const float*)d_in[30];
    const float* dbn2_v = (const float*)d_in[31];
    const float* dec_w3 = (const float*)d_in[32];
    const float* dec_b3 = (const float*)d_in[33];

    float* ws = (float*)d_ws;
    // workspace (float units), all 16B-aligned
    const size_t SSE_OFF  = 0;           // 1 f
    const size_t CNT_OFF  = 4;           // 256 u32
    const size_t ZP_OFF   = 260;         // 256 f zero page (1 KB)
    const size_t BPC2_OFF = 516;         // conv2 pack: 9216 f
    const size_t BPC3_OFF = 9732;        // conv3 pack: 4608 f
    const size_t BP1_OFF  = 14340;       // deconv1 pack: 9216 f
    const size_t BP2_OFF  = 23556;       // deconv2 pack: 9216 f
    const size_t BPO_OFF  = 32772;       // convout pack: 2304 f
    const size_t Q_OFF    = 35076;       // q NHWC bf16 C=32: 2,097,152 f
    const size_t Z_OFF    = 2132228;     // z fp32 NCHW: 1,310,720 f
    const size_t H1_OFF   = 3442948;     // h1 NHWC bf16: 8,388,608 f
    const size_t H2_OFF   = 11831556;    // h2 NHWC bf16: 4,194,304 f
    const size_t DD2_OFF  = 2132228;     // dd2 CHUNK (16 imgs, 2-plane): 16,777,216 f (overlays z/h1/h2)
    const size_t DD1_OFF  = 18909444;    // dd1 (4-plane): 16,777,216 f
    const size_t NEEDED_F = DD1_OFF + 16777216;   // ~143 MB

    if (ws_size < NEEDED_F * sizeof(float)) return;

    float* sse  = ws + SSE_OFF;
    unsigned int* counts = (unsigned int*)(ws + CNT_OFF);
    cbfp zp = (cbfp)(ws + ZP_OFF + 128);   // middle of zero page, +/-512B margin
    __hip_bfloat16* bpc2 = (__hip_bfloat16*)(ws + BPC2_OFF);
    __hip_bfloat16* bpc3 = (__hip_bfloat16*)(ws + BPC3_OFF);
    __hip_bfloat16* bp1  = (__hip_bfloat16*)(ws + BP1_OFF);
    __hip_bfloat16* bp2  = (__hip_bfloat16*)(ws + BP2_OFF);
    __hip_bfloat16* bpo  = (__hip_bfloat16*)(ws + BPO_OFF);
    __hip_bfloat16* qbuf = (__hip_bfloat16*)(ws + Q_OFF);
    float* zbuf = ws + Z_OFF;
    __hip_bfloat16* h1  = (__hip_bfloat16*)(ws + H1_OFF);
    __hip_bfloat16* h2  = (__hip_bfloat16*)(ws + H2_OFF);
    __hip_bfloat16* dd1 = (__hip_bfloat16*)(ws + DD1_OFF);
    __hip_bfloat16* dd2 = (__hip_bfloat16*)(ws + DD2_OFF);
    float* out = (float*)d_out;

    zero_k<<<3, 256, 0, stream>>>(ws, 516);
    pack_conv2_k<<<9, 256, 0, stream>>>(enc_w2, bpc2);
    pack_conv3_k<<<5, 256, 0, stream>>>(enc_w3, bpc3);
    pack_deconv_k<1><<<9, 256, 0, stream>>>(dec_w1, bp1);
    pack_deconv_k<2><<<9, 256, 0, stream>>>(dec_w2, bp2);
    pack_convout_k<<<3, 256, 0, stream>>>(dec_w3, bpo);

    // encoder
    conv1_k<<<2048, 256, 0, stream>>>(x, enc_w1, enc_b1, bn1_g, bn1_b, bn1_m, bn1_v, h1);
    conv2_mfma_k<<<2048, 256, 0, stream>>>(h1, bpc2, enc_b2, bn2_g, bn2_b, bn2_m, bn2_v, h2, zp);
    conv3_mfma_k<<<512, 256, 0, stream>>>(h2, bpc3, enc_b3, bn3_g, bn3_b, bn3_m, bn3_v, zbuf, zp);

    // VQ
    vq_k<<<512, 256, 0, stream>>>(zbuf, emb, qbuf, sse, counts, 4096, 40960);

    // decoder: deconv1 (I_T=4) all n -> dd1; per 16-image chunk deconv2 (I_T=4, XCD-swizzled) -> dd2 -> convout
    deconv_mfma_k<1, 4><<<2048, 256, 0, stream>>>(
        qbuf, bp1, dec_b1, dbn1_g, dbn1_b, dbn1_m, dbn1_v, dd1, zp, 0);
    for (int half = 0; half < 2; ++half) {
        deconv_mfma_k<2, 4><<<2048, 256, 0, stream>>>(
            dd1, bp2, dec_b2, dbn2_g, dbn2_b, dbn2_m, dbn2_v, dd2, zp, half * 16);
        convout_mfma_k<<<4096, 256, 0, stream>>>(dd2, bpo, dec_b3, out, zp, half * 16);
    }

    vq_finalize_k<<<1, 256, 0, stream>>>(sse, counts, out + 6291456, out + 6291457,
                                         1.f / 1310720.f, 1.f / 131072.f);
}